// Round 5
// baseline (393.279 us; speedup 1.0000x reference)
//
#include <hip/hip_runtime.h>
#include <hip/hip_bf16.h>
#include <cstdint>

// ---------------------------------------------------------------------------
// GABlock, channel-last bf16-MFMA pipeline.
// R5: swin rewritten lane-per-token: SGPR-broadcast weights, K/V in LDS
//     [ch][m] (conflict-free writes, broadcast float4 reads), lane-local
//     softmax, pre-expanded rpb table, compile-time shift mask.
// ---------------------------------------------------------------------------

typedef __attribute__((ext_vector_type(8))) short bf8_t;   // 8 bf16 (4 VGPR)
typedef __attribute__((ext_vector_type(4))) float f4_t;    // 4 f32 acc

__device__ __forceinline__ float bf2f(unsigned short u) {
  union { unsigned int i; float f; } x; x.i = ((unsigned int)u) << 16; return x.f;
}
__device__ __forceinline__ unsigned short f2bf(float f) {
  union { float f; unsigned int i; } x; x.f = f;
  unsigned int r = x.i + 0x7FFFu + ((x.i >> 16) & 1u);
  return (unsigned short)(r >> 16);
}
__device__ __forceinline__ unsigned int pk2(float a, float b) {
  return (unsigned int)f2bf(a) | ((unsigned int)f2bf(b) << 16);
}

#define MB (1048576L)

// ---------------- dynamic position bias MLP --------------------------------
__global__ void pos_mlp_k(const float* __restrict__ w1, const float* __restrict__ b1,
                          const float* __restrict__ w2, const float* __restrict__ b2,
                          const float* __restrict__ w3, const float* __restrict__ b3,
                          float* __restrict__ table) {
  int j = blockIdx.x * 256 + threadIdx.x;
  if (j >= 961) return;
  float chv = (float)(j / 31) - 15.0f;
  float cwv = (float)(j % 31) - 15.0f;
  float t1[16], t2[16];
#pragma unroll
  for (int i = 0; i < 16; ++i) {
    float s = fmaf(w1[i * 2], chv, fmaf(w1[i * 2 + 1], cwv, b1[i]));
    t1[i] = fmaxf(s, 0.0f);
  }
#pragma unroll
  for (int i = 0; i < 16; ++i) {
    float s = b2[i];
#pragma unroll
    for (int k = 0; k < 16; ++k) s = fmaf(w2[i * 16 + k], t1[k], s);
    t2[i] = fmaxf(s, 0.0f);
  }
#pragma unroll
  for (int hh = 0; hh < 4; ++hh) {
    float s = b3[hh];
#pragma unroll
    for (int k = 0; k < 16; ++k) s = fmaf(w3[hh * 16 + k], t2[k], s);
    table[j * 4 + hh] = s;
  }
}

// pbT[h][m][q] = bias for query q, key m (transposed for the swapped-QK MFMA)
__global__ void pbT_gather_k(const float* __restrict__ table, float* __restrict__ pbT) {
  int t = blockIdx.x * 256 + threadIdx.x;   // 4*256*256
  int hh = t >> 16;
  int r = t & 65535;
  int m = r >> 8;
  int q = r & 255;
  int idx = ((q >> 4) - (m >> 4) + 15) * 31 + ((q & 15) - (m & 15) + 15);
  pbT[t] = table[idx * 4 + hh];
}

// rpbE[h][m][n] = rpb[idx(n,m)][h] expanded for the swin kernels
__global__ void rpbE_k(const float* __restrict__ rpb, float* __restrict__ rpbE) {
  int t = blockIdx.x * 256 + threadIdx.x;  // 4*64*64 = 16384
  int h = t >> 12, r = t & 4095, m = r >> 6, n = r & 63;
  int idx = ((n >> 3) - (m >> 3) + 7) * 15 + ((n & 7) - (m & 7) + 7);
  rpbE[t] = rpb[idx * 4 + h];
}

// ---------------- NCHW fp32 -> channel-last fp32 (and back) ----------------
__global__ __launch_bounds__(256) void tin_k(const float* __restrict__ x,
                                             float* __restrict__ xTf) {
  __shared__ float tile[64][132];
  const int b = blockIdx.z, px0 = blockIdx.x * 64, tid = threadIdx.x;
#pragma unroll
  for (int i = 0; i < 8; ++i) {
    int e = i * 256 + tid;
    int c = e >> 4, p4 = (e & 15) * 4;
    float4 v = *(const float4*)(x + (((size_t)(b * 128 + c)) << 14) + px0 + p4);
    tile[p4][c] = v.x; tile[p4 + 1][c] = v.y; tile[p4 + 2][c] = v.z; tile[p4 + 3][c] = v.w;
  }
  __syncthreads();
#pragma unroll
  for (int i = 0; i < 8; ++i) {
    int e = i * 256 + tid;
    int px = e >> 5, c4 = (e & 31) * 4;
    float4 v = make_float4(tile[px][c4], tile[px][c4 + 1], tile[px][c4 + 2], tile[px][c4 + 3]);
    *(float4*)(xTf + ((size_t)(b * 16384 + px0 + px)) * 128 + c4) = v;
  }
}

__global__ __launch_bounds__(256) void tout_k(const float* __restrict__ outT,
                                              float* __restrict__ out) {
  __shared__ float tile[64][132];
  const int b = blockIdx.z, px0 = blockIdx.x * 64, tid = threadIdx.x;
#pragma unroll
  for (int i = 0; i < 8; ++i) {
    int e = i * 256 + tid;
    int px = e >> 5, c4 = (e & 31) * 4;
    float4 v = *(const float4*)(outT + ((size_t)(b * 16384 + px0 + px)) * 128 + c4);
    tile[px][c4] = v.x; tile[px][c4 + 1] = v.y; tile[px][c4 + 2] = v.z; tile[px][c4 + 3] = v.w;
  }
  __syncthreads();
#pragma unroll
  for (int i = 0; i < 8; ++i) {
    int e = i * 256 + tid;
    int c = e >> 4, p4 = (e & 15) * 4;
    float4 v = make_float4(tile[p4][c], tile[p4 + 1][c], tile[p4 + 2][c], tile[p4 + 3][c]);
    *(float4*)(out + (((size_t)(b * 128 + c)) << 14) + px0 + p4) = v;
  }
}

// ---------------- generic bf16-MFMA GEMM -----------------------------------
template <int NF, int KC, int AF32, int EPI, int OSHUF>
__global__ __launch_bounds__(256) void gemm_k(
    const void* __restrict__ A, int a_rs, int a_c0,
    const float* __restrict__ W, const float* __restrict__ bias,
    const float* __restrict__ g, const float* __restrict__ bb,
    const float* __restrict__ resf, const unsigned short* __restrict__ resb,
    void* __restrict__ out, int o_rs, int o_c0) {
  __shared__ __align__(16) char Asw[128 * 128];
  __shared__ __align__(16) char Bsw[NF * 16 * 128];
  const int tid = threadIdx.x;
  const int lane = tid & 63, wv = tid >> 6, wpx = wv * 32;
  const int lr = lane & 15, lg = lane >> 4;
  const int px0 = blockIdx.x * 128;
  const int co0 = blockIdx.y * (NF * 16);

  f4_t acc[2][NF];
#pragma unroll
  for (int mf = 0; mf < 2; ++mf)
#pragma unroll
    for (int nf = 0; nf < NF; ++nf) acc[mf][nf] = (f4_t){0.f, 0.f, 0.f, 0.f};

  for (int kc = 0; kc < KC; ++kc) {
    const int k0 = kc * 64;
    if (kc) __syncthreads();
#pragma unroll
    for (int i = 0; i < 4; ++i) {
      int e = i * 256 + tid;
      int row = e >> 3, q8 = e & 7;
      char* dst = Asw + row * 128 + ((q8 ^ (row & 7)) << 4);
      if (AF32) {
        const float* src = (const float*)A + (size_t)(px0 + row) * a_rs + a_c0 + k0 + q8 * 8;
        float4 v0 = *(const float4*)src, v1 = *(const float4*)(src + 4);
        uint4 pk;
        pk.x = pk2(v0.x, v0.y); pk.y = pk2(v0.z, v0.w);
        pk.z = pk2(v1.x, v1.y); pk.w = pk2(v1.z, v1.w);
        *(uint4*)dst = pk;
      } else {
        const unsigned short* src =
            (const unsigned short*)A + (size_t)(px0 + row) * a_rs + a_c0 + k0 + q8 * 8;
        *(uint4*)dst = *(const uint4*)src;
      }
    }
#pragma unroll
    for (int i = 0; i < NF / 2; ++i) {
      int e = i * 256 + tid;
      int row = e >> 3, q8 = e & 7;
      const float* src = W + (size_t)(co0 + row) * (KC * 64) + k0 + q8 * 8;
      float4 v0 = *(const float4*)src, v1 = *(const float4*)(src + 4);
      uint4 pk;
      pk.x = pk2(v0.x, v0.y); pk.y = pk2(v0.z, v0.w);
      pk.z = pk2(v1.x, v1.y); pk.w = pk2(v1.z, v1.w);
      *(uint4*)(Bsw + row * 128 + ((q8 ^ (row & 7)) << 4)) = pk;
    }
    __syncthreads();
#pragma unroll
    for (int ks = 0; ks < 2; ++ks) {
      const int xk = (((ks * 4) + lg) ^ (lane & 7)) << 4;
      bf8_t av[2], bv[NF];
#pragma unroll
      for (int mf = 0; mf < 2; ++mf)
        av[mf] = *(const bf8_t*)(Asw + (wpx + mf * 16 + lr) * 128 + xk);
#pragma unroll
      for (int nf = 0; nf < NF; ++nf)
        bv[nf] = *(const bf8_t*)(Bsw + (nf * 16 + lr) * 128 + xk);
#pragma unroll
      for (int mf = 0; mf < 2; ++mf)
#pragma unroll
        for (int nf = 0; nf < NF; ++nf)
          acc[mf][nf] = __builtin_amdgcn_mfma_f32_16x16x32_bf16(av[mf], bv[nf], acc[mf][nf], 0, 0, 0);
    }
  }

  float bco[NF];
#pragma unroll
  for (int nf = 0; nf < NF; ++nf) bco[nf] = bias[co0 + nf * 16 + lr];

  if constexpr (EPI >= 2) {
    float gv[NF], bbv[NF];
#pragma unroll
    for (int nf = 0; nf < NF; ++nf) { gv[nf] = g[nf * 16 + lr]; bbv[nf] = bb[nf * 16 + lr]; }
#pragma unroll
    for (int mf = 0; mf < 2; ++mf)
#pragma unroll
      for (int nf = 0; nf < NF; ++nf)
#pragma unroll
        for (int r = 0; r < 4; ++r) acc[mf][nf][r] += bco[nf];
#pragma unroll
    for (int mf = 0; mf < 2; ++mf) {
#pragma unroll
      for (int r = 0; r < 4; ++r) {
        float s = 0.f, q = 0.f;
#pragma unroll
        for (int nf = 0; nf < NF; ++nf) {
          float v = acc[mf][nf][r];
          s += v; q += v * v;
        }
#pragma unroll
        for (int msk = 1; msk < 16; msk <<= 1) {
          s += __shfl_xor(s, msk);
          q += __shfl_xor(q, msk);
        }
        float mu = s * (1.0f / 128.0f);
        float var = q * (1.0f / 128.0f) - mu * mu;
        float rstd = rsqrtf(var + 1e-5f);
        int px_e = px0 + wpx + mf * 16 + lg * 4 + r;
        const float* xr = resf + (size_t)px_e * 128 + lr;
        if constexpr (EPI == 2) {
          unsigned short* op = (unsigned short*)out + (size_t)px_e * o_rs + lr;
#pragma unroll
          for (int nf = 0; nf < NF; ++nf) {
            float v = (acc[mf][nf][r] - mu) * rstd * gv[nf] + bbv[nf] + xr[nf * 16];
            op[nf * 16] = f2bf(v);
          }
        } else {
          const unsigned short* x2r = resb + (size_t)px_e * 128 + lr;
          float* op = (float*)out + (size_t)px_e * 128 + lr;
#pragma unroll
          for (int nf = 0; nf < NF; ++nf) {
            float v = (acc[mf][nf][r] - mu) * rstd * gv[nf] + bbv[nf] + xr[nf * 16] + bf2f(x2r[nf * 16]);
            op[nf * 16] = v;
          }
        }
      }
    }
  } else {
#pragma unroll
    for (int mf = 0; mf < 2; ++mf) {
#pragma unroll
      for (int r = 0; r < 4; ++r) {
        int px_e = px0 + wpx + mf * 16 + lg * 4 + r;
        size_t orow;
        if constexpr (OSHUF == 0) {
          orow = (size_t)px_e;
        } else if constexpr (OSHUF == 1) {
          int b = px_e >> 14, p = px_e & 16383, hh = p >> 7, w_ = p & 127;
          orow = (size_t)(b * 64 + (hh & 7) * 8 + (w_ & 7)) * 256 + ((hh >> 3) * 16 + (w_ >> 3));
        } else {
          int gbb = px_e >> 8, n = px_e & 255;
          int b = gbb >> 6, ih = (gbb >> 3) & 7, iw = gbb & 7;
          orow = (size_t)b * 16384 + ((n >> 4) * 8 + ih) * 128 + (n & 15) * 8 + iw;
        }
        unsigned short* op = (unsigned short*)out + orow * o_rs + o_c0 + co0 + lr;
#pragma unroll
        for (int nf = 0; nf < NF; ++nf) {
          float v = acc[mf][nf][r] + bco[nf];
          if constexpr (EPI == 1) v = 0.5f * v * (1.0f + erff(v * 0.7071067811865475f));
          op[nf * 16] = f2bf(v);
        }
      }
    }
  }
}

// ---------------- MFMA grid attention (N=256, hd=16, 4 heads) --------------
__global__ __launch_bounds__(256) void gattn_k(
    const unsigned short* __restrict__ Q, int q_rs, int q_c0,
    const unsigned short* __restrict__ K, int k_rs, int k_c0,
    const unsigned short* __restrict__ V, int v_rs, int v_c0,
    const float* __restrict__ pbT, unsigned short* __restrict__ outb, int o_rs, int o_c0) {
  __shared__ __align__(16) unsigned short K_lds[256 * 16];   // [m][16d]
  __shared__ __align__(16) unsigned short Vt[16 * 264];      // [d][264m] padded
  __shared__ __align__(16) unsigned short P_lds[4 * 64 * 40];// per-wave [64q][40m]
  const int gb = blockIdx.x, h = blockIdx.y, tid = threadIdx.x;
  const int lane = tid & 63, wv = tid >> 6;
  const int lr = lane & 15, lg = lane >> 4;
  const int q0 = wv * 64;

  {
    const unsigned short* kp = K + (size_t)(gb * 256 + tid) * k_rs + k_c0 + h * 16;
    *(uint4*)&K_lds[tid * 16]     = *(const uint4*)kp;
    *(uint4*)&K_lds[tid * 16 + 8] = *(const uint4*)(kp + 8);
    const unsigned short* vp = V + (size_t)(gb * 256 + tid) * v_rs + v_c0 + h * 16;
    uint4 va = *(const uint4*)vp;
    uint4 vb = *(const uint4*)(vp + 8);
    unsigned int w8[8] = {va.x, va.y, va.z, va.w, vb.x, vb.y, vb.z, vb.w};
#pragma unroll
    for (int w = 0; w < 8; ++w) {
      Vt[(2 * w) * 264 + tid]     = (unsigned short)(w8[w] & 0xffff);
      Vt[(2 * w + 1) * 264 + tid] = (unsigned short)(w8[w] >> 16);
    }
  }
  bf8_t bq[4];
  const bf8_t bz = {0, 0, 0, 0, 0, 0, 0, 0};
#pragma unroll
  for (int qt = 0; qt < 4; ++qt) {
    bq[qt] = bz;
    if (lg < 2)
      bq[qt] = *(const bf8_t*)(Q + (size_t)(gb * 256 + q0 + qt * 16 + lr) * q_rs + q_c0 + h * 16 + lg * 8);
  }
  __syncthreads();

  const f4_t z4 = {0.f, 0.f, 0.f, 0.f};
  f4_t oacc[4];
  float mrun[4], lrun[4];
#pragma unroll
  for (int qt = 0; qt < 4; ++qt) { oacc[qt] = z4; mrun[qt] = -3e38f; lrun[qt] = 0.0f; }

  unsigned short* Pw = &P_lds[wv * 64 * 40];

  for (int m0 = 0; m0 < 256; m0 += 32) {
    bf8_t ak0 = bz, ak1 = bz;
    if (lg < 2) {
      ak0 = *(const bf8_t*)&K_lds[(m0 + lr) * 16 + lg * 8];
      ak1 = *(const bf8_t*)&K_lds[(m0 + 16 + lr) * 16 + lg * 8];
    }
    bf8_t av = *(const bf8_t*)&Vt[lr * 264 + m0 + lg * 8];

#pragma unroll
    for (int qt = 0; qt < 4; ++qt) {
      f4_t st0 = __builtin_amdgcn_mfma_f32_16x16x32_bf16(ak0, bq[qt], z4, 0, 0, 0);
      f4_t st1 = __builtin_amdgcn_mfma_f32_16x16x32_bf16(ak1, bq[qt], z4, 0, 0, 0);
      const float* bpm = pbT + ((size_t)(h * 256 + m0 + lg * 4) << 8) + q0 + qt * 16 + lr;
      float s0[4], s1[4];
#pragma unroll
      for (int r = 0; r < 4; ++r) {
        s0[r] = fmaf(st0[r], 0.25f, bpm[r * 256]);
        s1[r] = fmaf(st1[r], 0.25f, bpm[(16 + r) * 256]);
      }
      float cmax = fmaxf(fmaxf(fmaxf(s0[0], s0[1]), fmaxf(s0[2], s0[3])),
                         fmaxf(fmaxf(s1[0], s1[1]), fmaxf(s1[2], s1[3])));
      cmax = fmaxf(cmax, __shfl_xor(cmax, 16));
      cmax = fmaxf(cmax, __shfl_xor(cmax, 32));
      float newm = fmaxf(mrun[qt], cmax);
      float c = __expf(mrun[qt] - newm);
      float p0[4], p1[4], ls = 0.0f;
#pragma unroll
      for (int r = 0; r < 4; ++r) {
        p0[r] = __expf(s0[r] - newm);
        p1[r] = __expf(s1[r] - newm);
        ls += p0[r] + p1[r];
      }
      ls += __shfl_xor(ls, 16);
      ls += __shfl_xor(ls, 32);
      lrun[qt] = lrun[qt] * c + ls;
      mrun[qt] = newm;
#pragma unroll
      for (int r = 0; r < 4; ++r) oacc[qt][r] *= c;
      int row = qt * 16 + lr;
      uint2 w0 = {pk2(p0[0], p0[1]), pk2(p0[2], p0[3])};
      uint2 w1 = {pk2(p1[0], p1[1]), pk2(p1[2], p1[3])};
      *(uint2*)&Pw[row * 40 + lg * 4]      = w0;
      *(uint2*)&Pw[row * 40 + 16 + lg * 4] = w1;
    }
#pragma unroll
    for (int qt = 0; qt < 4; ++qt) {
      bf8_t bp = *(const bf8_t*)&Pw[(qt * 16 + lr) * 40 + lg * 8];
      oacc[qt] = __builtin_amdgcn_mfma_f32_16x16x32_bf16(av, bp, oacc[qt], 0, 0, 0);
    }
  }

#pragma unroll
  for (int qt = 0; qt < 4; ++qt) {
    float inv = 1.0f / lrun[qt];
    uint2 o;
    o.x = pk2(oacc[qt][0] * inv, oacc[qt][1] * inv);
    o.y = pk2(oacc[qt][2] * inv, oacc[qt][3] * inv);
    unsigned short* op = outb + (size_t)(gb * 256 + q0 + qt * 16 + lr) * o_rs + o_c0 + h * 16 + lg * 4;
    *(uint2*)op = o;
  }
}

// ---------------- swin window attention, lane-per-token --------------------
// wave = one 64-token window; 4 windows per block. x/q/o in registers,
// weights via wave-uniform (SGPR) loads, K/V in LDS [ch][m] (conflict-free
// writes, broadcast f4 reads), lane-local softmax, rpbE coalesced from global.
template <int SHIFT>
__global__ __launch_bounds__(256, 1) void swin_k(
    const float* __restrict__ xTf, int c0,
    const float* __restrict__ qkvw, const float* __restrict__ qkvb,
    const float* __restrict__ rpbE, const float* __restrict__ pw,
    const float* __restrict__ pb, unsigned short* __restrict__ yT, int yc0) {
  __shared__ float KV[4][64][64];   // [wave][ch: 32K,32V][m]
  const int tid = threadIdx.x;
  const int lane = tid & 63, wv = tid >> 6;
  const int wb = blockIdx.x * 4 + wv;
  const int b = wb >> 8, wrem = wb & 255, wh = wrem >> 4, ww = wrem & 15;
  const int rn = lane >> 3, cn = lane & 7;
  const int hsrc = (wh * 8 + rn + SHIFT) & 127;
  const int wsrc = (ww * 8 + cn + SHIFT) & 127;

  // token channels -> registers
  float xv[32];
  {
    const float* xr = xTf + ((size_t)(b * 16384 + hsrc * 128 + wsrc)) * 128 + c0;
#pragma unroll
    for (int i = 0; i < 8; ++i) {
      float4 v = *(const float4*)(xr + i * 4);
      xv[i * 4] = v.x; xv[i * 4 + 1] = v.y; xv[i * 4 + 2] = v.z; xv[i * 4 + 3] = v.w;
    }
  }
  // K,V -> LDS (channels 32..95), uniform weights
#pragma unroll 2
  for (int co = 32; co < 96; ++co) {
    float s = qkvb[co];
#pragma unroll
    for (int ci = 0; ci < 32; ++ci) s = fmaf(qkvw[co * 32 + ci], xv[ci], s);
    KV[wv][co - 32][lane] = s;
  }
  __syncthreads();

  int regn = 0;
  if (SHIFT > 0) {
    int hr = wh * 8 + rn, wr_ = ww * 8 + cn;
    regn = (hr < 120 ? 0 : (hr < 124 ? 1 : 2)) * 3 + (wr_ < 120 ? 0 : (wr_ < 124 ? 1 : 2));
  }

  float o[32];
#pragma unroll
  for (int h = 0; h < 4; ++h) {
    // q for this head
    float q8[8];
#pragma unroll
    for (int d = 0; d < 8; ++d) {
      float sacc = qkvb[h * 8 + d];
#pragma unroll
      for (int ci = 0; ci < 32; ++ci) sacc = fmaf(qkvw[(h * 8 + d) * 32 + ci], xv[ci], sacc);
      q8[d] = sacc * 0.35355339059327373f;
    }
    // scores (lane-local full row)
    float s[64];
#pragma unroll
    for (int m0 = 0; m0 < 64; m0 += 16) {
#pragma unroll
      for (int i = 0; i < 16; ++i)
        s[m0 + i] = rpbE[h * 4096 + (m0 + i) * 64 + lane];
#pragma unroll
      for (int d = 0; d < 8; ++d) {
        float qd = q8[d];
        const float* kr = &KV[wv][h * 8 + d][m0];
#pragma unroll
        for (int i4 = 0; i4 < 4; ++i4) {
          float4 kv4 = *(const float4*)(kr + i4 * 4);
          s[m0 + i4 * 4 + 0] = fmaf(qd, kv4.x, s[m0 + i4 * 4 + 0]);
          s[m0 + i4 * 4 + 1] = fmaf(qd, kv4.y, s[m0 + i4 * 4 + 1]);
          s[m0 + i4 * 4 + 2] = fmaf(qd, kv4.z, s[m0 + i4 * 4 + 2]);
          s[m0 + i4 * 4 + 3] = fmaf(qd, kv4.w, s[m0 + i4 * 4 + 3]);
        }
      }
    }
    if (SHIFT > 0) {
#pragma unroll
      for (int m = 0; m < 64; ++m) {
        int hr = wh * 8 + (m >> 3), wr_ = ww * 8 + (m & 7);
        int regm = (hr < 120 ? 0 : (hr < 124 ? 1 : 2)) * 3 + (wr_ < 120 ? 0 : (wr_ < 124 ? 1 : 2));
        if (regm != regn) s[m] -= 100.0f;
      }
    }
    float mx = s[0];
#pragma unroll
    for (int m = 1; m < 64; ++m) mx = fmaxf(mx, s[m]);
    float l = 0.0f;
#pragma unroll
    for (int m = 0; m < 64; ++m) {
      float p = __expf(s[m] - mx);
      s[m] = p;
      l += p;
    }
    float inv = 1.0f / l;
    // PV
#pragma unroll
    for (int d = 0; d < 8; ++d) {
      const float* vr = &KV[wv][32 + h * 8 + d][0];
      float a = 0.0f;
#pragma unroll
      for (int i4 = 0; i4 < 16; ++i4) {
        float4 vv = *(const float4*)(vr + i4 * 4);
        a = fmaf(s[i4 * 4 + 0], vv.x, a);
        a = fmaf(s[i4 * 4 + 1], vv.y, a);
        a = fmaf(s[i4 * 4 + 2], vv.z, a);
        a = fmaf(s[i4 * 4 + 3], vv.w, a);
      }
      o[h * 8 + d] = a * inv;
    }
  }
  // out projection (registers + uniform weights) and write-back
  unsigned int opk[16];
#pragma unroll
  for (int cp = 0; cp < 16; ++cp) {
    float s0 = pb[2 * cp], s1 = pb[2 * cp + 1];
#pragma unroll
    for (int ci = 0; ci < 32; ++ci) {
      s0 = fmaf(pw[(2 * cp) * 32 + ci], o[ci], s0);
      s1 = fmaf(pw[(2 * cp + 1) * 32 + ci], o[ci], s1);
    }
    opk[cp] = pk2(s0, s1);
  }
  unsigned short* yp = yT + ((size_t)(b * 16384 + hsrc * 128 + wsrc)) * 128 + yc0;
#pragma unroll
  for (int i = 0; i < 4; ++i) {
    uint4 v = {opk[4 * i], opk[4 * i + 1], opk[4 * i + 2], opk[4 * i + 3]};
    *(uint4*)(yp + i * 8) = v;
  }
}

// ---------------------------------------------------------------------------
extern "C" void kernel_launch(void* const* d_in, const int* in_sizes, int n_in,
                              void* d_out, int out_size, void* d_ws, size_t ws_size,
                              hipStream_t stream) {
  (void)in_sizes; (void)n_in; (void)out_size; (void)ws_size;
  const float* x        = (const float*)d_in[0];
  const float* ln_g     = (const float*)d_in[1];
  const float* ln_b     = (const float*)d_in[2];
  const float* ga_qkv_w = (const float*)d_in[3];
  const float* ga_qkv_b = (const float*)d_in[4];
  const float* ga_gp_w  = (const float*)d_in[5];
  const float* ga_gp_b  = (const float*)d_in[6];
  const float* pos_w1   = (const float*)d_in[7];
  const float* pos_b1   = (const float*)d_in[8];
  const float* pos_w2   = (const float*)d_in[9];
  const float* pos_b2   = (const float*)d_in[10];
  const float* pos_w3   = (const float*)d_in[11];
  const float* pos_b3   = (const float*)d_in[12];
  const float* a1_pw    = (const float*)d_in[13];
  const float* a1_pb    = (const float*)d_in[14];
  const float* a2_pw    = (const float*)d_in[15];
  const float* a2_pb    = (const float*)d_in[16];
  const float* sw_qkv_w = (const float*)d_in[17];
  const float* sw_qkv_b = (const float*)d_in[18];
  const float* sw_rpb   = (const float*)d_in[19];
  const float* sw_pw    = (const float*)d_in[20];
  const float* sw_pb    = (const float*)d_in[21];
  const float* wn_qkv_w = (const float*)d_in[22];
  const float* wn_qkv_b = (const float*)d_in[23];
  const float* wn_rpb   = (const float*)d_in[24];
  const float* wn_pw    = (const float*)d_in[25];
  const float* wn_pb    = (const float*)d_in[26];
  const float* fc_w     = (const float*)d_in[27];
  const float* fc_b     = (const float*)d_in[28];
  const float* n2_g     = (const float*)d_in[29];
  const float* n2_b     = (const float*)d_in[30];
  const float* m1_w     = (const float*)d_in[31];
  const float* m1_b     = (const float*)d_in[32];
  const float* m2_w     = (const float*)d_in[33];
  const float* m2_b     = (const float*)d_in[34];
  float* out = (float*)d_out;
  char* base = (char*)d_ws;

  float*          xTf    = (float*)(base);                    // 32 MB
  unsigned short* qkvT   = (unsigned short*)(base + 32 * MB); // 24 MB
  unsigned short* xgridT = (unsigned short*)(base + 56 * MB); //  8 MB
  unsigned short* t1T    = (unsigned short*)(base + 64 * MB); //  8 MB
  unsigned short* t1pT   = (unsigned short*)(base + 72 * MB); //  8 MB
  unsigned short* yT     = (unsigned short*)(base + 80 * MB); // 16 MB
  unsigned short* x2T    = (unsigned short*)(base + 96 * MB); // 16 MB
  unsigned short* hT     = (unsigned short*)(base + 32 * MB); // alias
  float*          outT   = (float*)(base + 64 * MB);          // alias
  float*          pbT    = (float*)(base + 112 * MB);         //  1 MB
  float*          ptab   = (float*)(base + 113 * MB);         // 16 KB
  float*          rpbE_sw= (float*)(base + 113 * MB + 65536); // 64 KB
  float*          rpbE_wn= (float*)(base + 113 * MB + 131072);// 64 KB

  pos_mlp_k<<<4, 256, 0, stream>>>(pos_w1, pos_b1, pos_w2, pos_b2, pos_w3, pos_b3, ptab);
  pbT_gather_k<<<1024, 256, 0, stream>>>(ptab, pbT);
  rpbE_k<<<64, 256, 0, stream>>>(sw_rpb, rpbE_sw);
  rpbE_k<<<64, 256, 0, stream>>>(wn_rpb, rpbE_wn);

  tin_k<<<dim3(256, 1, 4), 256, 0, stream>>>(x, xTf);

  gemm_k<4, 1, 1, 0, 1><<<dim3(512, 3, 1), 256, 0, stream>>>(
      xTf, 128, 0, ga_qkv_w, ga_qkv_b, nullptr, nullptr, nullptr, nullptr, qkvT, 192, 0);
  gemm_k<4, 1, 1, 0, 1><<<dim3(512, 1, 1), 256, 0, stream>>>(
      xTf, 128, 0, ga_gp_w, ga_gp_b, nullptr, nullptr, nullptr, nullptr, xgridT, 64, 0);

  gattn_k<<<dim3(256, 4), 256, 0, stream>>>(
      xgridT, 64, 0, qkvT, 192, 64, qkvT, 192, 128, pbT, t1T, 64, 0);
  gemm_k<4, 1, 0, 0, 0><<<dim3(512, 1, 1), 256, 0, stream>>>(
      t1T, 64, 0, a1_pw, a1_pb, nullptr, nullptr, nullptr, nullptr, t1pT, 64, 0);

  gattn_k<<<dim3(256, 4), 256, 0, stream>>>(
      qkvT, 192, 0, xgridT, 64, 0, t1pT, 64, 0, pbT, t1T, 64, 0);
  gemm_k<4, 1, 0, 0, 2><<<dim3(512, 1, 1), 256, 0, stream>>>(
      t1T, 64, 0, a2_pw, a2_pb, nullptr, nullptr, nullptr, nullptr, yT, 128, 64);

  swin_k<0><<<256, 256, 0, stream>>>(xTf, 96, wn_qkv_w, wn_qkv_b, rpbE_wn, wn_pw, wn_pb, yT, 0);
  swin_k<4><<<256, 256, 0, stream>>>(xTf, 64, sw_qkv_w, sw_qkv_b, rpbE_sw, sw_pw, sw_pb, yT, 32);

  gemm_k<8, 2, 0, 2, 0><<<dim3(512, 1, 1), 256, 0, stream>>>(
      yT, 128, 0, fc_w, fc_b, ln_g, ln_b, xTf, nullptr, x2T, 128, 0);

  gemm_k<8, 2, 0, 1, 0><<<dim3(512, 2, 1), 256, 0, stream>>>(
      x2T, 128, 0, m1_w, m1_b, nullptr, nullptr, nullptr, nullptr, hT, 256, 0);
  gemm_k<8, 4, 0, 3, 0><<<dim3(512, 1, 1), 256, 0, stream>>>(
      hT, 256, 0, m2_w, m2_b, n2_g, n2_b, xTf, x2T, outT, 128, 0);

  tout_k<<<dim3(256, 1, 4), 256, 0, stream>>>(outT, out);
}

// Round 6
// 294.899 us; speedup vs baseline: 1.3336x; 1.3336x over previous
//
#include <hip/hip_runtime.h>
#include <hip/hip_bf16.h>
#include <cstdint>

// ---------------------------------------------------------------------------
// GABlock, channel-last bf16-MFMA pipeline.
// R6: swin back to thread=(head,query) structure with: per-thread global x
//     loads, channel-major K/V LDS (broadcast f4 reads), pre-expanded global
//     rpb[h][n][m], both branches merged into one launch.
// ---------------------------------------------------------------------------

typedef __attribute__((ext_vector_type(8))) short bf8_t;   // 8 bf16 (4 VGPR)
typedef __attribute__((ext_vector_type(4))) float f4_t;    // 4 f32 acc

__device__ __forceinline__ float bf2f(unsigned short u) {
  union { unsigned int i; float f; } x; x.i = ((unsigned int)u) << 16; return x.f;
}
__device__ __forceinline__ unsigned short f2bf(float f) {
  union { float f; unsigned int i; } x; x.f = f;
  unsigned int r = x.i + 0x7FFFu + ((x.i >> 16) & 1u);
  return (unsigned short)(r >> 16);
}
__device__ __forceinline__ unsigned int pk2(float a, float b) {
  return (unsigned int)f2bf(a) | ((unsigned int)f2bf(b) << 16);
}

#define MB (1048576L)

// ---------------- dynamic position bias MLP --------------------------------
__global__ void pos_mlp_k(const float* __restrict__ w1, const float* __restrict__ b1,
                          const float* __restrict__ w2, const float* __restrict__ b2,
                          const float* __restrict__ w3, const float* __restrict__ b3,
                          float* __restrict__ table) {
  int j = blockIdx.x * 256 + threadIdx.x;
  if (j >= 961) return;
  float chv = (float)(j / 31) - 15.0f;
  float cwv = (float)(j % 31) - 15.0f;
  float t1[16], t2[16];
#pragma unroll
  for (int i = 0; i < 16; ++i) {
    float s = fmaf(w1[i * 2], chv, fmaf(w1[i * 2 + 1], cwv, b1[i]));
    t1[i] = fmaxf(s, 0.0f);
  }
#pragma unroll
  for (int i = 0; i < 16; ++i) {
    float s = b2[i];
#pragma unroll
    for (int k = 0; k < 16; ++k) s = fmaf(w2[i * 16 + k], t1[k], s);
    t2[i] = fmaxf(s, 0.0f);
  }
#pragma unroll
  for (int hh = 0; hh < 4; ++hh) {
    float s = b3[hh];
#pragma unroll
    for (int k = 0; k < 16; ++k) s = fmaf(w3[hh * 16 + k], t2[k], s);
    table[j * 4 + hh] = s;
  }
}

// pbT[h][m][q] = bias for query q, key m (transposed for the swapped-QK MFMA)
__global__ void pbT_gather_k(const float* __restrict__ table, float* __restrict__ pbT) {
  int t = blockIdx.x * 256 + threadIdx.x;   // 4*256*256
  int hh = t >> 16;
  int r = t & 65535;
  int m = r >> 8;
  int q = r & 255;
  int idx = ((q >> 4) - (m >> 4) + 15) * 31 + ((q & 15) - (m & 15) + 15);
  pbT[t] = table[idx * 4 + hh];
}

// rpbE[h][n][m] = rpb[idx(n,m)][h]  (query-major for the swin kernel)
__global__ void rpbE_k(const float* __restrict__ rpb, float* __restrict__ rpbE) {
  int t = blockIdx.x * 256 + threadIdx.x;  // 4*64*64 = 16384
  int h = t >> 12, r = t & 4095, n = r >> 6, m = r & 63;
  int idx = ((n >> 3) - (m >> 3) + 7) * 15 + ((n & 7) - (m & 7) + 7);
  rpbE[t] = rpb[idx * 4 + h];
}

// ---------------- NCHW fp32 -> channel-last fp32 (and back) ----------------
__global__ __launch_bounds__(256) void tin_k(const float* __restrict__ x,
                                             float* __restrict__ xTf) {
  __shared__ float tile[64][132];
  const int b = blockIdx.z, px0 = blockIdx.x * 64, tid = threadIdx.x;
#pragma unroll
  for (int i = 0; i < 8; ++i) {
    int e = i * 256 + tid;
    int c = e >> 4, p4 = (e & 15) * 4;
    float4 v = *(const float4*)(x + (((size_t)(b * 128 + c)) << 14) + px0 + p4);
    tile[p4][c] = v.x; tile[p4 + 1][c] = v.y; tile[p4 + 2][c] = v.z; tile[p4 + 3][c] = v.w;
  }
  __syncthreads();
#pragma unroll
  for (int i = 0; i < 8; ++i) {
    int e = i * 256 + tid;
    int px = e >> 5, c4 = (e & 31) * 4;
    float4 v = make_float4(tile[px][c4], tile[px][c4 + 1], tile[px][c4 + 2], tile[px][c4 + 3]);
    *(float4*)(xTf + ((size_t)(b * 16384 + px0 + px)) * 128 + c4) = v;
  }
}

__global__ __launch_bounds__(256) void tout_k(const float* __restrict__ outT,
                                              float* __restrict__ out) {
  __shared__ float tile[64][132];
  const int b = blockIdx.z, px0 = blockIdx.x * 64, tid = threadIdx.x;
#pragma unroll
  for (int i = 0; i < 8; ++i) {
    int e = i * 256 + tid;
    int px = e >> 5, c4 = (e & 31) * 4;
    float4 v = *(const float4*)(outT + ((size_t)(b * 16384 + px0 + px)) * 128 + c4);
    tile[px][c4] = v.x; tile[px][c4 + 1] = v.y; tile[px][c4 + 2] = v.z; tile[px][c4 + 3] = v.w;
  }
  __syncthreads();
#pragma unroll
  for (int i = 0; i < 8; ++i) {
    int e = i * 256 + tid;
    int c = e >> 4, p4 = (e & 15) * 4;
    float4 v = make_float4(tile[p4][c], tile[p4 + 1][c], tile[p4 + 2][c], tile[p4 + 3][c]);
    *(float4*)(out + (((size_t)(b * 128 + c)) << 14) + px0 + p4) = v;
  }
}

// ---------------- generic bf16-MFMA GEMM -----------------------------------
template <int NF, int KC, int AF32, int EPI, int OSHUF>
__global__ __launch_bounds__(256) void gemm_k(
    const void* __restrict__ A, int a_rs, int a_c0,
    const float* __restrict__ W, const float* __restrict__ bias,
    const float* __restrict__ g, const float* __restrict__ bb,
    const float* __restrict__ resf, const unsigned short* __restrict__ resb,
    void* __restrict__ out, int o_rs, int o_c0) {
  __shared__ __align__(16) char Asw[128 * 128];
  __shared__ __align__(16) char Bsw[NF * 16 * 128];
  const int tid = threadIdx.x;
  const int lane = tid & 63, wv = tid >> 6, wpx = wv * 32;
  const int lr = lane & 15, lg = lane >> 4;
  const int px0 = blockIdx.x * 128;
  const int co0 = blockIdx.y * (NF * 16);

  f4_t acc[2][NF];
#pragma unroll
  for (int mf = 0; mf < 2; ++mf)
#pragma unroll
    for (int nf = 0; nf < NF; ++nf) acc[mf][nf] = (f4_t){0.f, 0.f, 0.f, 0.f};

  for (int kc = 0; kc < KC; ++kc) {
    const int k0 = kc * 64;
    if (kc) __syncthreads();
#pragma unroll
    for (int i = 0; i < 4; ++i) {
      int e = i * 256 + tid;
      int row = e >> 3, q8 = e & 7;
      char* dst = Asw + row * 128 + ((q8 ^ (row & 7)) << 4);
      if (AF32) {
        const float* src = (const float*)A + (size_t)(px0 + row) * a_rs + a_c0 + k0 + q8 * 8;
        float4 v0 = *(const float4*)src, v1 = *(const float4*)(src + 4);
        uint4 pk;
        pk.x = pk2(v0.x, v0.y); pk.y = pk2(v0.z, v0.w);
        pk.z = pk2(v1.x, v1.y); pk.w = pk2(v1.z, v1.w);
        *(uint4*)dst = pk;
      } else {
        const unsigned short* src =
            (const unsigned short*)A + (size_t)(px0 + row) * a_rs + a_c0 + k0 + q8 * 8;
        *(uint4*)dst = *(const uint4*)src;
      }
    }
#pragma unroll
    for (int i = 0; i < NF / 2; ++i) {
      int e = i * 256 + tid;
      int row = e >> 3, q8 = e & 7;
      const float* src = W + (size_t)(co0 + row) * (KC * 64) + k0 + q8 * 8;
      float4 v0 = *(const float4*)src, v1 = *(const float4*)(src + 4);
      uint4 pk;
      pk.x = pk2(v0.x, v0.y); pk.y = pk2(v0.z, v0.w);
      pk.z = pk2(v1.x, v1.y); pk.w = pk2(v1.z, v1.w);
      *(uint4*)(Bsw + row * 128 + ((q8 ^ (row & 7)) << 4)) = pk;
    }
    __syncthreads();
#pragma unroll
    for (int ks = 0; ks < 2; ++ks) {
      const int xk = (((ks * 4) + lg) ^ (lane & 7)) << 4;
      bf8_t av[2], bv[NF];
#pragma unroll
      for (int mf = 0; mf < 2; ++mf)
        av[mf] = *(const bf8_t*)(Asw + (wpx + mf * 16 + lr) * 128 + xk);
#pragma unroll
      for (int nf = 0; nf < NF; ++nf)
        bv[nf] = *(const bf8_t*)(Bsw + (nf * 16 + lr) * 128 + xk);
#pragma unroll
      for (int mf = 0; mf < 2; ++mf)
#pragma unroll
        for (int nf = 0; nf < NF; ++nf)
          acc[mf][nf] = __builtin_amdgcn_mfma_f32_16x16x32_bf16(av[mf], bv[nf], acc[mf][nf], 0, 0, 0);
    }
  }

  float bco[NF];
#pragma unroll
  for (int nf = 0; nf < NF; ++nf) bco[nf] = bias[co0 + nf * 16 + lr];

  if constexpr (EPI >= 2) {
    float gv[NF], bbv[NF];
#pragma unroll
    for (int nf = 0; nf < NF; ++nf) { gv[nf] = g[nf * 16 + lr]; bbv[nf] = bb[nf * 16 + lr]; }
#pragma unroll
    for (int mf = 0; mf < 2; ++mf)
#pragma unroll
      for (int nf = 0; nf < NF; ++nf)
#pragma unroll
        for (int r = 0; r < 4; ++r) acc[mf][nf][r] += bco[nf];
#pragma unroll
    for (int mf = 0; mf < 2; ++mf) {
#pragma unroll
      for (int r = 0; r < 4; ++r) {
        float s = 0.f, q = 0.f;
#pragma unroll
        for (int nf = 0; nf < NF; ++nf) {
          float v = acc[mf][nf][r];
          s += v; q += v * v;
        }
#pragma unroll
        for (int msk = 1; msk < 16; msk <<= 1) {
          s += __shfl_xor(s, msk);
          q += __shfl_xor(q, msk);
        }
        float mu = s * (1.0f / 128.0f);
        float var = q * (1.0f / 128.0f) - mu * mu;
        float rstd = rsqrtf(var + 1e-5f);
        int px_e = px0 + wpx + mf * 16 + lg * 4 + r;
        const float* xr = resf + (size_t)px_e * 128 + lr;
        if constexpr (EPI == 2) {
          unsigned short* op = (unsigned short*)out + (size_t)px_e * o_rs + lr;
#pragma unroll
          for (int nf = 0; nf < NF; ++nf) {
            float v = (acc[mf][nf][r] - mu) * rstd * gv[nf] + bbv[nf] + xr[nf * 16];
            op[nf * 16] = f2bf(v);
          }
        } else {
          const unsigned short* x2r = resb + (size_t)px_e * 128 + lr;
          float* op = (float*)out + (size_t)px_e * 128 + lr;
#pragma unroll
          for (int nf = 0; nf < NF; ++nf) {
            float v = (acc[mf][nf][r] - mu) * rstd * gv[nf] + bbv[nf] + xr[nf * 16] + bf2f(x2r[nf * 16]);
            op[nf * 16] = v;
          }
        }
      }
    }
  } else {
#pragma unroll
    for (int mf = 0; mf < 2; ++mf) {
#pragma unroll
      for (int r = 0; r < 4; ++r) {
        int px_e = px0 + wpx + mf * 16 + lg * 4 + r;
        size_t orow;
        if constexpr (OSHUF == 0) {
          orow = (size_t)px_e;
        } else if constexpr (OSHUF == 1) {
          int b = px_e >> 14, p = px_e & 16383, hh = p >> 7, w_ = p & 127;
          orow = (size_t)(b * 64 + (hh & 7) * 8 + (w_ & 7)) * 256 + ((hh >> 3) * 16 + (w_ >> 3));
        } else {
          int gbb = px_e >> 8, n = px_e & 255;
          int b = gbb >> 6, ih = (gbb >> 3) & 7, iw = gbb & 7;
          orow = (size_t)b * 16384 + ((n >> 4) * 8 + ih) * 128 + (n & 15) * 8 + iw;
        }
        unsigned short* op = (unsigned short*)out + orow * o_rs + o_c0 + co0 + lr;
#pragma unroll
        for (int nf = 0; nf < NF; ++nf) {
          float v = acc[mf][nf][r] + bco[nf];
          if constexpr (EPI == 1) v = 0.5f * v * (1.0f + erff(v * 0.7071067811865475f));
          op[nf * 16] = f2bf(v);
        }
      }
    }
  }
}

// ---------------- MFMA grid attention (N=256, hd=16, 4 heads) --------------
__global__ __launch_bounds__(256) void gattn_k(
    const unsigned short* __restrict__ Q, int q_rs, int q_c0,
    const unsigned short* __restrict__ K, int k_rs, int k_c0,
    const unsigned short* __restrict__ V, int v_rs, int v_c0,
    const float* __restrict__ pbT, unsigned short* __restrict__ outb, int o_rs, int o_c0) {
  __shared__ __align__(16) unsigned short K_lds[256 * 16];   // [m][16d]
  __shared__ __align__(16) unsigned short Vt[16 * 264];      // [d][264m] padded
  __shared__ __align__(16) unsigned short P_lds[4 * 64 * 40];// per-wave [64q][40m]
  const int gb = blockIdx.x, h = blockIdx.y, tid = threadIdx.x;
  const int lane = tid & 63, wv = tid >> 6;
  const int lr = lane & 15, lg = lane >> 4;
  const int q0 = wv * 64;

  {
    const unsigned short* kp = K + (size_t)(gb * 256 + tid) * k_rs + k_c0 + h * 16;
    *(uint4*)&K_lds[tid * 16]     = *(const uint4*)kp;
    *(uint4*)&K_lds[tid * 16 + 8] = *(const uint4*)(kp + 8);
    const unsigned short* vp = V + (size_t)(gb * 256 + tid) * v_rs + v_c0 + h * 16;
    uint4 va = *(const uint4*)vp;
    uint4 vb = *(const uint4*)(vp + 8);
    unsigned int w8[8] = {va.x, va.y, va.z, va.w, vb.x, vb.y, vb.z, vb.w};
#pragma unroll
    for (int w = 0; w < 8; ++w) {
      Vt[(2 * w) * 264 + tid]     = (unsigned short)(w8[w] & 0xffff);
      Vt[(2 * w + 1) * 264 + tid] = (unsigned short)(w8[w] >> 16);
    }
  }
  bf8_t bq[4];
  const bf8_t bz = {0, 0, 0, 0, 0, 0, 0, 0};
#pragma unroll
  for (int qt = 0; qt < 4; ++qt) {
    bq[qt] = bz;
    if (lg < 2)
      bq[qt] = *(const bf8_t*)(Q + (size_t)(gb * 256 + q0 + qt * 16 + lr) * q_rs + q_c0 + h * 16 + lg * 8);
  }
  __syncthreads();

  const f4_t z4 = {0.f, 0.f, 0.f, 0.f};
  f4_t oacc[4];
  float mrun[4], lrun[4];
#pragma unroll
  for (int qt = 0; qt < 4; ++qt) { oacc[qt] = z4; mrun[qt] = -3e38f; lrun[qt] = 0.0f; }

  unsigned short* Pw = &P_lds[wv * 64 * 40];

  for (int m0 = 0; m0 < 256; m0 += 32) {
    bf8_t ak0 = bz, ak1 = bz;
    if (lg < 2) {
      ak0 = *(const bf8_t*)&K_lds[(m0 + lr) * 16 + lg * 8];
      ak1 = *(const bf8_t*)&K_lds[(m0 + 16 + lr) * 16 + lg * 8];
    }
    bf8_t av = *(const bf8_t*)&Vt[lr * 264 + m0 + lg * 8];

#pragma unroll
    for (int qt = 0; qt < 4; ++qt) {
      f4_t st0 = __builtin_amdgcn_mfma_f32_16x16x32_bf16(ak0, bq[qt], z4, 0, 0, 0);
      f4_t st1 = __builtin_amdgcn_mfma_f32_16x16x32_bf16(ak1, bq[qt], z4, 0, 0, 0);
      const float* bpm = pbT + ((size_t)(h * 256 + m0 + lg * 4) << 8) + q0 + qt * 16 + lr;
      float s0[4], s1[4];
#pragma unroll
      for (int r = 0; r < 4; ++r) {
        s0[r] = fmaf(st0[r], 0.25f, bpm[r * 256]);
        s1[r] = fmaf(st1[r], 0.25f, bpm[(16 + r) * 256]);
      }
      float cmax = fmaxf(fmaxf(fmaxf(s0[0], s0[1]), fmaxf(s0[2], s0[3])),
                         fmaxf(fmaxf(s1[0], s1[1]), fmaxf(s1[2], s1[3])));
      cmax = fmaxf(cmax, __shfl_xor(cmax, 16));
      cmax = fmaxf(cmax, __shfl_xor(cmax, 32));
      float newm = fmaxf(mrun[qt], cmax);
      float c = __expf(mrun[qt] - newm);
      float p0[4], p1[4], ls = 0.0f;
#pragma unroll
      for (int r = 0; r < 4; ++r) {
        p0[r] = __expf(s0[r] - newm);
        p1[r] = __expf(s1[r] - newm);
        ls += p0[r] + p1[r];
      }
      ls += __shfl_xor(ls, 16);
      ls += __shfl_xor(ls, 32);
      lrun[qt] = lrun[qt] * c + ls;
      mrun[qt] = newm;
#pragma unroll
      for (int r = 0; r < 4; ++r) oacc[qt][r] *= c;
      int row = qt * 16 + lr;
      uint2 w0 = {pk2(p0[0], p0[1]), pk2(p0[2], p0[3])};
      uint2 w1 = {pk2(p1[0], p1[1]), pk2(p1[2], p1[3])};
      *(uint2*)&Pw[row * 40 + lg * 4]      = w0;
      *(uint2*)&Pw[row * 40 + 16 + lg * 4] = w1;
    }
#pragma unroll
    for (int qt = 0; qt < 4; ++qt) {
      bf8_t bp = *(const bf8_t*)&Pw[(qt * 16 + lr) * 40 + lg * 8];
      oacc[qt] = __builtin_amdgcn_mfma_f32_16x16x32_bf16(av, bp, oacc[qt], 0, 0, 0);
    }
  }

#pragma unroll
  for (int qt = 0; qt < 4; ++qt) {
    float inv = 1.0f / lrun[qt];
    uint2 o;
    o.x = pk2(oacc[qt][0] * inv, oacc[qt][1] * inv);
    o.y = pk2(oacc[qt][2] * inv, oacc[qt][3] * inv);
    unsigned short* op = outb + (size_t)(gb * 256 + q0 + qt * 16 + lr) * o_rs + o_c0 + h * 16 + lg * 4;
    *(uint2*)op = o;
  }
}

// ---------------- swin window attention (merged branches) ------------------
// block = one window (grid.x = 1024), grid.y selects branch (0 plain / 1 shift).
// Thread = (head h = tid>>6, query n = tid&63). Per-thread x row in regs,
// K/V channel-major in LDS (broadcast f4 reads), rpbE[h][n][m] from global.
__global__ __launch_bounds__(256) void swin_k(
    const float* __restrict__ xTf,
    const float* __restrict__ qkvw0, const float* __restrict__ qkvb0,
    const float* __restrict__ rpbE0, const float* __restrict__ pw0,
    const float* __restrict__ pb0,
    const float* __restrict__ qkvw1, const float* __restrict__ qkvb1,
    const float* __restrict__ rpbE1, const float* __restrict__ pw1,
    const float* __restrict__ pb1,
    unsigned short* __restrict__ yT) {
  __shared__ float KV[64][64];    // [ch: 32K,32V][m]
  __shared__ float ao[64][33];    // attn out, token-major
  const int br = blockIdx.y;
  const float* qkvw = br ? qkvw1 : qkvw0;
  const float* qkvb = br ? qkvb1 : qkvb0;
  const float* rpbE = br ? rpbE1 : rpbE0;
  const float* pw   = br ? pw1 : pw0;
  const float* pb   = br ? pb1 : pb0;
  const int c0 = br ? 64 : 96, yc0 = br ? 32 : 0, shift = br ? 4 : 0;

  const int wb = blockIdx.x;
  const int b = wb >> 8, wrem = wb & 255, wh = wrem >> 4, ww = wrem & 15;
  const int tid = threadIdx.x;
  const int h = tid >> 6, n = tid & 63;
  const int rn = n >> 3, cn = n & 7;
  const int hsrc = (wh * 8 + rn + shift) & 127;
  const int wsrc = (ww * 8 + cn + shift) & 127;

  // token channels -> registers (each of the 4 head-threads re-reads; L1 hit)
  float xv[32];
  {
    const float* xr = xTf + ((size_t)(b * 16384 + hsrc * 128 + wsrc)) * 128 + c0;
#pragma unroll
    for (int i = 0; i < 8; ++i) {
      float4 v = *(const float4*)(xr + i * 4);
      xv[i * 4] = v.x; xv[i * 4 + 1] = v.y; xv[i * 4 + 2] = v.z; xv[i * 4 + 3] = v.w;
    }
  }
  // q (kept in regs) + K,V (to LDS) for head h, 8 channels each
  float q8[8];
#pragma unroll
  for (int d = 0; d < 8; ++d) {
    int cq = h * 8 + d, ck = 32 + h * 8 + d, cv = 64 + h * 8 + d;
    float sq = qkvb[cq], sk = qkvb[ck], sv = qkvb[cv];
#pragma unroll
    for (int ci = 0; ci < 32; ++ci) {
      float xc = xv[ci];
      sq = fmaf(qkvw[cq * 32 + ci], xc, sq);
      sk = fmaf(qkvw[ck * 32 + ci], xc, sk);
      sv = fmaf(qkvw[cv * 32 + ci], xc, sv);
    }
    q8[d] = sq * 0.35355339059327373f;
    KV[h * 8 + d][n] = sk;
    KV[32 + h * 8 + d][n] = sv;
  }
  __syncthreads();

  int regn = 0;
  if (shift > 0) {
    int hr = wh * 8 + rn, wr_ = ww * 8 + cn;
    regn = (hr < 120 ? 0 : (hr < 124 ? 1 : 2)) * 3 + (wr_ < 120 ? 0 : (wr_ < 124 ? 1 : 2));
  }

  // scores: lane-local full row; rpbE[h][n][m] coalesced-ish f4 global reads
  float s[64];
  const float* rpr = rpbE + h * 4096 + n * 64;
#pragma unroll
  for (int m0 = 0; m0 < 64; m0 += 16) {
#pragma unroll
    for (int i4 = 0; i4 < 4; ++i4) {
      float4 bv = *(const float4*)(rpr + m0 + i4 * 4);
      s[m0 + i4 * 4 + 0] = bv.x; s[m0 + i4 * 4 + 1] = bv.y;
      s[m0 + i4 * 4 + 2] = bv.z; s[m0 + i4 * 4 + 3] = bv.w;
    }
#pragma unroll
    for (int d = 0; d < 8; ++d) {
      float qd = q8[d];
      const float* kr = &KV[h * 8 + d][m0];
#pragma unroll
      for (int i4 = 0; i4 < 4; ++i4) {
        float4 kv4 = *(const float4*)(kr + i4 * 4);
        s[m0 + i4 * 4 + 0] = fmaf(qd, kv4.x, s[m0 + i4 * 4 + 0]);
        s[m0 + i4 * 4 + 1] = fmaf(qd, kv4.y, s[m0 + i4 * 4 + 1]);
        s[m0 + i4 * 4 + 2] = fmaf(qd, kv4.z, s[m0 + i4 * 4 + 2]);
        s[m0 + i4 * 4 + 3] = fmaf(qd, kv4.w, s[m0 + i4 * 4 + 3]);
      }
    }
  }
  if (shift > 0) {
#pragma unroll
    for (int m = 0; m < 64; ++m) {
      int hr = wh * 8 + (m >> 3), wr_ = ww * 8 + (m & 7);
      int regm = (hr < 120 ? 0 : (hr < 124 ? 1 : 2)) * 3 + (wr_ < 120 ? 0 : (wr_ < 124 ? 1 : 2));
      if (regm != regn) s[m] -= 100.0f;
    }
  }
  float mx = s[0];
#pragma unroll
  for (int m = 1; m < 64; ++m) mx = fmaxf(mx, s[m]);
  float l = 0.0f;
#pragma unroll
  for (int m = 0; m < 64; ++m) {
    float p = __expf(s[m] - mx);
    s[m] = p;
    l += p;
  }
  float inv = 1.0f / l;
  // PV (broadcast f4 reads), write ao
#pragma unroll
  for (int d = 0; d < 8; ++d) {
    const float* vr = &KV[32 + h * 8 + d][0];
    float a = 0.0f;
#pragma unroll
    for (int i4 = 0; i4 < 16; ++i4) {
      float4 vv = *(const float4*)(vr + i4 * 4);
      a = fmaf(s[i4 * 4 + 0], vv.x, a);
      a = fmaf(s[i4 * 4 + 1], vv.y, a);
      a = fmaf(s[i4 * 4 + 2], vv.z, a);
      a = fmaf(s[i4 * 4 + 3], vv.w, a);
    }
    ao[n][h * 8 + d] = a * inv;
  }
  __syncthreads();
  // out projection: thread (h=cg, n) computes channels cg*8..cg*8+7
  {
    float oi[32];
#pragma unroll
    for (int ci = 0; ci < 32; ++ci) oi[ci] = ao[n][ci];
    unsigned int opk[4];
#pragma unroll
    for (int cp = 0; cp < 4; ++cp) {
      int c_0 = h * 8 + 2 * cp;
      float s0 = pb[c_0], s1 = pb[c_0 + 1];
#pragma unroll
      for (int ci = 0; ci < 32; ++ci) {
        s0 = fmaf(pw[c_0 * 32 + ci], oi[ci], s0);
        s1 = fmaf(pw[(c_0 + 1) * 32 + ci], oi[ci], s1);
      }
      opk[cp] = pk2(s0, s1);
    }
    uint4 v = {opk[0], opk[1], opk[2], opk[3]};
    *(uint4*)(yT + ((size_t)(b * 16384 + hsrc * 128 + wsrc)) * 128 + yc0 + h * 8) = v;
  }
}

// ---------------------------------------------------------------------------
extern "C" void kernel_launch(void* const* d_in, const int* in_sizes, int n_in,
                              void* d_out, int out_size, void* d_ws, size_t ws_size,
                              hipStream_t stream) {
  (void)in_sizes; (void)n_in; (void)out_size; (void)ws_size;
  const float* x        = (const float*)d_in[0];
  const float* ln_g     = (const float*)d_in[1];
  const float* ln_b     = (const float*)d_in[2];
  const float* ga_qkv_w = (const float*)d_in[3];
  const float* ga_qkv_b = (const float*)d_in[4];
  const float* ga_gp_w  = (const float*)d_in[5];
  const float* ga_gp_b  = (const float*)d_in[6];
  const float* pos_w1   = (const float*)d_in[7];
  const float* pos_b1   = (const float*)d_in[8];
  const float* pos_w2   = (const float*)d_in[9];
  const float* pos_b2   = (const float*)d_in[10];
  const float* pos_w3   = (const float*)d_in[11];
  const float* pos_b3   = (const float*)d_in[12];
  const float* a1_pw    = (const float*)d_in[13];
  const float* a1_pb    = (const float*)d_in[14];
  const float* a2_pw    = (const float*)d_in[15];
  const float* a2_pb    = (const float*)d_in[16];
  const float* sw_qkv_w = (const float*)d_in[17];
  const float* sw_qkv_b = (const float*)d_in[18];
  const float* sw_rpb   = (const float*)d_in[19];
  const float* sw_pw    = (const float*)d_in[20];
  const float* sw_pb    = (const float*)d_in[21];
  const float* wn_qkv_w = (const float*)d_in[22];
  const float* wn_qkv_b = (const float*)d_in[23];
  const float* wn_rpb   = (const float*)d_in[24];
  const float* wn_pw    = (const float*)d_in[25];
  const float* wn_pb    = (const float*)d_in[26];
  const float* fc_w     = (const float*)d_in[27];
  const float* fc_b     = (const float*)d_in[28];
  const float* n2_g     = (const float*)d_in[29];
  const float* n2_b     = (const float*)d_in[30];
  const float* m1_w     = (const float*)d_in[31];
  const float* m1_b     = (const float*)d_in[32];
  const float* m2_w     = (const float*)d_in[33];
  const float* m2_b     = (const float*)d_in[34];
  float* out = (float*)d_out;
  char* base = (char*)d_ws;

  float*          xTf    = (float*)(base);                    // 32 MB
  unsigned short* qkvT   = (unsigned short*)(base + 32 * MB); // 24 MB
  unsigned short* xgridT = (unsigned short*)(base + 56 * MB); //  8 MB
  unsigned short* t1T    = (unsigned short*)(base + 64 * MB); //  8 MB
  unsigned short* t1pT   = (unsigned short*)(base + 72 * MB); //  8 MB
  unsigned short* yT     = (unsigned short*)(base + 80 * MB); // 16 MB
  unsigned short* x2T    = (unsigned short*)(base + 96 * MB); // 16 MB
  unsigned short* hT     = (unsigned short*)(base + 32 * MB); // alias
  float*          outT   = (float*)(base + 64 * MB);          // alias
  float*          pbT    = (float*)(base + 112 * MB);         //  1 MB
  float*          ptab   = (float*)(base + 113 * MB);         // 16 KB
  float*          rpbE_sw= (float*)(base + 113 * MB + 65536); // 64 KB
  float*          rpbE_wn= (float*)(base + 113 * MB + 131072);// 64 KB

  pos_mlp_k<<<4, 256, 0, stream>>>(pos_w1, pos_b1, pos_w2, pos_b2, pos_w3, pos_b3, ptab);
  pbT_gather_k<<<1024, 256, 0, stream>>>(ptab, pbT);
  rpbE_k<<<64, 256, 0, stream>>>(sw_rpb, rpbE_sw);
  rpbE_k<<<64, 256, 0, stream>>>(wn_rpb, rpbE_wn);

  tin_k<<<dim3(256, 1, 4), 256, 0, stream>>>(x, xTf);

  gemm_k<4, 1, 1, 0, 1><<<dim3(512, 3, 1), 256, 0, stream>>>(
      xTf, 128, 0, ga_qkv_w, ga_qkv_b, nullptr, nullptr, nullptr, nullptr, qkvT, 192, 0);
  gemm_k<4, 1, 1, 0, 1><<<dim3(512, 1, 1), 256, 0, stream>>>(
      xTf, 128, 0, ga_gp_w, ga_gp_b, nullptr, nullptr, nullptr, nullptr, xgridT, 64, 0);

  gattn_k<<<dim3(256, 4), 256, 0, stream>>>(
      xgridT, 64, 0, qkvT, 192, 64, qkvT, 192, 128, pbT, t1T, 64, 0);
  gemm_k<4, 1, 0, 0, 0><<<dim3(512, 1, 1), 256, 0, stream>>>(
      t1T, 64, 0, a1_pw, a1_pb, nullptr, nullptr, nullptr, nullptr, t1pT, 64, 0);

  gattn_k<<<dim3(256, 4), 256, 0, stream>>>(
      qkvT, 192, 0, xgridT, 64, 0, t1pT, 64, 0, pbT, t1T, 64, 0);
  gemm_k<4, 1, 0, 0, 2><<<dim3(512, 1, 1), 256, 0, stream>>>(
      t1T, 64, 0, a2_pw, a2_pb, nullptr, nullptr, nullptr, nullptr, yT, 128, 64);

  // merged window branches: y=0 plain (x[96:128] -> yT[0:32]), y=1 shifted
  swin_k<<<dim3(1024, 2), 256, 0, stream>>>(
      xTf,
      wn_qkv_w, wn_qkv_b, rpbE_wn, wn_pw, wn_pb,
      sw_qkv_w, sw_qkv_b, rpbE_sw, sw_pw, sw_pb,
      yT);

  gemm_k<8, 2, 0, 2, 0><<<dim3(512, 1, 1), 256, 0, stream>>>(
      yT, 128, 0, fc_w, fc_b, ln_g, ln_b, xTf, nullptr, x2T, 128, 0);

  gemm_k<8, 2, 0, 1, 0><<<dim3(512, 2, 1), 256, 0, stream>>>(
      x2T, 128, 0, m1_w, m1_b, nullptr, nullptr, nullptr, nullptr, hT, 256, 0);
  gemm_k<8, 4, 0, 3, 0><<<dim3(512, 1, 1), 256, 0, stream>>>(
      hT, 256, 0, m2_w, m2_b, n2_g, n2_b, xTf, x2T, outT, 128, 0);

  tout_k<<<dim3(256, 1, 4), 256, 0, stream>>>(outT, out);
}

// Round 7
// 234.790 us; speedup vs baseline: 1.6750x; 1.2560x over previous
//
#include <hip/hip_runtime.h>
#include <hip/hip_bf16.h>
#include <cstdint>

// ---------------------------------------------------------------------------
// GABlock, channel-last bf16-MFMA pipeline.
// R7: swin = block-diagonal qkv GEMM (window-ordered output, shift folded in)
//     + barrier-free per-wave MFMA window attention (swat_k).
// ---------------------------------------------------------------------------

typedef __attribute__((ext_vector_type(8))) short bf8_t;   // 8 bf16 (4 VGPR)
typedef __attribute__((ext_vector_type(4))) float f4_t;    // 4 f32 acc

__device__ __forceinline__ float bf2f(unsigned short u) {
  union { unsigned int i; float f; } x; x.i = ((unsigned int)u) << 16; return x.f;
}
__device__ __forceinline__ unsigned short f2bf(float f) {
  union { float f; unsigned int i; } x; x.f = f;
  unsigned int r = x.i + 0x7FFFu + ((x.i >> 16) & 1u);
  return (unsigned short)(r >> 16);
}
__device__ __forceinline__ unsigned int pk2(float a, float b) {
  return (unsigned int)f2bf(a) | ((unsigned int)f2bf(b) << 16);
}

#define MB (1048576L)

// ---------------- dynamic position bias MLP --------------------------------
__global__ void pos_mlp_k(const float* __restrict__ w1, const float* __restrict__ b1,
                          const float* __restrict__ w2, const float* __restrict__ b2,
                          const float* __restrict__ w3, const float* __restrict__ b3,
                          float* __restrict__ table) {
  int j = blockIdx.x * 256 + threadIdx.x;
  if (j >= 961) return;
  float chv = (float)(j / 31) - 15.0f;
  float cwv = (float)(j % 31) - 15.0f;
  float t1[16], t2[16];
#pragma unroll
  for (int i = 0; i < 16; ++i) {
    float s = fmaf(w1[i * 2], chv, fmaf(w1[i * 2 + 1], cwv, b1[i]));
    t1[i] = fmaxf(s, 0.0f);
  }
#pragma unroll
  for (int i = 0; i < 16; ++i) {
    float s = b2[i];
#pragma unroll
    for (int k = 0; k < 16; ++k) s = fmaf(w2[i * 16 + k], t1[k], s);
    t2[i] = fmaxf(s, 0.0f);
  }
#pragma unroll
  for (int hh = 0; hh < 4; ++hh) {
    float s = b3[hh];
#pragma unroll
    for (int k = 0; k < 16; ++k) s = fmaf(w3[hh * 16 + k], t2[k], s);
    table[j * 4 + hh] = s;
  }
}

// pbT[h][m][q] = bias for query q, key m (transposed for the swapped-QK MFMA)
__global__ void pbT_gather_k(const float* __restrict__ table, float* __restrict__ pbT) {
  int t = blockIdx.x * 256 + threadIdx.x;   // 4*256*256
  int hh = t >> 16;
  int r = t & 65535;
  int m = r >> 8;
  int q = r & 255;
  int idx = ((q >> 4) - (m >> 4) + 15) * 31 + ((q & 15) - (m & 15) + 15);
  pbT[t] = table[idx * 4 + hh];
}

// rpbT[h][m][n] = rpb[idx(n,m)][h]  (key-major, for the swapped-QK swat)
__global__ void rpbT_k(const float* __restrict__ rpb, float* __restrict__ rpbT) {
  int t = blockIdx.x * 256 + threadIdx.x;  // 4*64*64 = 16384
  int h = t >> 12, r = t & 4095, m = r >> 6, n = r & 63;
  int idx = ((n >> 3) - (m >> 3) + 7) * 15 + ((n & 7) - (m & 7) + 7);
  rpbT[t] = rpb[idx * 4 + h];
}

// block-diagonal 192x64 qkv weight + 192 bias for both window branches
__global__ void wq2_k(const float* __restrict__ sw_w, const float* __restrict__ sw_b,
                      const float* __restrict__ wn_w, const float* __restrict__ wn_b,
                      float* __restrict__ w2, float* __restrict__ b2) {
  int t = blockIdx.x * 256 + threadIdx.x;   // 12288
  if (t < 12288) {
    int row = t >> 6, col = t & 63;
    float v = 0.0f;
    if (row < 96) { if (col < 32) v = sw_w[row * 32 + col]; }
    else          { if (col >= 32) v = wn_w[(row - 96) * 32 + col - 32]; }
    w2[t] = v;
  }
  if (t < 192) b2[t] = t < 96 ? sw_b[t] : wn_b[t - 96];
}

// ---------------- NCHW fp32 -> channel-last fp32 (and back) ----------------
__global__ __launch_bounds__(256) void tin_k(const float* __restrict__ x,
                                             float* __restrict__ xTf) {
  __shared__ float tile[64][132];
  const int b = blockIdx.z, px0 = blockIdx.x * 64, tid = threadIdx.x;
#pragma unroll
  for (int i = 0; i < 8; ++i) {
    int e = i * 256 + tid;
    int c = e >> 4, p4 = (e & 15) * 4;
    float4 v = *(const float4*)(x + (((size_t)(b * 128 + c)) << 14) + px0 + p4);
    tile[p4][c] = v.x; tile[p4 + 1][c] = v.y; tile[p4 + 2][c] = v.z; tile[p4 + 3][c] = v.w;
  }
  __syncthreads();
#pragma unroll
  for (int i = 0; i < 8; ++i) {
    int e = i * 256 + tid;
    int px = e >> 5, c4 = (e & 31) * 4;
    float4 v = make_float4(tile[px][c4], tile[px][c4 + 1], tile[px][c4 + 2], tile[px][c4 + 3]);
    *(float4*)(xTf + ((size_t)(b * 16384 + px0 + px)) * 128 + c4) = v;
  }
}

__global__ __launch_bounds__(256) void tout_k(const float* __restrict__ outT,
                                              float* __restrict__ out) {
  __shared__ float tile[64][132];
  const int b = blockIdx.z, px0 = blockIdx.x * 64, tid = threadIdx.x;
#pragma unroll
  for (int i = 0; i < 8; ++i) {
    int e = i * 256 + tid;
    int px = e >> 5, c4 = (e & 31) * 4;
    float4 v = *(const float4*)(outT + ((size_t)(b * 16384 + px0 + px)) * 128 + c4);
    tile[px][c4] = v.x; tile[px][c4 + 1] = v.y; tile[px][c4 + 2] = v.z; tile[px][c4 + 3] = v.w;
  }
  __syncthreads();
#pragma unroll
  for (int i = 0; i < 8; ++i) {
    int e = i * 256 + tid;
    int c = e >> 4, p4 = (e & 15) * 4;
    float4 v = make_float4(tile[p4][c], tile[p4 + 1][c], tile[p4 + 2][c], tile[p4 + 3][c]);
    *(float4*)(out + (((size_t)(b * 128 + c)) << 14) + px0 + p4) = v;
  }
}

// ---------------- generic bf16-MFMA GEMM -----------------------------------
// OSHUF: 0 none, 1 grid-shuffle, 2 grid-unshuffle, 3 window-order (qkv2)
template <int NF, int KC, int AF32, int EPI, int OSHUF>
__global__ __launch_bounds__(256) void gemm_k(
    const void* __restrict__ A, int a_rs, int a_c0,
    const float* __restrict__ W, const float* __restrict__ bias,
    const float* __restrict__ g, const float* __restrict__ bb,
    const float* __restrict__ resf, const unsigned short* __restrict__ resb,
    void* __restrict__ out, int o_rs, int o_c0) {
  __shared__ __align__(16) char Asw[128 * 128];
  __shared__ __align__(16) char Bsw[NF * 16 * 128];
  const int tid = threadIdx.x;
  const int lane = tid & 63, wv = tid >> 6, wpx = wv * 32;
  const int lr = lane & 15, lg = lane >> 4;
  const int px0 = blockIdx.x * 128;
  const int co0 = blockIdx.y * (NF * 16);

  f4_t acc[2][NF];
#pragma unroll
  for (int mf = 0; mf < 2; ++mf)
#pragma unroll
    for (int nf = 0; nf < NF; ++nf) acc[mf][nf] = (f4_t){0.f, 0.f, 0.f, 0.f};

  for (int kc = 0; kc < KC; ++kc) {
    const int k0 = kc * 64;
    if (kc) __syncthreads();
#pragma unroll
    for (int i = 0; i < 4; ++i) {
      int e = i * 256 + tid;
      int row = e >> 3, q8 = e & 7;
      char* dst = Asw + row * 128 + ((q8 ^ (row & 7)) << 4);
      if (AF32) {
        const float* src = (const float*)A + (size_t)(px0 + row) * a_rs + a_c0 + k0 + q8 * 8;
        float4 v0 = *(const float4*)src, v1 = *(const float4*)(src + 4);
        uint4 pk;
        pk.x = pk2(v0.x, v0.y); pk.y = pk2(v0.z, v0.w);
        pk.z = pk2(v1.x, v1.y); pk.w = pk2(v1.z, v1.w);
        *(uint4*)dst = pk;
      } else {
        const unsigned short* src =
            (const unsigned short*)A + (size_t)(px0 + row) * a_rs + a_c0 + k0 + q8 * 8;
        *(uint4*)dst = *(const uint4*)src;
      }
    }
#pragma unroll
    for (int i = 0; i < NF / 2; ++i) {
      int e = i * 256 + tid;
      int row = e >> 3, q8 = e & 7;
      const float* src = W + (size_t)(co0 + row) * (KC * 64) + k0 + q8 * 8;
      float4 v0 = *(const float4*)src, v1 = *(const float4*)(src + 4);
      uint4 pk;
      pk.x = pk2(v0.x, v0.y); pk.y = pk2(v0.z, v0.w);
      pk.z = pk2(v1.x, v1.y); pk.w = pk2(v1.z, v1.w);
      *(uint4*)(Bsw + row * 128 + ((q8 ^ (row & 7)) << 4)) = pk;
    }
    __syncthreads();
#pragma unroll
    for (int ks = 0; ks < 2; ++ks) {
      const int xk = (((ks * 4) + lg) ^ (lane & 7)) << 4;
      bf8_t av[2], bv[NF];
#pragma unroll
      for (int mf = 0; mf < 2; ++mf)
        av[mf] = *(const bf8_t*)(Asw + (wpx + mf * 16 + lr) * 128 + xk);
#pragma unroll
      for (int nf = 0; nf < NF; ++nf)
        bv[nf] = *(const bf8_t*)(Bsw + (nf * 16 + lr) * 128 + xk);
#pragma unroll
      for (int mf = 0; mf < 2; ++mf)
#pragma unroll
        for (int nf = 0; nf < NF; ++nf)
          acc[mf][nf] = __builtin_amdgcn_mfma_f32_16x16x32_bf16(av[mf], bv[nf], acc[mf][nf], 0, 0, 0);
    }
  }

  float bco[NF];
#pragma unroll
  for (int nf = 0; nf < NF; ++nf) bco[nf] = bias[co0 + nf * 16 + lr];

  if constexpr (EPI >= 2) {
    float gv[NF], bbv[NF];
#pragma unroll
    for (int nf = 0; nf < NF; ++nf) { gv[nf] = g[nf * 16 + lr]; bbv[nf] = bb[nf * 16 + lr]; }
#pragma unroll
    for (int mf = 0; mf < 2; ++mf)
#pragma unroll
      for (int nf = 0; nf < NF; ++nf)
#pragma unroll
        for (int r = 0; r < 4; ++r) acc[mf][nf][r] += bco[nf];
#pragma unroll
    for (int mf = 0; mf < 2; ++mf) {
#pragma unroll
      for (int r = 0; r < 4; ++r) {
        float s = 0.f, q = 0.f;
#pragma unroll
        for (int nf = 0; nf < NF; ++nf) {
          float v = acc[mf][nf][r];
          s += v; q += v * v;
        }
#pragma unroll
        for (int msk = 1; msk < 16; msk <<= 1) {
          s += __shfl_xor(s, msk);
          q += __shfl_xor(q, msk);
        }
        float mu = s * (1.0f / 128.0f);
        float var = q * (1.0f / 128.0f) - mu * mu;
        float rstd = rsqrtf(var + 1e-5f);
        int px_e = px0 + wpx + mf * 16 + lg * 4 + r;
        const float* xr = resf + (size_t)px_e * 128 + lr;
        if constexpr (EPI == 2) {
          unsigned short* op = (unsigned short*)out + (size_t)px_e * o_rs + lr;
#pragma unroll
          for (int nf = 0; nf < NF; ++nf) {
            float v = (acc[mf][nf][r] - mu) * rstd * gv[nf] + bbv[nf] + xr[nf * 16];
            op[nf * 16] = f2bf(v);
          }
        } else {
          const unsigned short* x2r = resb + (size_t)px_e * 128 + lr;
          float* op = (float*)out + (size_t)px_e * 128 + lr;
#pragma unroll
          for (int nf = 0; nf < NF; ++nf) {
            float v = (acc[mf][nf][r] - mu) * rstd * gv[nf] + bbv[nf] + xr[nf * 16] + bf2f(x2r[nf * 16]);
            op[nf * 16] = v;
          }
        }
      }
    }
  } else {
#pragma unroll
    for (int mf = 0; mf < 2; ++mf) {
#pragma unroll
      for (int r = 0; r < 4; ++r) {
        int px_e = px0 + wpx + mf * 16 + lg * 4 + r;
        size_t orow;
        int cadj = co0;
        if constexpr (OSHUF == 0) {
          orow = (size_t)px_e;
        } else if constexpr (OSHUF == 1) {
          int b = px_e >> 14, p = px_e & 16383, hh = p >> 7, w_ = p & 127;
          orow = (size_t)(b * 64 + (hh & 7) * 8 + (w_ & 7)) * 256 + ((hh >> 3) * 16 + (w_ >> 3));
        } else if constexpr (OSHUF == 2) {
          int gbb = px_e >> 8, n = px_e & 255;
          int b = gbb >> 6, ih = (gbb >> 3) & 7, iw = gbb & 7;
          orow = (size_t)b * 16384 + ((n >> 4) * 8 + ih) * 128 + (n & 15) * 8 + iw;
        } else {  // window-order: br0 = sw(shift 4), br1 = wn(shift 0)
          int brx = (co0 >= 96);
          int b = px_e >> 14, p = px_e & 16383, hh = p >> 7, w_ = p & 127;
          int sh = brx ? 0 : 4;
          int h2 = (hh - sh) & 127, w2_ = (w_ - sh) & 127;
          orow = (size_t)brx * 65536 + (size_t)b * 16384 +
                 (size_t)(((h2 >> 3) * 16 + (w2_ >> 3)) * 64 + (h2 & 7) * 8 + (w2_ & 7));
          cadj = co0 - brx * 96;
        }
        unsigned short* op = (unsigned short*)out + orow * o_rs + o_c0 + cadj + lr;
#pragma unroll
        for (int nf = 0; nf < NF; ++nf) {
          float v = acc[mf][nf][r] + bco[nf];
          if constexpr (EPI == 1) v = 0.5f * v * (1.0f + erff(v * 0.7071067811865475f));
          op[nf * 16] = f2bf(v);
        }
      }
    }
  }
}

// ---------------- MFMA grid attention (N=256, hd=16, 4 heads) --------------
__global__ __launch_bounds__(256) void gattn_k(
    const unsigned short* __restrict__ Q, int q_rs, int q_c0,
    const unsigned short* __restrict__ K, int k_rs, int k_c0,
    const unsigned short* __restrict__ V, int v_rs, int v_c0,
    const float* __restrict__ pbT, unsigned short* __restrict__ outb, int o_rs, int o_c0) {
  __shared__ __align__(16) unsigned short K_lds[256 * 16];   // [m][16d]
  __shared__ __align__(16) unsigned short Vt[16 * 264];      // [d][264m] padded
  __shared__ __align__(16) unsigned short P_lds[4 * 64 * 40];// per-wave [64q][40m]
  const int gb = blockIdx.x, h = blockIdx.y, tid = threadIdx.x;
  const int lane = tid & 63, wv = tid >> 6;
  const int lr = lane & 15, lg = lane >> 4;
  const int q0 = wv * 64;

  {
    const unsigned short* kp = K + (size_t)(gb * 256 + tid) * k_rs + k_c0 + h * 16;
    *(uint4*)&K_lds[tid * 16]     = *(const uint4*)kp;
    *(uint4*)&K_lds[tid * 16 + 8] = *(const uint4*)(kp + 8);
    const unsigned short* vp = V + (size_t)(gb * 256 + tid) * v_rs + v_c0 + h * 16;
    uint4 va = *(const uint4*)vp;
    uint4 vb = *(const uint4*)(vp + 8);
    unsigned int w8[8] = {va.x, va.y, va.z, va.w, vb.x, vb.y, vb.z, vb.w};
#pragma unroll
    for (int w = 0; w < 8; ++w) {
      Vt[(2 * w) * 264 + tid]     = (unsigned short)(w8[w] & 0xffff);
      Vt[(2 * w + 1) * 264 + tid] = (unsigned short)(w8[w] >> 16);
    }
  }
  bf8_t bq[4];
  const bf8_t bz = {0, 0, 0, 0, 0, 0, 0, 0};
#pragma unroll
  for (int qt = 0; qt < 4; ++qt) {
    bq[qt] = bz;
    if (lg < 2)
      bq[qt] = *(const bf8_t*)(Q + (size_t)(gb * 256 + q0 + qt * 16 + lr) * q_rs + q_c0 + h * 16 + lg * 8);
  }
  __syncthreads();

  const f4_t z4 = {0.f, 0.f, 0.f, 0.f};
  f4_t oacc[4];
  float mrun[4], lrun[4];
#pragma unroll
  for (int qt = 0; qt < 4; ++qt) { oacc[qt] = z4; mrun[qt] = -3e38f; lrun[qt] = 0.0f; }

  unsigned short* Pw = &P_lds[wv * 64 * 40];

  for (int m0 = 0; m0 < 256; m0 += 32) {
    bf8_t ak0 = bz, ak1 = bz;
    if (lg < 2) {
      ak0 = *(const bf8_t*)&K_lds[(m0 + lr) * 16 + lg * 8];
      ak1 = *(const bf8_t*)&K_lds[(m0 + 16 + lr) * 16 + lg * 8];
    }
    bf8_t av = *(const bf8_t*)&Vt[lr * 264 + m0 + lg * 8];

#pragma unroll
    for (int qt = 0; qt < 4; ++qt) {
      f4_t st0 = __builtin_amdgcn_mfma_f32_16x16x32_bf16(ak0, bq[qt], z4, 0, 0, 0);
      f4_t st1 = __builtin_amdgcn_mfma_f32_16x16x32_bf16(ak1, bq[qt], z4, 0, 0, 0);
      const float* bpm = pbT + ((size_t)(h * 256 + m0 + lg * 4) << 8) + q0 + qt * 16 + lr;
      float s0[4], s1[4];
#pragma unroll
      for (int r = 0; r < 4; ++r) {
        s0[r] = fmaf(st0[r], 0.25f, bpm[r * 256]);
        s1[r] = fmaf(st1[r], 0.25f, bpm[(16 + r) * 256]);
      }
      float cmax = fmaxf(fmaxf(fmaxf(s0[0], s0[1]), fmaxf(s0[2], s0[3])),
                         fmaxf(fmaxf(s1[0], s1[1]), fmaxf(s1[2], s1[3])));
      cmax = fmaxf(cmax, __shfl_xor(cmax, 16));
      cmax = fmaxf(cmax, __shfl_xor(cmax, 32));
      float newm = fmaxf(mrun[qt], cmax);
      float c = __expf(mrun[qt] - newm);
      float p0[4], p1[4], ls = 0.0f;
#pragma unroll
      for (int r = 0; r < 4; ++r) {
        p0[r] = __expf(s0[r] - newm);
        p1[r] = __expf(s1[r] - newm);
        ls += p0[r] + p1[r];
      }
      ls += __shfl_xor(ls, 16);
      ls += __shfl_xor(ls, 32);
      lrun[qt] = lrun[qt] * c + ls;
      mrun[qt] = newm;
#pragma unroll
      for (int r = 0; r < 4; ++r) oacc[qt][r] *= c;
      int row = qt * 16 + lr;
      uint2 w0 = {pk2(p0[0], p0[1]), pk2(p0[2], p0[3])};
      uint2 w1 = {pk2(p1[0], p1[1]), pk2(p1[2], p1[3])};
      *(uint2*)&Pw[row * 40 + lg * 4]      = w0;
      *(uint2*)&Pw[row * 40 + 16 + lg * 4] = w1;
    }
#pragma unroll
    for (int qt = 0; qt < 4; ++qt) {
      bf8_t bp = *(const bf8_t*)&Pw[(qt * 16 + lr) * 40 + lg * 8];
      oacc[qt] = __builtin_amdgcn_mfma_f32_16x16x32_bf16(av, bp, oacc[qt], 0, 0, 0);
    }
  }

#pragma unroll
  for (int qt = 0; qt < 4; ++qt) {
    float inv = 1.0f / lrun[qt];
    uint2 o;
    o.x = pk2(oacc[qt][0] * inv, oacc[qt][1] * inv);
    o.y = pk2(oacc[qt][2] * inv, oacc[qt][3] * inv);
    unsigned short* op = outb + (size_t)(gb * 256 + q0 + qt * 16 + lr) * o_rs + o_c0 + h * 16 + lg * 4;
    *(uint2*)op = o;
  }
}

// ---------------- MFMA swin window attention (barrier-free) ----------------
// wave = one window; 4 windows/block; grid.y = branch (0 sw/shift4, 1 wn).
// qkv2: [2][65536 rows in window order][96 ch] bf16.
// Per head: swapped QK (K-dim 8 pad 32), rpbT bias, softmax (1/l folded),
// Pt in wave-private LDS, PV with per-head V^T stage, then MFMA out-proj.
__global__ __launch_bounds__(256) void swat_k(
    const unsigned short* __restrict__ qkv2,
    const float* __restrict__ rpbT_sw, const float* __restrict__ rpbT_wn,
    const float* __restrict__ sw_pw, const float* __restrict__ sw_pb,
    const float* __restrict__ wn_pw, const float* __restrict__ wn_pb,
    unsigned short* __restrict__ yT) {
  __shared__ __align__(16) unsigned short Vt[4][8][72];
  __shared__ __align__(16) unsigned short Pt[4][64][72];
  __shared__ __align__(16) unsigned short aoT[4][64][40];
  const int tid = threadIdx.x, lane = tid & 63, wv = tid >> 6;
  const int lr = lane & 15, lg = lane >> 4;
  const int br = blockIdx.y;
  const int win = blockIdx.x * 4 + wv;
  const int b = win >> 8, wl = win & 255, wh = wl >> 4, ww = wl & 15;
  const float* rpbT = br ? rpbT_wn : rpbT_sw;
  const float* pw   = br ? wn_pw : sw_pw;
  const float* pb   = br ? wn_pb : sw_pb;
  const int shift = br ? 0 : 4;
  const int yc0 = br ? 0 : 32;
  const bool edge = (shift > 0) && (wh == 15 || ww == 15);

  const unsigned short* qw = qkv2 + (size_t)br * 65536 * 96 + (size_t)win * 64 * 96;
  const f4_t z4 = {0.f, 0.f, 0.f, 0.f};
  const bf8_t bz = {0, 0, 0, 0, 0, 0, 0, 0};

#pragma unroll 1
  for (int h = 0; h < 4; ++h) {
    // stage V^T for this head: lane = token m, 8 d-channels
    {
      uint4 v = *(const uint4*)(qw + lane * 96 + 64 + h * 8);
      Vt[wv][0][lane] = (unsigned short)(v.x);       Vt[wv][1][lane] = (unsigned short)(v.x >> 16);
      Vt[wv][2][lane] = (unsigned short)(v.y);       Vt[wv][3][lane] = (unsigned short)(v.y >> 16);
      Vt[wv][4][lane] = (unsigned short)(v.z);       Vt[wv][5][lane] = (unsigned short)(v.z >> 16);
      Vt[wv][6][lane] = (unsigned short)(v.w);       Vt[wv][7][lane] = (unsigned short)(v.w >> 16);
    }
    // Q fragments
    bf8_t bq[4];
#pragma unroll
    for (int nt = 0; nt < 4; ++nt) {
      bq[nt] = bz;
      if (lg == 0) bq[nt] = *(const bf8_t*)(qw + (nt * 16 + lr) * 96 + h * 8);
    }
    // QK: S^T tiles [mt][nt]
    f4_t st[4][4];
#pragma unroll
    for (int mt = 0; mt < 4; ++mt) {
      bf8_t ak = bz;
      if (lg == 0) ak = *(const bf8_t*)(qw + (mt * 16 + lr) * 96 + 32 + h * 8);
#pragma unroll
      for (int nt = 0; nt < 4; ++nt)
        st[mt][nt] = __builtin_amdgcn_mfma_f32_16x16x32_bf16(ak, bq[nt], z4, 0, 0, 0);
    }
    // bias + mask + softmax + pack P (per n-tile)
#pragma unroll
    for (int nt = 0; nt < 4; ++nt) {
      float sv[16];
#pragma unroll
      for (int mt = 0; mt < 4; ++mt) {
        const float* rp = rpbT + h * 4096 + (mt * 16 + lg * 4) * 64 + nt * 16 + lr;
#pragma unroll
        for (int r = 0; r < 4; ++r)
          sv[mt * 4 + r] = fmaf(st[mt][nt][r], 0.35355339059327373f, rp[r * 64]);
      }
      if (edge) {
        int n = nt * 16 + lr;
        int regn = ((wh < 15) ? 0 : (((n >> 3) < 4) ? 1 : 2)) * 3 +
                   ((ww < 15) ? 0 : (((n & 7) < 4) ? 1 : 2));
#pragma unroll
        for (int mt = 0; mt < 4; ++mt)
#pragma unroll
          for (int r = 0; r < 4; ++r) {
            int m = mt * 16 + lg * 4 + r;
            int regm = ((wh < 15) ? 0 : (((m >> 3) < 4) ? 1 : 2)) * 3 +
                       ((ww < 15) ? 0 : (((m & 7) < 4) ? 1 : 2));
            if (regm != regn) sv[mt * 4 + r] -= 100.0f;
          }
      }
      float mx = sv[0];
#pragma unroll
      for (int i = 1; i < 16; ++i) mx = fmaxf(mx, sv[i]);
      mx = fmaxf(mx, __shfl_xor(mx, 16));
      mx = fmaxf(mx, __shfl_xor(mx, 32));
      float l = 0.0f;
#pragma unroll
      for (int i = 0; i < 16; ++i) {
        sv[i] = __expf(sv[i] - mx);
        l += sv[i];
      }
      l += __shfl_xor(l, 16);
      l += __shfl_xor(l, 32);
      float inv = 1.0f / l;
#pragma unroll
      for (int mt = 0; mt < 4; ++mt) {
        uint2 w = {pk2(sv[mt * 4] * inv, sv[mt * 4 + 1] * inv),
                   pk2(sv[mt * 4 + 2] * inv, sv[mt * 4 + 3] * inv)};
        *(uint2*)&Pt[wv][nt * 16 + lr][mt * 16 + lg * 4] = w;
      }
    }
    // PV: O^T[d][n] tiles over n
    f4_t oa[4] = {z4, z4, z4, z4};
#pragma unroll
    for (int ks = 0; ks < 2; ++ks) {
      bf8_t av = bz;
      if (lr < 8) av = *(const bf8_t*)&Vt[wv][lr][ks * 32 + lg * 8];
#pragma unroll
      for (int nt = 0; nt < 4; ++nt) {
        bf8_t bp = *(const bf8_t*)&Pt[wv][nt * 16 + lr][ks * 32 + lg * 8];
        oa[nt] = __builtin_amdgcn_mfma_f32_16x16x32_bf16(av, bp, oa[nt], 0, 0, 0);
      }
    }
    if (lg < 2) {
#pragma unroll
      for (int nt = 0; nt < 4; ++nt) {
        uint2 w = {pk2(oa[nt][0], oa[nt][1]), pk2(oa[nt][2], oa[nt][3])};
        *(uint2*)&aoT[wv][nt * 16 + lr][h * 8 + lg * 4] = w;
      }
    }
  }

  // out projection: out^T[co][n] = pw[co][ci] * ao^T[ci][n]
#pragma unroll
  for (int mt = 0; mt < 2; ++mt) {
    const float* wr = pw + (mt * 16 + lr) * 32 + lg * 8;
    float4 a0 = *(const float4*)wr, a1 = *(const float4*)(wr + 4);
    union { uint4 u; bf8_t v; } aw;
    aw.u.x = pk2(a0.x, a0.y); aw.u.y = pk2(a0.z, a0.w);
    aw.u.z = pk2(a1.x, a1.y); aw.u.w = pk2(a1.z, a1.w);
    float pb0 = pb[mt * 16 + lg * 4], pb1 = pb[mt * 16 + lg * 4 + 1];
    float pb2 = pb[mt * 16 + lg * 4 + 2], pb3 = pb[mt * 16 + lg * 4 + 3];
#pragma unroll
    for (int nt = 0; nt < 4; ++nt) {
      bf8_t bo = *(const bf8_t*)&aoT[wv][nt * 16 + lr][lg * 8];
      f4_t po = __builtin_amdgcn_mfma_f32_16x16x32_bf16(aw.v, bo, z4, 0, 0, 0);
      int n = nt * 16 + lr;
      int hdst = (wh * 8 + (n >> 3) + shift) & 127;
      int wdst = (ww * 8 + (n & 7) + shift) & 127;
      uint2 w = {pk2(po[0] + pb0, po[1] + pb1), pk2(po[2] + pb2, po[3] + pb3)};
      *(uint2*)(yT + ((size_t)(b * 16384 + hdst * 128 + wdst)) * 128 + yc0 + mt * 16 + lg * 4) = w;
    }
  }
}

// ---------------------------------------------------------------------------
extern "C" void kernel_launch(void* const* d_in, const int* in_sizes, int n_in,
                              void* d_out, int out_size, void* d_ws, size_t ws_size,
                              hipStream_t stream) {
  (void)in_sizes; (void)n_in; (void)out_size; (void)ws_size;
  const float* x        = (const float*)d_in[0];
  const float* ln_g     = (const float*)d_in[1];
  const float* ln_b     = (const float*)d_in[2];
  const float* ga_qkv_w = (const float*)d_in[3];
  const float* ga_qkv_b = (const float*)d_in[4];
  const float* ga_gp_w  = (const float*)d_in[5];
  const float* ga_gp_b  = (const float*)d_in[6];
  const float* pos_w1   = (const float*)d_in[7];
  const float* pos_b1   = (const float*)d_in[8];
  const float* pos_w2   = (const float*)d_in[9];
  const float* pos_b2   = (const float*)d_in[10];
  const float* pos_w3   = (const float*)d_in[11];
  const float* pos_b3   = (const float*)d_in[12];
  const float* a1_pw    = (const float*)d_in[13];
  const float* a1_pb    = (const float*)d_in[14];
  const float* a2_pw    = (const float*)d_in[15];
  const float* a2_pb    = (const float*)d_in[16];
  const float* sw_qkv_w = (const float*)d_in[17];
  const float* sw_qkv_b = (const float*)d_in[18];
  const float* sw_rpb   = (const float*)d_in[19];
  const float* sw_pw    = (const float*)d_in[20];
  const float* sw_pb    = (const float*)d_in[21];
  const float* wn_qkv_w = (const float*)d_in[22];
  const float* wn_qkv_b = (const float*)d_in[23];
  const float* wn_rpb   = (const float*)d_in[24];
  const float* wn_pw    = (const float*)d_in[25];
  const float* wn_pb    = (const float*)d_in[26];
  const float* fc_w     = (const float*)d_in[27];
  const float* fc_b     = (const float*)d_in[28];
  const float* n2_g     = (const float*)d_in[29];
  const float* n2_b     = (const float*)d_in[30];
  const float* m1_w     = (const float*)d_in[31];
  const float* m1_b     = (const float*)d_in[32];
  const float* m2_w     = (const float*)d_in[33];
  const float* m2_b     = (const float*)d_in[34];
  float* out = (float*)d_out;
  char* base = (char*)d_ws;

  float*          xTf    = (float*)(base);                    // 32 MB
  unsigned short* qkvT   = (unsigned short*)(base + 32 * MB); // 24 MB (dead after gattn2)
  unsigned short* xgridT = (unsigned short*)(base + 56 * MB); //  8 MB
  unsigned short* t1T    = (unsigned short*)(base + 64 * MB); //  8 MB
  unsigned short* t1pT   = (unsigned short*)(base + 72 * MB); //  8 MB
  unsigned short* yT     = (unsigned short*)(base + 80 * MB); // 16 MB
  unsigned short* x2T    = (unsigned short*)(base + 96 * MB); // 16 MB
  unsigned short* qkv2   = (unsigned short*)(base + 32 * MB); // 24 MB alias (after gattn2)
  unsigned short* hT     = (unsigned short*)(base + 32 * MB); // 32 MB alias (after swat)
  float*          outT   = (float*)(base + 64 * MB);          // alias
  float*          pbT    = (float*)(base + 112 * MB);         //  1 MB
  float*          ptab   = (float*)(base + 113 * MB);         // 16 KB
  float*          rpbT_sw= (float*)(base + 113 * MB + 65536); // 64 KB
  float*          rpbT_wn= (float*)(base + 113 * MB + 131072);// 64 KB
  float*          wqkv2  = (float*)(base + 113 * MB + 196608);// 48 KB
  float*          bias192= (float*)(base + 113 * MB + 262144);// 768 B

  pos_mlp_k<<<4, 256, 0, stream>>>(pos_w1, pos_b1, pos_w2, pos_b2, pos_w3, pos_b3, ptab);
  pbT_gather_k<<<1024, 256, 0, stream>>>(ptab, pbT);
  rpbT_k<<<64, 256, 0, stream>>>(sw_rpb, rpbT_sw);
  rpbT_k<<<64, 256, 0, stream>>>(wn_rpb, rpbT_wn);
  wq2_k<<<48, 256, 0, stream>>>(sw_qkv_w, sw_qkv_b, wn_qkv_w, wn_qkv_b, wqkv2, bias192);

  tin_k<<<dim3(256, 1, 4), 256, 0, stream>>>(x, xTf);

  // grid branch
  gemm_k<4, 1, 1, 0, 1><<<dim3(512, 3, 1), 256, 0, stream>>>(
      xTf, 128, 0, ga_qkv_w, ga_qkv_b, nullptr, nullptr, nullptr, nullptr, qkvT, 192, 0);
  gemm_k<4, 1, 1, 0, 1><<<dim3(512, 1, 1), 256, 0, stream>>>(
      xTf, 128, 0, ga_gp_w, ga_gp_b, nullptr, nullptr, nullptr, nullptr, xgridT, 64, 0);

  gattn_k<<<dim3(256, 4), 256, 0, stream>>>(
      xgridT, 64, 0, qkvT, 192, 64, qkvT, 192, 128, pbT, t1T, 64, 0);
  gemm_k<4, 1, 0, 0, 0><<<dim3(512, 1, 1), 256, 0, stream>>>(
      t1T, 64, 0, a1_pw, a1_pb, nullptr, nullptr, nullptr, nullptr, t1pT, 64, 0);

  gattn_k<<<dim3(256, 4), 256, 0, stream>>>(
      qkvT, 192, 0, xgridT, 64, 0, t1pT, 64, 0, pbT, t1T, 64, 0);
  gemm_k<4, 1, 0, 0, 2><<<dim3(512, 1, 1), 256, 0, stream>>>(
      t1T, 64, 0, a2_pw, a2_pb, nullptr, nullptr, nullptr, nullptr, yT, 128, 64);

  // window branches: qkv GEMM (window-ordered) + MFMA attention
  gemm_k<6, 1, 1, 0, 3><<<dim3(512, 2, 1), 256, 0, stream>>>(
      xTf, 128, 64, wqkv2, bias192, nullptr, nullptr, nullptr, nullptr, qkv2, 96, 0);
  swat_k<<<dim3(256, 2), 256, 0, stream>>>(
      qkv2, rpbT_sw, rpbT_wn, sw_pw, sw_pb, wn_pw, wn_pb, yT);

  gemm_k<8, 2, 0, 2, 0><<<dim3(512, 1, 1), 256, 0, stream>>>(
      yT, 128, 0, fc_w, fc_b, ln_g, ln_b, xTf, nullptr, x2T, 128, 0);

  gemm_k<8, 2, 0, 1, 0><<<dim3(512, 2, 1), 256, 0, stream>>>(
      x2T, 128, 0, m1_w, m1_b, nullptr, nullptr, nullptr, nullptr, hT, 256, 0);
  gemm_k<8, 4, 0, 3, 0><<<dim3(512, 1, 1), 256, 0, stream>>>(
      hT, 256, 0, m2_w, m2_b, n2_g, n2_b, xTf, x2T, outT, 128, 0);

  tout_k<<<dim3(256, 1, 4), 256, 0, stream>>>(outT, out);
}

// Round 8
// 225.659 us; speedup vs baseline: 1.7428x; 1.0405x over previous
//
#include <hip/hip_runtime.h>
#include <hip/hip_bf16.h>
#include <cstdint>

// ---------------------------------------------------------------------------
// GABlock, channel-last bf16-MFMA pipeline.
// R8: v_cvt_pk_bf16_f32 for all hot bf16 packing; XOR chunk-swizzled LDS in
//     gattn/swat (bank-BW floor); weights pre-converted to bf16 once.
// ---------------------------------------------------------------------------

typedef __attribute__((ext_vector_type(8))) short bf8_t;   // 8 bf16 (4 VGPR)
typedef __attribute__((ext_vector_type(4))) float f4_t;    // 4 f32 acc

__device__ __forceinline__ float bf2f(unsigned short u) {
  union { unsigned int i; float f; } x; x.i = ((unsigned int)u) << 16; return x.f;
}
__device__ __forceinline__ unsigned short f2bf(float f) {
  union { float f; unsigned int i; } x; x.f = f;
  unsigned int r = x.i + 0x7FFFu + ((x.i >> 16) & 1u);
  return (unsigned short)(r >> 16);
}
// HW packed f32x2 -> bf16x2 (RNE). Non-volatile: scheduler may reorder.
__device__ __forceinline__ unsigned int pk2(float a, float b) {
  unsigned int d;
  asm("v_cvt_pk_bf16_f32 %0, %1, %2" : "=v"(d) : "v"(a), "v"(b));
  return d;
}

#define MB (1048576L)

// ---------------- dynamic position bias MLP --------------------------------
__global__ void pos_mlp_k(const float* __restrict__ w1, const float* __restrict__ b1,
                          const float* __restrict__ w2, const float* __restrict__ b2,
                          const float* __restrict__ w3, const float* __restrict__ b3,
                          float* __restrict__ table) {
  int j = blockIdx.x * 256 + threadIdx.x;
  if (j >= 961) return;
  float chv = (float)(j / 31) - 15.0f;
  float cwv = (float)(j % 31) - 15.0f;
  float t1[16], t2[16];
#pragma unroll
  for (int i = 0; i < 16; ++i) {
    float s = fmaf(w1[i * 2], chv, fmaf(w1[i * 2 + 1], cwv, b1[i]));
    t1[i] = fmaxf(s, 0.0f);
  }
#pragma unroll
  for (int i = 0; i < 16; ++i) {
    float s = b2[i];
#pragma unroll
    for (int k = 0; k < 16; ++k) s = fmaf(w2[i * 16 + k], t1[k], s);
    t2[i] = fmaxf(s, 0.0f);
  }
#pragma unroll
  for (int hh = 0; hh < 4; ++hh) {
    float s = b3[hh];
#pragma unroll
    for (int k = 0; k < 16; ++k) s = fmaf(w3[hh * 16 + k], t2[k], s);
    table[j * 4 + hh] = s;
  }
}

// pbT[h][m][q] = bias for query q, key m
__global__ void pbT_gather_k(const float* __restrict__ table, float* __restrict__ pbT) {
  int t = blockIdx.x * 256 + threadIdx.x;   // 4*256*256
  int hh = t >> 16;
  int r = t & 65535;
  int m = r >> 8;
  int q = r & 255;
  int idx = ((q >> 4) - (m >> 4) + 15) * 31 + ((q & 15) - (m & 15) + 15);
  pbT[t] = table[idx * 4 + hh];
}

// rpbT[h][m][n] = rpb[idx(n,m)][h]
__global__ void rpbT_k(const float* __restrict__ rpb, float* __restrict__ rpbT) {
  int t = blockIdx.x * 256 + threadIdx.x;  // 16384
  int h = t >> 12, r = t & 4095, m = r >> 6, n = r & 63;
  int idx = ((n >> 3) - (m >> 3) + 7) * 15 + ((n & 7) - (m & 7) + 7);
  rpbT[t] = rpb[idx * 4 + h];
}

// block-diagonal 192x64 qkv weight (bf16) + 192 bias for both window branches
__global__ void wq2_k(const float* __restrict__ sw_w, const float* __restrict__ sw_b,
                      const float* __restrict__ wn_w, const float* __restrict__ wn_b,
                      unsigned short* __restrict__ w2, float* __restrict__ b2) {
  int t = blockIdx.x * 256 + threadIdx.x;   // 12288
  if (t < 12288) {
    int row = t >> 6, col = t & 63;
    float v = 0.0f;
    if (row < 96) { if (col < 32) v = sw_w[row * 32 + col]; }
    else          { if (col >= 32) v = wn_w[(row - 96) * 32 + col - 32]; }
    w2[t] = f2bf(v);
  }
  if (t < 192) b2[t] = t < 96 ? sw_b[t] : wn_b[t - 96];
}

// all GEMM weights -> bf16, one pass. layout offsets (elements):
// 0 ga_qkv(12288) | 12288 ga_gp(4096) | 16384 a1(4096) | 20480 a2(4096)
// 24576 fc(16384) | 40960 m1(32768) | 73728 m2(32768)   total 106496
__global__ void wcvt_k(const float* __restrict__ w0, const float* __restrict__ w1,
                       const float* __restrict__ w2, const float* __restrict__ w3,
                       const float* __restrict__ w4, const float* __restrict__ w5,
                       const float* __restrict__ w6, unsigned short* __restrict__ dst) {
  int t = blockIdx.x * 256 + threadIdx.x;
  if (t >= 106496) return;
  const float* src; int off;
  if (t < 12288)      { src = w0; off = 0; }
  else if (t < 16384) { src = w1; off = 12288; }
  else if (t < 20480) { src = w2; off = 16384; }
  else if (t < 24576) { src = w3; off = 20480; }
  else if (t < 40960) { src = w4; off = 24576; }
  else if (t < 73728) { src = w5; off = 40960; }
  else                { src = w6; off = 73728; }
  dst[t] = f2bf(src[t - off]);
}

// ---------------- NCHW fp32 -> channel-last fp32 (and back) ----------------
__global__ __launch_bounds__(256) void tin_k(const float* __restrict__ x,
                                             float* __restrict__ xTf) {
  __shared__ float tile[64][132];
  const int b = blockIdx.z, px0 = blockIdx.x * 64, tid = threadIdx.x;
#pragma unroll
  for (int i = 0; i < 8; ++i) {
    int e = i * 256 + tid;
    int c = e >> 4, p4 = (e & 15) * 4;
    float4 v = *(const float4*)(x + (((size_t)(b * 128 + c)) << 14) + px0 + p4);
    tile[p4][c] = v.x; tile[p4 + 1][c] = v.y; tile[p4 + 2][c] = v.z; tile[p4 + 3][c] = v.w;
  }
  __syncthreads();
#pragma unroll
  for (int i = 0; i < 8; ++i) {
    int e = i * 256 + tid;
    int px = e >> 5, c4 = (e & 31) * 4;
    float4 v = make_float4(tile[px][c4], tile[px][c4 + 1], tile[px][c4 + 2], tile[px][c4 + 3]);
    *(float4*)(xTf + ((size_t)(b * 16384 + px0 + px)) * 128 + c4) = v;
  }
}

__global__ __launch_bounds__(256) void tout_k(const float* __restrict__ outT,
                                              float* __restrict__ out) {
  __shared__ float tile[64][132];
  const int b = blockIdx.z, px0 = blockIdx.x * 64, tid = threadIdx.x;
#pragma unroll
  for (int i = 0; i < 8; ++i) {
    int e = i * 256 + tid;
    int px = e >> 5, c4 = (e & 31) * 4;
    float4 v = *(const float4*)(outT + ((size_t)(b * 16384 + px0 + px)) * 128 + c4);
    tile[px][c4] = v.x; tile[px][c4 + 1] = v.y; tile[px][c4 + 2] = v.z; tile[px][c4 + 3] = v.w;
  }
  __syncthreads();
#pragma unroll
  for (int i = 0; i < 8; ++i) {
    int e = i * 256 + tid;
    int c = e >> 4, p4 = (e & 15) * 4;
    float4 v = make_float4(tile[p4][c], tile[p4 + 1][c], tile[p4 + 2][c], tile[p4 + 3][c]);
    *(float4*)(out + (((size_t)(b * 128 + c)) << 14) + px0 + p4) = v;
  }
}

// ---------------- generic bf16-MFMA GEMM (W pre-converted bf16) ------------
template <int NF, int KC, int AF32, int EPI, int OSHUF>
__global__ __launch_bounds__(256) void gemm_k(
    const void* __restrict__ A, int a_rs, int a_c0,
    const unsigned short* __restrict__ W, const float* __restrict__ bias,
    const float* __restrict__ g, const float* __restrict__ bb,
    const float* __restrict__ resf, const unsigned short* __restrict__ resb,
    void* __restrict__ out, int o_rs, int o_c0) {
  __shared__ __align__(16) char Asw[128 * 128];
  __shared__ __align__(16) char Bsw[NF * 16 * 128];
  const int tid = threadIdx.x;
  const int lane = tid & 63, wv = tid >> 6, wpx = wv * 32;
  const int lr = lane & 15, lg = lane >> 4;
  const int px0 = blockIdx.x * 128;
  const int co0 = blockIdx.y * (NF * 16);

  f4_t acc[2][NF];
#pragma unroll
  for (int mf = 0; mf < 2; ++mf)
#pragma unroll
    for (int nf = 0; nf < NF; ++nf) acc[mf][nf] = (f4_t){0.f, 0.f, 0.f, 0.f};

  for (int kc = 0; kc < KC; ++kc) {
    const int k0 = kc * 64;
    if (kc) __syncthreads();
#pragma unroll
    for (int i = 0; i < 4; ++i) {
      int e = i * 256 + tid;
      int row = e >> 3, q8 = e & 7;
      char* dst = Asw + row * 128 + ((q8 ^ (row & 7)) << 4);
      if (AF32) {
        const float* src = (const float*)A + (size_t)(px0 + row) * a_rs + a_c0 + k0 + q8 * 8;
        float4 v0 = *(const float4*)src, v1 = *(const float4*)(src + 4);
        uint4 pk;
        pk.x = pk2(v0.x, v0.y); pk.y = pk2(v0.z, v0.w);
        pk.z = pk2(v1.x, v1.y); pk.w = pk2(v1.z, v1.w);
        *(uint4*)dst = pk;
      } else {
        const unsigned short* src =
            (const unsigned short*)A + (size_t)(px0 + row) * a_rs + a_c0 + k0 + q8 * 8;
        *(uint4*)dst = *(const uint4*)src;
      }
    }
#pragma unroll
    for (int i = 0; i < NF / 2; ++i) {
      int e = i * 256 + tid;
      int row = e >> 3, q8 = e & 7;
      const unsigned short* src = W + (size_t)(co0 + row) * (KC * 64) + k0 + q8 * 8;
      *(uint4*)(Bsw + row * 128 + ((q8 ^ (row & 7)) << 4)) = *(const uint4*)src;
    }
    __syncthreads();
#pragma unroll
    for (int ks = 0; ks < 2; ++ks) {
      const int xk = (((ks * 4) + lg) ^ (lane & 7)) << 4;
      bf8_t av[2], bv[NF];
#pragma unroll
      for (int mf = 0; mf < 2; ++mf)
        av[mf] = *(const bf8_t*)(Asw + (wpx + mf * 16 + lr) * 128 + xk);
#pragma unroll
      for (int nf = 0; nf < NF; ++nf)
        bv[nf] = *(const bf8_t*)(Bsw + (nf * 16 + lr) * 128 + xk);
#pragma unroll
      for (int mf = 0; mf < 2; ++mf)
#pragma unroll
        for (int nf = 0; nf < NF; ++nf)
          acc[mf][nf] = __builtin_amdgcn_mfma_f32_16x16x32_bf16(av[mf], bv[nf], acc[mf][nf], 0, 0, 0);
    }
  }

  float bco[NF];
#pragma unroll
  for (int nf = 0; nf < NF; ++nf) bco[nf] = bias[co0 + nf * 16 + lr];

  if constexpr (EPI >= 2) {
    float gv[NF], bbv[NF];
#pragma unroll
    for (int nf = 0; nf < NF; ++nf) { gv[nf] = g[nf * 16 + lr]; bbv[nf] = bb[nf * 16 + lr]; }
#pragma unroll
    for (int mf = 0; mf < 2; ++mf)
#pragma unroll
      for (int nf = 0; nf < NF; ++nf)
#pragma unroll
        for (int r = 0; r < 4; ++r) acc[mf][nf][r] += bco[nf];
#pragma unroll
    for (int mf = 0; mf < 2; ++mf) {
#pragma unroll
      for (int r = 0; r < 4; ++r) {
        float s = 0.f, q = 0.f;
#pragma unroll
        for (int nf = 0; nf < NF; ++nf) {
          float v = acc[mf][nf][r];
          s += v; q += v * v;
        }
#pragma unroll
        for (int msk = 1; msk < 16; msk <<= 1) {
          s += __shfl_xor(s, msk);
          q += __shfl_xor(q, msk);
        }
        float mu = s * (1.0f / 128.0f);
        float var = q * (1.0f / 128.0f) - mu * mu;
        float rstd = rsqrtf(var + 1e-5f);
        int px_e = px0 + wpx + mf * 16 + lg * 4 + r;
        const float* xr = resf + (size_t)px_e * 128 + lr;
        if constexpr (EPI == 2) {
          unsigned short* op = (unsigned short*)out + (size_t)px_e * o_rs + lr;
#pragma unroll
          for (int nf = 0; nf < NF; ++nf) {
            float v = (acc[mf][nf][r] - mu) * rstd * gv[nf] + bbv[nf] + xr[nf * 16];
            op[nf * 16] = f2bf(v);
          }
        } else {
          const unsigned short* x2r = resb + (size_t)px_e * 128 + lr;
          float* op = (float*)out + (size_t)px_e * 128 + lr;
#pragma unroll
          for (int nf = 0; nf < NF; ++nf) {
            float v = (acc[mf][nf][r] - mu) * rstd * gv[nf] + bbv[nf] + xr[nf * 16] + bf2f(x2r[nf * 16]);
            op[nf * 16] = v;
          }
        }
      }
    }
  } else {
#pragma unroll
    for (int mf = 0; mf < 2; ++mf) {
#pragma unroll
      for (int r = 0; r < 4; ++r) {
        int px_e = px0 + wpx + mf * 16 + lg * 4 + r;
        size_t orow;
        int cadj = co0;
        if constexpr (OSHUF == 0) {
          orow = (size_t)px_e;
        } else if constexpr (OSHUF == 1) {
          int b = px_e >> 14, p = px_e & 16383, hh = p >> 7, w_ = p & 127;
          orow = (size_t)(b * 64 + (hh & 7) * 8 + (w_ & 7)) * 256 + ((hh >> 3) * 16 + (w_ >> 3));
        } else if constexpr (OSHUF == 2) {
          int gbb = px_e >> 8, n = px_e & 255;
          int b = gbb >> 6, ih = (gbb >> 3) & 7, iw = gbb & 7;
          orow = (size_t)b * 16384 + ((n >> 4) * 8 + ih) * 128 + (n & 15) * 8 + iw;
        } else {  // window-order: br0 = sw(shift 4), br1 = wn(shift 0)
          int brx = (co0 >= 96);
          int b = px_e >> 14, p = px_e & 16383, hh = p >> 7, w_ = p & 127;
          int sh = brx ? 0 : 4;
          int h2 = (hh - sh) & 127, w2_ = (w_ - sh) & 127;
          orow = (size_t)brx * 65536 + (size_t)b * 16384 +
                 (size_t)(((h2 >> 3) * 16 + (w2_ >> 3)) * 64 + (h2 & 7) * 8 + (w2_ & 7));
          cadj = co0 - brx * 96;
        }
        unsigned short* op = (unsigned short*)out + orow * o_rs + o_c0 + cadj + lr;
#pragma unroll
        for (int nf = 0; nf < NF; ++nf) {
          float v = acc[mf][nf][r] + bco[nf];
          if constexpr (EPI == 1) v = 0.5f * v * (1.0f + erff(v * 0.7071067811865475f));
          op[nf * 16] = f2bf(v);
        }
      }
    }
  }
}

// ---------------- MFMA grid attention (N=256, hd=16, 4 heads) --------------
// LDS: K[m][16d] (32B rows, 32-lane reads BW-bound); Vt/P XOR chunk-swizzled.
__global__ __launch_bounds__(256) void gattn_k(
    const unsigned short* __restrict__ Q, int q_rs, int q_c0,
    const unsigned short* __restrict__ K, int k_rs, int k_c0,
    const unsigned short* __restrict__ V, int v_rs, int v_c0,
    const float* __restrict__ pbT, unsigned short* __restrict__ outb, int o_rs, int o_c0) {
  __shared__ __align__(16) unsigned short K_lds[256 * 16];   // 8 KB
  __shared__ __align__(16) unsigned short Vt[16 * 256];      // 8 KB, swz [d][m]
  __shared__ __align__(16) unsigned short P_lds[4 * 64 * 32];// 16 KB, per-wave swz [q][m]
  const int gb = blockIdx.x, h = blockIdx.y, tid = threadIdx.x;
  const int lane = tid & 63, wv = tid >> 6;
  const int lr = lane & 15, lg = lane >> 4;
  const int q0 = wv * 64;

  {
    const unsigned short* kp = K + (size_t)(gb * 256 + tid) * k_rs + k_c0 + h * 16;
    *(uint4*)&K_lds[tid * 16]     = *(const uint4*)kp;
    *(uint4*)&K_lds[tid * 16 + 8] = *(const uint4*)(kp + 8);
    const unsigned short* vp = V + (size_t)(gb * 256 + tid) * v_rs + v_c0 + h * 16;
    uint4 va = *(const uint4*)vp;
    uint4 vb = *(const uint4*)(vp + 8);
    unsigned int w8[8] = {va.x, va.y, va.z, va.w, vb.x, vb.y, vb.z, vb.w};
    int chb = (tid >> 3);        // m-chunk
    int wi = tid & 7;
#pragma unroll
    for (int w = 0; w < 8; ++w) {
      int d0 = 2 * w, d1 = 2 * w + 1;
      Vt[d0 * 256 + ((chb ^ (d0 & 7)) << 3) + wi] = (unsigned short)(w8[w] & 0xffff);
      Vt[d1 * 256 + ((chb ^ (d1 & 7)) << 3) + wi] = (unsigned short)(w8[w] >> 16);
    }
  }
  bf8_t bq[4];
  const bf8_t bz = {0, 0, 0, 0, 0, 0, 0, 0};
#pragma unroll
  for (int qt = 0; qt < 4; ++qt) {
    bq[qt] = bz;
    if (lg < 2)
      bq[qt] = *(const bf8_t*)(Q + (size_t)(gb * 256 + q0 + qt * 16 + lr) * q_rs + q_c0 + h * 16 + lg * 8);
  }
  __syncthreads();

  const f4_t z4 = {0.f, 0.f, 0.f, 0.f};
  f4_t oacc[4];
  float mrun[4], lrun[4];
#pragma unroll
  for (int qt = 0; qt < 4; ++qt) { oacc[qt] = z4; mrun[qt] = -3e38f; lrun[qt] = 0.0f; }

  unsigned short* Pw = &P_lds[wv * 64 * 32];

  for (int m0 = 0; m0 < 256; m0 += 32) {
    bf8_t ak0 = bz, ak1 = bz;
    if (lg < 2) {
      ak0 = *(const bf8_t*)&K_lds[(m0 + lr) * 16 + lg * 8];
      ak1 = *(const bf8_t*)&K_lds[(m0 + 16 + lr) * 16 + lg * 8];
    }
    // V^T frag: d=lr, m = m0+lg*8  (swz chunk)
    bf8_t av = *(const bf8_t*)&Vt[lr * 256 + ((((m0 >> 3) + lg) ^ (lr & 7)) << 3)];

#pragma unroll
    for (int qt = 0; qt < 4; ++qt) {
      f4_t st0 = __builtin_amdgcn_mfma_f32_16x16x32_bf16(ak0, bq[qt], z4, 0, 0, 0);
      f4_t st1 = __builtin_amdgcn_mfma_f32_16x16x32_bf16(ak1, bq[qt], z4, 0, 0, 0);
      const float* bpm = pbT + ((size_t)(h * 256 + m0 + lg * 4) << 8) + q0 + qt * 16 + lr;
      float s0[4], s1[4];
#pragma unroll
      for (int r = 0; r < 4; ++r) {
        s0[r] = fmaf(st0[r], 0.25f, bpm[r * 256]);
        s1[r] = fmaf(st1[r], 0.25f, bpm[(16 + r) * 256]);
      }
      float cmax = fmaxf(fmaxf(fmaxf(s0[0], s0[1]), fmaxf(s0[2], s0[3])),
                         fmaxf(fmaxf(s1[0], s1[1]), fmaxf(s1[2], s1[3])));
      cmax = fmaxf(cmax, __shfl_xor(cmax, 16));
      cmax = fmaxf(cmax, __shfl_xor(cmax, 32));
      float newm = fmaxf(mrun[qt], cmax);
      float c = __expf(mrun[qt] - newm);
      float p0[4], p1[4], ls = 0.0f;
#pragma unroll
      for (int r = 0; r < 4; ++r) {
        p0[r] = __expf(s0[r] - newm);
        p1[r] = __expf(s1[r] - newm);
        ls += p0[r] + p1[r];
      }
      ls += __shfl_xor(ls, 16);
      ls += __shfl_xor(ls, 32);
      lrun[qt] = lrun[qt] * c + ls;
      mrun[qt] = newm;
#pragma unroll
      for (int r = 0; r < 4; ++r) oacc[qt][r] *= c;
      // P pack -> swizzled wave-private LDS: row q, m-chunks (lg>>1) / 2+(lg>>1)
      int row = qt * 16 + lr;
      int rw3 = row & 3;
      uint2 w0 = {pk2(p0[0], p0[1]), pk2(p0[2], p0[3])};
      uint2 w1 = {pk2(p1[0], p1[1]), pk2(p1[2], p1[3])};
      *(uint2*)&Pw[row * 32 + ((((lg >> 1)) ^ rw3) << 3) + (lg & 1) * 4]     = w0;
      *(uint2*)&Pw[row * 32 + (((2 + (lg >> 1)) ^ rw3) << 3) + (lg & 1) * 4] = w1;
    }
#pragma unroll
    for (int qt = 0; qt < 4; ++qt) {
      int row = qt * 16 + lr;
      bf8_t bp = *(const bf8_t*)&Pw[row * 32 + ((lg ^ (row & 3)) << 3)];
      oacc[qt] = __builtin_amdgcn_mfma_f32_16x16x32_bf16(av, bp, oacc[qt], 0, 0, 0);
    }
  }

#pragma unroll
  for (int qt = 0; qt < 4; ++qt) {
    float inv = 1.0f / lrun[qt];
    uint2 o;
    o.x = pk2(oacc[qt][0] * inv, oacc[qt][1] * inv);
    o.y = pk2(oacc[qt][2] * inv, oacc[qt][3] * inv);
    unsigned short* op = outb + (size_t)(gb * 256 + q0 + qt * 16 + lr) * o_rs + o_c0 + h * 16 + lg * 4;
    *(uint2*)op = o;
  }
}

// ---------------- MFMA swin window attention (barrier-free) ----------------
// wave = one window; 4 windows/block; grid.y = branch. XOR-swizzled LDS.
__global__ __launch_bounds__(256) void swat_k(
    const unsigned short* __restrict__ qkv2,
    const float* __restrict__ rpbT_sw, const float* __restrict__ rpbT_wn,
    const float* __restrict__ sw_pw, const float* __restrict__ sw_pb,
    const float* __restrict__ wn_pw, const float* __restrict__ wn_pb,
    unsigned short* __restrict__ yT) {
  __shared__ __align__(16) unsigned short Vt[4 * 8 * 64];    // 4 KB, swz [d][m]
  __shared__ __align__(16) unsigned short Pt[4 * 64 * 64];   // 32 KB, swz [q][m]
  __shared__ __align__(16) unsigned short aoT[4 * 64 * 32];  // 16 KB, swz [n][ch]
  const int tid = threadIdx.x, lane = tid & 63, wv = tid >> 6;
  const int lr = lane & 15, lg = lane >> 4;
  const int br = blockIdx.y;
  const int win = blockIdx.x * 4 + wv;
  const int b = win >> 8, wl = win & 255, wh = wl >> 4, ww = wl & 15;
  const float* rpbT = br ? rpbT_wn : rpbT_sw;
  const float* pw   = br ? wn_pw : sw_pw;
  const float* pb   = br ? wn_pb : sw_pb;
  const int shift = br ? 0 : 4;
  const int yc0 = br ? 0 : 32;
  const bool edge = (shift > 0) && (wh == 15 || ww == 15);

  const unsigned short* qw = qkv2 + (size_t)br * 65536 * 96 + (size_t)win * 64 * 96;
  const f4_t z4 = {0.f, 0.f, 0.f, 0.f};
  const bf8_t bz = {0, 0, 0, 0, 0, 0, 0, 0};
  unsigned short* Vw = &Vt[wv * 8 * 64];
  unsigned short* Pw = &Pt[wv * 64 * 64];
  unsigned short* aw_ = &aoT[wv * 64 * 32];

#pragma unroll 1
  for (int h = 0; h < 4; ++h) {
    {  // stage V^T (swz): lane = token m, 8 d-channels
      uint4 v = *(const uint4*)(qw + lane * 96 + 64 + h * 8);
      unsigned int w4[4] = {v.x, v.y, v.z, v.w};
      int chb = lane >> 3, wi = lane & 7;
#pragma unroll
      for (int j = 0; j < 4; ++j) {
        int d0 = 2 * j, d1 = 2 * j + 1;
        Vw[d0 * 64 + ((chb ^ (d0 & 7)) << 3) + wi] = (unsigned short)(w4[j] & 0xffff);
        Vw[d1 * 64 + ((chb ^ (d1 & 7)) << 3) + wi] = (unsigned short)(w4[j] >> 16);
      }
    }
    bf8_t bq[4];
#pragma unroll
    for (int nt = 0; nt < 4; ++nt) {
      bq[nt] = bz;
      if (lg == 0) bq[nt] = *(const bf8_t*)(qw + (nt * 16 + lr) * 96 + h * 8);
    }
    f4_t st[4][4];
#pragma unroll
    for (int mt = 0; mt < 4; ++mt) {
      bf8_t ak = bz;
      if (lg == 0) ak = *(const bf8_t*)(qw + (mt * 16 + lr) * 96 + 32 + h * 8);
#pragma unroll
      for (int nt = 0; nt < 4; ++nt)
        st[mt][nt] = __builtin_amdgcn_mfma_f32_16x16x32_bf16(ak, bq[nt], z4, 0, 0, 0);
    }
#pragma unroll
    for (int nt = 0; nt < 4; ++nt) {
      float sv[16];
#pragma unroll
      for (int mt = 0; mt < 4; ++mt) {
        const float* rp = rpbT + h * 4096 + (mt * 16 + lg * 4) * 64 + nt * 16 + lr;
#pragma unroll
        for (int r = 0; r < 4; ++r)
          sv[mt * 4 + r] = fmaf(st[mt][nt][r], 0.35355339059327373f, rp[r * 64]);
      }
      if (edge) {
        int n = nt * 16 + lr;
        int regn = ((wh < 15) ? 0 : (((n >> 3) < 4) ? 1 : 2)) * 3 +
                   ((ww < 15) ? 0 : (((n & 7) < 4) ? 1 : 2));
#pragma unroll
        for (int mt = 0; mt < 4; ++mt)
#pragma unroll
          for (int r = 0; r < 4; ++r) {
            int m = mt * 16 + lg * 4 + r;
            int regm = ((wh < 15) ? 0 : (((m >> 3) < 4) ? 1 : 2)) * 3 +
                       ((ww < 15) ? 0 : (((m & 7) < 4) ? 1 : 2));
            if (regm != regn) sv[mt * 4 + r] -= 100.0f;
          }
      }
      float mx = sv[0];
#pragma unroll
      for (int i = 1; i < 16; ++i) mx = fmaxf(mx, sv[i]);
      mx = fmaxf(mx, __shfl_xor(mx, 16));
      mx = fmaxf(mx, __shfl_xor(mx, 32));
      float l = 0.0f;
#pragma unroll
      for (int i = 0; i < 16; ++i) {
        sv[i] = __expf(sv[i] - mx);
        l += sv[i];
      }
      l += __shfl_xor(l, 16);
      l += __shfl_xor(l, 32);
      float inv = 1.0f / l;
      int row = nt * 16 + lr, rw7 = lr & 7;
#pragma unroll
      for (int mt = 0; mt < 4; ++mt) {
        uint2 w = {pk2(sv[mt * 4] * inv, sv[mt * 4 + 1] * inv),
                   pk2(sv[mt * 4 + 2] * inv, sv[mt * 4 + 3] * inv)};
        *(uint2*)&Pw[row * 64 + (((2 * mt + (lg >> 1)) ^ rw7) << 3) + (lg & 1) * 4] = w;
      }
    }
    f4_t oa[4] = {z4, z4, z4, z4};
#pragma unroll
    for (int ks = 0; ks < 2; ++ks) {
      bf8_t av = bz;
      if (lr < 8) av = *(const bf8_t*)&Vw[lr * 64 + (((4 * ks + lg) ^ (lr & 7)) << 3)];
#pragma unroll
      for (int nt = 0; nt < 4; ++nt) {
        int row = nt * 16 + lr;
        bf8_t bp = *(const bf8_t*)&Pw[row * 64 + (((4 * ks + lg) ^ (lr & 7)) << 3)];
        oa[nt] = __builtin_amdgcn_mfma_f32_16x16x32_bf16(av, bp, oa[nt], 0, 0, 0);
      }
    }
    if (lg < 2) {
#pragma unroll
      for (int nt = 0; nt < 4; ++nt) {
        uint2 w = {pk2(oa[nt][0], oa[nt][1]), pk2(oa[nt][2], oa[nt][3])};
        int row = nt * 16 + lr;
        *(uint2*)&aw_[row * 32 + ((h ^ (lr & 3)) << 3) + lg * 4] = w;
      }
    }
  }

  // out projection via MFMA: out^T[co][n]
#pragma unroll
  for (int mt = 0; mt < 2; ++mt) {
    const float* wr = pw + (mt * 16 + lr) * 32 + lg * 8;
    float4 a0 = *(const float4*)wr, a1 = *(const float4*)(wr + 4);
    union { uint4 u; bf8_t v; } aw;
    aw.u.x = pk2(a0.x, a0.y); aw.u.y = pk2(a0.z, a0.w);
    aw.u.z = pk2(a1.x, a1.y); aw.u.w = pk2(a1.z, a1.w);
    float pb0 = pb[mt * 16 + lg * 4], pb1 = pb[mt * 16 + lg * 4 + 1];
    float pb2 = pb[mt * 16 + lg * 4 + 2], pb3 = pb[mt * 16 + lg * 4 + 3];
#pragma unroll
    for (int nt = 0; nt < 4; ++nt) {
      int row = nt * 16 + lr;
      bf8_t bo = *(const bf8_t*)&aw_[row * 32 + ((lg ^ (lr & 3)) << 3)];
      f4_t po = __builtin_amdgcn_mfma_f32_16x16x32_bf16(aw.v, bo, z4, 0, 0, 0);
      int n = nt * 16 + lr;
      int hdst = (wh * 8 + (n >> 3) + shift) & 127;
      int wdst = (ww * 8 + (n & 7) + shift) & 127;
      uint2 w = {pk2(po[0] + pb0, po[1] + pb1), pk2(po[2] + pb2, po[3] + pb3)};
      *(uint2*)(yT + ((size_t)(b * 16384 + hdst * 128 + wdst)) * 128 + yc0 + mt * 16 + lg * 4) = w;
    }
  }
}

// ---------------------------------------------------------------------------
extern "C" void kernel_launch(void* const* d_in, const int* in_sizes, int n_in,
                              void* d_out, int out_size, void* d_ws, size_t ws_size,
                              hipStream_t stream) {
  (void)in_sizes; (void)n_in; (void)out_size; (void)ws_size;
  const float* x        = (const float*)d_in[0];
  const float* ln_g     = (const float*)d_in[1];
  const float* ln_b     = (const float*)d_in[2];
  const float* ga_qkv_w = (const float*)d_in[3];
  const float* ga_qkv_b = (const float*)d_in[4];
  const float* ga_gp_w  = (const float*)d_in[5];
  const float* ga_gp_b  = (const float*)d_in[6];
  const float* pos_w1   = (const float*)d_in[7];
  const float* pos_b1   = (const float*)d_in[8];
  const float* pos_w2   = (const float*)d_in[9];
  const float* pos_b2   = (const float*)d_in[10];
  const float* pos_w3   = (const float*)d_in[11];
  const float* pos_b3   = (const float*)d_in[12];
  const float* a1_pw    = (const float*)d_in[13];
  const float* a1_pb    = (const float*)d_in[14];
  const float* a2_pw    = (const float*)d_in[15];
  const float* a2_pb    = (const float*)d_in[16];
  const float* sw_qkv_w = (const float*)d_in[17];
  const float* sw_qkv_b = (const float*)d_in[18];
  const float* sw_rpb   = (const float*)d_in[19];
  const float* sw_pw    = (const float*)d_in[20];
  const float* sw_pb    = (const float*)d_in[21];
  const float* wn_qkv_w = (const float*)d_in[22];
  const float* wn_qkv_b = (const float*)d_in[23];
  const float* wn_rpb   = (const float*)d_in[24];
  const float* wn_pw    = (const float*)d_in[25];
  const float* wn_pb    = (const float*)d_in[26];
  const float* fc_w     = (const float*)d_in[27];
  const float* fc_b     = (const float*)d_in[28];
  const float* n2_g     = (const float*)d_in[29];
  const float* n2_b     = (const float*)d_in[30];
  const float* m1_w     = (const float*)d_in[31];
  const float* m1_b     = (const float*)d_in[32];
  const float* m2_w     = (const float*)d_in[33];
  const float* m2_b     = (const float*)d_in[34];
  float* out = (float*)d_out;
  char* base = (char*)d_ws;

  float*          xTf    = (float*)(base);                    // 32 MB
  unsigned short* qkvT   = (unsigned short*)(base + 32 * MB); // 24 MB
  unsigned short* xgridT = (unsigned short*)(base + 56 * MB); //  8 MB
  unsigned short* t1T    = (unsigned short*)(base + 64 * MB); //  8 MB
  unsigned short* t1pT   = (unsigned short*)(base + 72 * MB); //  8 MB
  unsigned short* yT     = (unsigned short*)(base + 80 * MB); // 16 MB
  unsigned short* x2T    = (unsigned short*)(base + 96 * MB); // 16 MB
  unsigned short* qkv2   = (unsigned short*)(base + 32 * MB); // alias (after gattn2)
  unsigned short* hT     = (unsigned short*)(base + 32 * MB); // alias (after swat)
  float*          outT   = (float*)(base + 64 * MB);          // alias
  float*          pbT    = (float*)(base + 112 * MB);         //  1 MB
  float*          ptab   = (float*)(base + 113 * MB);         // 16 KB
  float*          rpbT_sw= (float*)(base + 113 * MB + 65536);
  float*          rpbT_wn= (float*)(base + 113 * MB + 131072);
  unsigned short* wq2bf  = (unsigned short*)(base + 113 * MB + 196608); // 24 KB
  float*          bias192= (float*)(base + 113 * MB + 229376);          // 768 B
  unsigned short* wbf    = (unsigned short*)(base + 113 * MB + 262144); // 208 KB

  pos_mlp_k<<<4, 256, 0, stream>>>(pos_w1, pos_b1, pos_w2, pos_b2, pos_w3, pos_b3, ptab);
  pbT_gather_k<<<1024, 256, 0, stream>>>(ptab, pbT);
  rpbT_k<<<64, 256, 0, stream>>>(sw_rpb, rpbT_sw);
  rpbT_k<<<64, 256, 0, stream>>>(wn_rpb, rpbT_wn);
  wq2_k<<<48, 256, 0, stream>>>(sw_qkv_w, sw_qkv_b, wn_qkv_w, wn_qkv_b, wq2bf, bias192);
  wcvt_k<<<416, 256, 0, stream>>>(ga_qkv_w, ga_gp_w, a1_pw, a2_pw, fc_w, m1_w, m2_w, wbf);

  tin_k<<<dim3(256, 1, 4), 256, 0, stream>>>(x, xTf);

  // grid branch
  gemm_k<4, 1, 1, 0, 1><<<dim3(512, 3, 1), 256, 0, stream>>>(
      xTf, 128, 0, wbf, ga_qkv_b, nullptr, nullptr, nullptr, nullptr, qkvT, 192, 0);
  gemm_k<4, 1, 1, 0, 1><<<dim3(512, 1, 1), 256, 0, stream>>>(
      xTf, 128, 0, wbf + 12288, ga_gp_b, nullptr, nullptr, nullptr, nullptr, xgridT, 64, 0);

  gattn_k<<<dim3(256, 4), 256, 0, stream>>>(
      xgridT, 64, 0, qkvT, 192, 64, qkvT, 192, 128, pbT, t1T, 64, 0);
  gemm_k<4, 1, 0, 0, 0><<<dim3(512, 1, 1), 256, 0, stream>>>(
      t1T, 64, 0, wbf + 16384, a1_pb, nullptr, nullptr, nullptr, nullptr, t1pT, 64, 0);

  gattn_k<<<dim3(256, 4), 256, 0, stream>>>(
      qkvT, 192, 0, xgridT, 64, 0, t1pT, 64, 0, pbT, t1T, 64, 0);
  gemm_k<4, 1, 0, 0, 2><<<dim3(512, 1, 1), 256, 0, stream>>>(
      t1T, 64, 0, wbf + 20480, a2_pb, nullptr, nullptr, nullptr, nullptr, yT, 128, 64);

  // window branches: qkv GEMM (window-ordered) + MFMA attention
  gemm_k<6, 1, 1, 0, 3><<<dim3(512, 2, 1), 256, 0, stream>>>(
      xTf, 128, 64, wq2bf, bias192, nullptr, nullptr, nullptr, nullptr, qkv2, 96, 0);
  swat_k<<<dim3(256, 2), 256, 0, stream>>>(
      qkv2, rpbT_sw, rpbT_wn, sw_pw, sw_pb, wn_pw, wn_pb, yT);

  gemm_k<8, 2, 0, 2, 0><<<dim3(512, 1, 1), 256, 0, stream>>>(
      yT, 128, 0, wbf + 24576, fc_b, ln_g, ln_b, xTf, nullptr, x2T, 128, 0);

  gemm_k<8, 2, 0, 1, 0><<<dim3(512, 2, 1), 256, 0, stream>>>(
      x2T, 128, 0, wbf + 40960, m1_b, nullptr, nullptr, nullptr, nullptr, hT, 256, 0);
  gemm_k<8, 4, 0, 3, 0><<<dim3(512, 1, 1), 256, 0, stream>>>(
      hT, 256, 0, wbf + 73728, m2_b, n2_g, n2_b, xTf, x2T, outT, 128, 0);

  tout_k<<<dim3(256, 1, 4), 256, 0, stream>>>(outT, out);
}

// Round 9
// 211.048 us; speedup vs baseline: 1.8635x; 1.0692x over previous
//
#include <hip/hip_runtime.h>
#include <hip/hip_bf16.h>
#include <cstdint>

// ---------------------------------------------------------------------------
// GABlock, channel-last bf16-MFMA pipeline.
// R9: merged grid qkv+gp GEMM; bias folded into MFMA C operand; softmax
//     shift-free (scores provably small); scales folded into weights;
//     m2 epilogue writes NCHW directly (tout_k eliminated).
// ---------------------------------------------------------------------------

typedef __attribute__((ext_vector_type(8))) short bf8_t;   // 8 bf16 (4 VGPR)
typedef __attribute__((ext_vector_type(4))) float f4_t;    // 4 f32 acc

__device__ __forceinline__ float bf2f(unsigned short u) {
  union { unsigned int i; float f; } x; x.i = ((unsigned int)u) << 16; return x.f;
}
__device__ __forceinline__ unsigned short f2bf(float f) {
  union { float f; unsigned int i; } x; x.f = f;
  unsigned int r = x.i + 0x7FFFu + ((x.i >> 16) & 1u);
  return (unsigned short)(r >> 16);
}
// HW packed f32x2 -> bf16x2 (RNE).
__device__ __forceinline__ unsigned int pk2(float a, float b) {
  unsigned int d;
  asm("v_cvt_pk_bf16_f32 %0, %1, %2" : "=v"(d) : "v"(a), "v"(b));
  return d;
}

#define MB (1048576L)

// ---------------- dynamic position bias MLP --------------------------------
__global__ void pos_mlp_k(const float* __restrict__ w1, const float* __restrict__ b1,
                          const float* __restrict__ w2, const float* __restrict__ b2,
                          const float* __restrict__ w3, const float* __restrict__ b3,
                          float* __restrict__ table) {
  int j = blockIdx.x * 256 + threadIdx.x;
  if (j >= 961) return;
  float chv = (float)(j / 31) - 15.0f;
  float cwv = (float)(j % 31) - 15.0f;
  float t1[16], t2[16];
#pragma unroll
  for (int i = 0; i < 16; ++i) {
    float s = fmaf(w1[i * 2], chv, fmaf(w1[i * 2 + 1], cwv, b1[i]));
    t1[i] = fmaxf(s, 0.0f);
  }
#pragma unroll
  for (int i = 0; i < 16; ++i) {
    float s = b2[i];
#pragma unroll
    for (int k = 0; k < 16; ++k) s = fmaf(w2[i * 16 + k], t1[k], s);
    t2[i] = fmaxf(s, 0.0f);
  }
#pragma unroll
  for (int hh = 0; hh < 4; ++hh) {
    float s = b3[hh];
#pragma unroll
    for (int k = 0; k < 16; ++k) s = fmaf(w3[hh * 16 + k], t2[k], s);
    table[j * 4 + hh] = s;
  }
}

// pbT[h][m][q] = bias for query q, key m
__global__ void pbT_gather_k(const float* __restrict__ table, float* __restrict__ pbT) {
  int t = blockIdx.x * 256 + threadIdx.x;   // 4*256*256
  int hh = t >> 16;
  int r = t & 65535;
  int m = r >> 8;
  int q = r & 255;
  int idx = ((q >> 4) - (m >> 4) + 15) * 31 + ((q & 15) - (m & 15) + 15);
  pbT[t] = table[idx * 4 + hh];
}

// rpbT[h][m][n] = rpb[idx(n,m)][h]
__global__ void rpbT_k(const float* __restrict__ rpb, float* __restrict__ rpbT) {
  int t = blockIdx.x * 256 + threadIdx.x;  // 16384
  int h = t >> 12, r = t & 4095, m = r >> 6, n = r & 63;
  int idx = ((n >> 3) - (m >> 3) + 7) * 15 + ((n & 7) - (m & 7) + 7);
  rpbT[t] = rpb[idx * 4 + h];
}

// block-diagonal 192x64 qkv weight (bf16, q-rows pre-scaled) + 192 bias
__global__ void wq2_k(const float* __restrict__ sw_w, const float* __restrict__ sw_b,
                      const float* __restrict__ wn_w, const float* __restrict__ wn_b,
                      unsigned short* __restrict__ w2, float* __restrict__ b2) {
  const float QS = 0.35355339059327373f;
  int t = blockIdx.x * 256 + threadIdx.x;   // 12288
  if (t < 12288) {
    int row = t >> 6, col = t & 63;
    float v = 0.0f;
    if (row < 96) { if (col < 32) v = sw_w[row * 32 + col]; }
    else          { if (col >= 32) v = wn_w[(row - 96) * 32 + col - 32]; }
    int rb = row % 96;
    if (rb < 32) v *= QS;               // q rows pre-scaled
    w2[t] = f2bf(v);
  }
  if (t < 192) {
    float v = t < 96 ? sw_b[t] : wn_b[t - 96];
    if ((t % 96) < 32) v *= QS;
    b2[t] = v;
  }
}

// all GEMM weights -> bf16 (ga_gp pre-scaled 0.25), plus combined qg bias.
// layout: 0 ga_qkv(12288) | 12288 ga_gp(4096) | 16384 a1 | 20480 a2
// 24576 fc(16384) | 40960 m1(32768) | 73728 m2(32768)
__global__ void wcvt_k(const float* __restrict__ w0, const float* __restrict__ w1,
                       const float* __restrict__ w2, const float* __restrict__ w3,
                       const float* __restrict__ w4, const float* __restrict__ w5,
                       const float* __restrict__ w6,
                       const float* __restrict__ qkv_b, const float* __restrict__ gp_b,
                       unsigned short* __restrict__ dst, float* __restrict__ biasQG) {
  int t = blockIdx.x * 256 + threadIdx.x;
  if (t < 256) biasQG[t] = t < 192 ? qkv_b[t] : gp_b[t - 192] * 0.25f;
  if (t >= 106496) return;
  const float* src; int off; float sc = 1.0f;
  if (t < 12288)      { src = w0; off = 0; }
  else if (t < 16384) { src = w1; off = 12288; sc = 0.25f; }
  else if (t < 20480) { src = w2; off = 16384; }
  else if (t < 24576) { src = w3; off = 20480; }
  else if (t < 40960) { src = w4; off = 24576; }
  else if (t < 73728) { src = w5; off = 40960; }
  else                { src = w6; off = 73728; }
  dst[t] = f2bf(src[t - off] * sc);
}

// ---------------- NCHW fp32 -> channel-last fp32 ---------------------------
__global__ __launch_bounds__(256) void tin_k(const float* __restrict__ x,
                                             float* __restrict__ xTf) {
  __shared__ float tile[64][132];
  const int b = blockIdx.z, px0 = blockIdx.x * 64, tid = threadIdx.x;
#pragma unroll
  for (int i = 0; i < 8; ++i) {
    int e = i * 256 + tid;
    int c = e >> 4, p4 = (e & 15) * 4;
    float4 v = *(const float4*)(x + (((size_t)(b * 128 + c)) << 14) + px0 + p4);
    tile[p4][c] = v.x; tile[p4 + 1][c] = v.y; tile[p4 + 2][c] = v.z; tile[p4 + 3][c] = v.w;
  }
  __syncthreads();
#pragma unroll
  for (int i = 0; i < 8; ++i) {
    int e = i * 256 + tid;
    int px = e >> 5, c4 = (e & 31) * 4;
    float4 v = make_float4(tile[px][c4], tile[px][c4 + 1], tile[px][c4 + 2], tile[px][c4 + 3]);
    *(float4*)(xTf + ((size_t)(b * 16384 + px0 + px)) * 128 + c4) = v;
  }
}

// ---------------- generic bf16-MFMA GEMM (W pre-converted bf16) ------------
// EPI: 0 plain->bf16, 1 gelu->bf16, 2 cLN+res->bf16, 3 cLN+res+res->f32 NCHW
template <int NF, int KC, int AF32, int EPI, int OSHUF>
__global__ __launch_bounds__(256) void gemm_k(
    const void* __restrict__ A, int a_rs, int a_c0,
    const unsigned short* __restrict__ W, const float* __restrict__ bias,
    const float* __restrict__ g, const float* __restrict__ bb,
    const float* __restrict__ resf, const unsigned short* __restrict__ resb,
    void* __restrict__ out, int o_rs, int o_c0) {
  __shared__ __align__(16) char Asw[128 * 128];
  __shared__ __align__(16) char Bsw[NF * 16 * 128];
  const int tid = threadIdx.x;
  const int lane = tid & 63, wv = tid >> 6, wpx = wv * 32;
  const int lr = lane & 15, lg = lane >> 4;
  const int px0 = blockIdx.x * 128;
  const int co0 = blockIdx.y * (NF * 16);

  f4_t acc[2][NF];
#pragma unroll
  for (int mf = 0; mf < 2; ++mf)
#pragma unroll
    for (int nf = 0; nf < NF; ++nf) acc[mf][nf] = (f4_t){0.f, 0.f, 0.f, 0.f};

  for (int kc = 0; kc < KC; ++kc) {
    const int k0 = kc * 64;
    if (kc) __syncthreads();
#pragma unroll
    for (int i = 0; i < 4; ++i) {
      int e = i * 256 + tid;
      int row = e >> 3, q8 = e & 7;
      char* dst = Asw + row * 128 + ((q8 ^ (row & 7)) << 4);
      if (AF32) {
        const float* src = (const float*)A + (size_t)(px0 + row) * a_rs + a_c0 + k0 + q8 * 8;
        float4 v0 = *(const float4*)src, v1 = *(const float4*)(src + 4);
        uint4 pk;
        pk.x = pk2(v0.x, v0.y); pk.y = pk2(v0.z, v0.w);
        pk.z = pk2(v1.x, v1.y); pk.w = pk2(v1.z, v1.w);
        *(uint4*)dst = pk;
      } else {
        const unsigned short* src =
            (const unsigned short*)A + (size_t)(px0 + row) * a_rs + a_c0 + k0 + q8 * 8;
        *(uint4*)dst = *(const uint4*)src;
      }
    }
#pragma unroll
    for (int i = 0; i < NF / 2; ++i) {
      int e = i * 256 + tid;
      int row = e >> 3, q8 = e & 7;
      const unsigned short* src = W + (size_t)(co0 + row) * (KC * 64) + k0 + q8 * 8;
      *(uint4*)(Bsw + row * 128 + ((q8 ^ (row & 7)) << 4)) = *(const uint4*)src;
    }
    __syncthreads();
#pragma unroll
    for (int ks = 0; ks < 2; ++ks) {
      const int xk = (((ks * 4) + lg) ^ (lane & 7)) << 4;
      bf8_t av[2], bv[NF];
#pragma unroll
      for (int mf = 0; mf < 2; ++mf)
        av[mf] = *(const bf8_t*)(Asw + (wpx + mf * 16 + lr) * 128 + xk);
#pragma unroll
      for (int nf = 0; nf < NF; ++nf)
        bv[nf] = *(const bf8_t*)(Bsw + (nf * 16 + lr) * 128 + xk);
#pragma unroll
      for (int mf = 0; mf < 2; ++mf)
#pragma unroll
        for (int nf = 0; nf < NF; ++nf)
          acc[mf][nf] = __builtin_amdgcn_mfma_f32_16x16x32_bf16(av[mf], bv[nf], acc[mf][nf], 0, 0, 0);
    }
  }

  float bco[NF];
#pragma unroll
  for (int nf = 0; nf < NF; ++nf) bco[nf] = bias[co0 + nf * 16 + lr];

  if constexpr (EPI >= 2) {
    float gv[NF], bbv[NF];
#pragma unroll
    for (int nf = 0; nf < NF; ++nf) { gv[nf] = g[nf * 16 + lr]; bbv[nf] = bb[nf * 16 + lr]; }
#pragma unroll
    for (int mf = 0; mf < 2; ++mf)
#pragma unroll
      for (int nf = 0; nf < NF; ++nf)
#pragma unroll
        for (int r = 0; r < 4; ++r) acc[mf][nf][r] += bco[nf];
#pragma unroll
    for (int mf = 0; mf < 2; ++mf) {
#pragma unroll
      for (int r = 0; r < 4; ++r) {
        float s = 0.f, q = 0.f;
#pragma unroll
        for (int nf = 0; nf < NF; ++nf) {
          float v = acc[mf][nf][r];
          s += v; q += v * v;
        }
#pragma unroll
        for (int msk = 1; msk < 16; msk <<= 1) {
          s += __shfl_xor(s, msk);
          q += __shfl_xor(q, msk);
        }
        float mu = s * (1.0f / 128.0f);
        float var = q * (1.0f / 128.0f) - mu * mu;
        float rstd = rsqrtf(var + 1e-5f);
        int px_e = px0 + wpx + mf * 16 + lg * 4 + r;
        const float* xr = resf + (size_t)px_e * 128 + lr;
        if constexpr (EPI == 2) {
          unsigned short* op = (unsigned short*)out + (size_t)px_e * o_rs + lr;
#pragma unroll
          for (int nf = 0; nf < NF; ++nf) {
            float v = (acc[mf][nf][r] - mu) * rstd * gv[nf] + bbv[nf] + xr[nf * 16];
            op[nf * 16] = f2bf(v);
          }
        } else {  // EPI == 3: write fp32 NCHW directly
          const unsigned short* x2r = resb + (size_t)px_e * 128 + lr;
          int b_ = px_e >> 14, p_ = px_e & 16383;
          float* op = (float*)out + (((size_t)(b_ * 128) + lr) << 14) + p_;
#pragma unroll
          for (int nf = 0; nf < NF; ++nf) {
            float v = (acc[mf][nf][r] - mu) * rstd * gv[nf] + bbv[nf] + xr[nf * 16] + bf2f(x2r[nf * 16]);
            op[(size_t)nf << 18] = v;   // nf*16 channels * 16384 px
          }
        }
      }
    }
  } else {
#pragma unroll
    for (int mf = 0; mf < 2; ++mf) {
#pragma unroll
      for (int r = 0; r < 4; ++r) {
        int px_e = px0 + wpx + mf * 16 + lg * 4 + r;
        size_t orow;
        int cadj = co0;
        if constexpr (OSHUF == 0) {
          orow = (size_t)px_e;
        } else if constexpr (OSHUF == 1) {
          int b = px_e >> 14, p = px_e & 16383, hh = p >> 7, w_ = p & 127;
          orow = (size_t)(b * 64 + (hh & 7) * 8 + (w_ & 7)) * 256 + ((hh >> 3) * 16 + (w_ >> 3));
        } else if constexpr (OSHUF == 2) {
          int gbb = px_e >> 8, n = px_e & 255;
          int b = gbb >> 6, ih = (gbb >> 3) & 7, iw = gbb & 7;
          orow = (size_t)b * 16384 + ((n >> 4) * 8 + ih) * 128 + (n & 15) * 8 + iw;
        } else {  // window-order: br0 = sw(shift 4), br1 = wn(shift 0)
          int brx = (co0 >= 96);
          int b = px_e >> 14, p = px_e & 16383, hh = p >> 7, w_ = p & 127;
          int sh = brx ? 0 : 4;
          int h2 = (hh - sh) & 127, w2_ = (w_ - sh) & 127;
          orow = (size_t)brx * 65536 + (size_t)b * 16384 +
                 (size_t)(((h2 >> 3) * 16 + (w2_ >> 3)) * 64 + (h2 & 7) * 8 + (w2_ & 7));
          cadj = co0 - brx * 96;
        }
        unsigned short* op = (unsigned short*)out + orow * o_rs + o_c0 + cadj + lr;
#pragma unroll
        for (int nf = 0; nf < NF; ++nf) {
          float v = acc[mf][nf][r] + bco[nf];
          if constexpr (EPI == 1) v = 0.5f * v * (1.0f + erff(v * 0.7071067811865475f));
          op[nf * 16] = f2bf(v);
        }
      }
    }
  }
}

// ---------------- MFMA grid attention (N=256, hd=16, 4 heads) --------------
// bias folded into QK MFMA C operand; shift-free softmax (scores small).
__global__ __launch_bounds__(256) void gattn_k(
    const unsigned short* __restrict__ Q, int q_rs, int q_c0,
    const unsigned short* __restrict__ K, int k_rs, int k_c0,
    const unsigned short* __restrict__ V, int v_rs, int v_c0,
    const float* __restrict__ pbT, unsigned short* __restrict__ outb, int o_rs, int o_c0) {
  __shared__ __align__(16) unsigned short K_lds[256 * 16];
  __shared__ __align__(16) unsigned short Vt[16 * 256];      // swz [d][m]
  __shared__ __align__(16) unsigned short P_lds[4 * 64 * 32];// per-wave swz [q][m]
  const int gb = blockIdx.x, h = blockIdx.y, tid = threadIdx.x;
  const int lane = tid & 63, wv = tid >> 6;
  const int lr = lane & 15, lg = lane >> 4;
  const int q0 = wv * 64;

  {
    const unsigned short* kp = K + (size_t)(gb * 256 + tid) * k_rs + k_c0 + h * 16;
    *(uint4*)&K_lds[tid * 16]     = *(const uint4*)kp;
    *(uint4*)&K_lds[tid * 16 + 8] = *(const uint4*)(kp + 8);
    const unsigned short* vp = V + (size_t)(gb * 256 + tid) * v_rs + v_c0 + h * 16;
    uint4 va = *(const uint4*)vp;
    uint4 vb = *(const uint4*)(vp + 8);
    unsigned int w8[8] = {va.x, va.y, va.z, va.w, vb.x, vb.y, vb.z, vb.w};
    int chb = (tid >> 3);
    int wi = tid & 7;
#pragma unroll
    for (int w = 0; w < 8; ++w) {
      int d0 = 2 * w, d1 = 2 * w + 1;
      Vt[d0 * 256 + ((chb ^ (d0 & 7)) << 3) + wi] = (unsigned short)(w8[w] & 0xffff);
      Vt[d1 * 256 + ((chb ^ (d1 & 7)) << 3) + wi] = (unsigned short)(w8[w] >> 16);
    }
  }
  bf8_t bq[4];
  const bf8_t bz = {0, 0, 0, 0, 0, 0, 0, 0};
#pragma unroll
  for (int qt = 0; qt < 4; ++qt) {
    bq[qt] = bz;
    if (lg < 2)
      bq[qt] = *(const bf8_t*)(Q + (size_t)(gb * 256 + q0 + qt * 16 + lr) * q_rs + q_c0 + h * 16 + lg * 8);
  }
  __syncthreads();

  const f4_t z4 = {0.f, 0.f, 0.f, 0.f};
  f4_t oacc[4];
  float lrun[4];
#pragma unroll
  for (int qt = 0; qt < 4; ++qt) { oacc[qt] = z4; lrun[qt] = 0.0f; }

  unsigned short* Pw = &P_lds[wv * 64 * 32];

  for (int m0 = 0; m0 < 256; m0 += 32) {
    bf8_t ak0 = bz, ak1 = bz;
    if (lg < 2) {
      ak0 = *(const bf8_t*)&K_lds[(m0 + lr) * 16 + lg * 8];
      ak1 = *(const bf8_t*)&K_lds[(m0 + 16 + lr) * 16 + lg * 8];
    }
    bf8_t av = *(const bf8_t*)&Vt[lr * 256 + ((((m0 >> 3) + lg) ^ (lr & 7)) << 3)];

#pragma unroll
    for (int qt = 0; qt < 4; ++qt) {
      const float* bpm = pbT + ((size_t)(h * 256 + m0 + lg * 4) << 8) + q0 + qt * 16 + lr;
      f4_t c0v = {bpm[0], bpm[256], bpm[512], bpm[768]};
      f4_t c1v = {bpm[4096], bpm[4352], bpm[4608], bpm[4864]};
      f4_t st0 = __builtin_amdgcn_mfma_f32_16x16x32_bf16(ak0, bq[qt], c0v, 0, 0, 0);
      f4_t st1 = __builtin_amdgcn_mfma_f32_16x16x32_bf16(ak1, bq[qt], c1v, 0, 0, 0);
      float p0[4], p1[4], ls = 0.0f;
#pragma unroll
      for (int r = 0; r < 4; ++r) {
        p0[r] = __expf(st0[r]);
        p1[r] = __expf(st1[r]);
        ls += p0[r] + p1[r];
      }
      ls += __shfl_xor(ls, 16);
      ls += __shfl_xor(ls, 32);
      lrun[qt] += ls;
      int row = qt * 16 + lr;
      int rw3 = row & 3;
      uint2 w0 = {pk2(p0[0], p0[1]), pk2(p0[2], p0[3])};
      uint2 w1 = {pk2(p1[0], p1[1]), pk2(p1[2], p1[3])};
      *(uint2*)&Pw[row * 32 + ((((lg >> 1)) ^ rw3) << 3) + (lg & 1) * 4]     = w0;
      *(uint2*)&Pw[row * 32 + (((2 + (lg >> 1)) ^ rw3) << 3) + (lg & 1) * 4] = w1;
    }
#pragma unroll
    for (int qt = 0; qt < 4; ++qt) {
      int row = qt * 16 + lr;
      bf8_t bp = *(const bf8_t*)&Pw[row * 32 + ((lg ^ (row & 3)) << 3)];
      oacc[qt] = __builtin_amdgcn_mfma_f32_16x16x32_bf16(av, bp, oacc[qt], 0, 0, 0);
    }
  }

#pragma unroll
  for (int qt = 0; qt < 4; ++qt) {
    float inv = 1.0f / lrun[qt];
    uint2 o;
    o.x = pk2(oacc[qt][0] * inv, oacc[qt][1] * inv);
    o.y = pk2(oacc[qt][2] * inv, oacc[qt][3] * inv);
    unsigned short* op = outb + (size_t)(gb * 256 + q0 + qt * 16 + lr) * o_rs + o_c0 + h * 16 + lg * 4;
    *(uint2*)op = o;
  }
}

// ---------------- MFMA swin window attention (barrier-free) ----------------
__global__ __launch_bounds__(256) void swat_k(
    const unsigned short* __restrict__ qkv2,
    const float* __restrict__ rpbT_sw, const float* __restrict__ rpbT_wn,
    const float* __restrict__ sw_pw, const float* __restrict__ sw_pb,
    const float* __restrict__ wn_pw, const float* __restrict__ wn_pb,
    unsigned short* __restrict__ yT) {
  __shared__ __align__(16) unsigned short Vt[4 * 8 * 64];
  __shared__ __align__(16) unsigned short Pt[4 * 64 * 64];
  __shared__ __align__(16) unsigned short aoT[4 * 64 * 32];
  const int tid = threadIdx.x, lane = tid & 63, wv = tid >> 6;
  const int lr = lane & 15, lg = lane >> 4;
  const int br = blockIdx.y;
  const int win = blockIdx.x * 4 + wv;
  const int b = win >> 8, wl = win & 255, wh = wl >> 4, ww = wl & 15;
  const float* rpbT = br ? rpbT_wn : rpbT_sw;
  const float* pw   = br ? wn_pw : sw_pw;
  const float* pb   = br ? wn_pb : sw_pb;
  const int shift = br ? 0 : 4;
  const int yc0 = br ? 0 : 32;
  const bool edge = (shift > 0) && (wh == 15 || ww == 15);

  const unsigned short* qw = qkv2 + (size_t)br * 65536 * 96 + (size_t)win * 64 * 96;
  const f4_t z4 = {0.f, 0.f, 0.f, 0.f};
  const bf8_t bz = {0, 0, 0, 0, 0, 0, 0, 0};
  unsigned short* Vw = &Vt[wv * 8 * 64];
  unsigned short* Pw = &Pt[wv * 64 * 64];
  unsigned short* aw_ = &aoT[wv * 64 * 32];

#pragma unroll 1
  for (int h = 0; h < 4; ++h) {
    {
      uint4 v = *(const uint4*)(qw + lane * 96 + 64 + h * 8);
      unsigned int w4[4] = {v.x, v.y, v.z, v.w};
      int chb = lane >> 3, wi = lane & 7;
#pragma unroll
      for (int j = 0; j < 4; ++j) {
        int d0 = 2 * j, d1 = 2 * j + 1;
        Vw[d0 * 64 + ((chb ^ (d0 & 7)) << 3) + wi] = (unsigned short)(w4[j] & 0xffff);
        Vw[d1 * 64 + ((chb ^ (d1 & 7)) << 3) + wi] = (unsigned short)(w4[j] >> 16);
      }
    }
    bf8_t bq[4];
#pragma unroll
    for (int nt = 0; nt < 4; ++nt) {
      bq[nt] = bz;
      if (lg == 0) bq[nt] = *(const bf8_t*)(qw + (nt * 16 + lr) * 96 + h * 8);
    }
    f4_t st[4][4];
#pragma unroll
    for (int mt = 0; mt < 4; ++mt) {
      bf8_t ak = bz;
      if (lg == 0) ak = *(const bf8_t*)(qw + (mt * 16 + lr) * 96 + 32 + h * 8);
#pragma unroll
      for (int nt = 0; nt < 4; ++nt) {
        const float* rp = rpbT + h * 4096 + (mt * 16 + lg * 4) * 64 + nt * 16 + lr;
        f4_t cb = {rp[0], rp[64], rp[128], rp[192]};
        st[mt][nt] = __builtin_amdgcn_mfma_f32_16x16x32_bf16(ak, bq[nt], cb, 0, 0, 0);
      }
    }
#pragma unroll
    for (int nt = 0; nt < 4; ++nt) {
      float sv[16];
#pragma unroll
      for (int mt = 0; mt < 4; ++mt)
#pragma unroll
        for (int r = 0; r < 4; ++r) sv[mt * 4 + r] = st[mt][nt][r];
      if (edge) {
        int n = nt * 16 + lr;
        int regn = ((wh < 15) ? 0 : (((n >> 3) < 4) ? 1 : 2)) * 3 +
                   ((ww < 15) ? 0 : (((n & 7) < 4) ? 1 : 2));
#pragma unroll
        for (int mt = 0; mt < 4; ++mt)
#pragma unroll
          for (int r = 0; r < 4; ++r) {
            int m = mt * 16 + lg * 4 + r;
            int regm = ((wh < 15) ? 0 : (((m >> 3) < 4) ? 1 : 2)) * 3 +
                       ((ww < 15) ? 0 : (((m & 7) < 4) ? 1 : 2));
            if (regm != regn) sv[mt * 4 + r] -= 100.0f;
          }
      }
      float l = 0.0f;
#pragma unroll
      for (int i = 0; i < 16; ++i) {
        sv[i] = __expf(sv[i]);
        l += sv[i];
      }
      l += __shfl_xor(l, 16);
      l += __shfl_xor(l, 32);
      float inv = 1.0f / l;
      int row = nt * 16 + lr, rw7 = lr & 7;
#pragma unroll
      for (int mt = 0; mt < 4; ++mt) {
        uint2 w = {pk2(sv[mt * 4] * inv, sv[mt * 4 + 1] * inv),
                   pk2(sv[mt * 4 + 2] * inv, sv[mt * 4 + 3] * inv)};
        *(uint2*)&Pw[row * 64 + (((2 * mt + (lg >> 1)) ^ rw7) << 3) + (lg & 1) * 4] = w;
      }
    }
    f4_t oa[4] = {z4, z4, z4, z4};
#pragma unroll
    for (int ks = 0; ks < 2; ++ks) {
      bf8_t av = bz;
      if (lr < 8) av = *(const bf8_t*)&Vw[lr * 64 + (((4 * ks + lg) ^ (lr & 7)) << 3)];
#pragma unroll
      for (int nt = 0; nt < 4; ++nt) {
        int row = nt * 16 + lr;
        bf8_t bp = *(const bf8_t*)&Pw[row * 64 + (((4 * ks + lg) ^ (lr & 7)) << 3)];
        oa[nt] = __builtin_amdgcn_mfma_f32_16x16x32_bf16(av, bp, oa[nt], 0, 0, 0);
      }
    }
    if (lg < 2) {
#pragma unroll
      for (int nt = 0; nt < 4; ++nt) {
        uint2 w = {pk2(oa[nt][0], oa[nt][1]), pk2(oa[nt][2], oa[nt][3])};
        int row = nt * 16 + lr;
        *(uint2*)&aw_[row * 32 + ((h ^ (lr & 3)) << 3) + lg * 4] = w;
      }
    }
  }

#pragma unroll
  for (int mt = 0; mt < 2; ++mt) {
    const float* wr = pw + (mt * 16 + lr) * 32 + lg * 8;
    float4 a0 = *(const float4*)wr, a1 = *(const float4*)(wr + 4);
    union { uint4 u; bf8_t v; } aw;
    aw.u.x = pk2(a0.x, a0.y); aw.u.y = pk2(a0.z, a0.w);
    aw.u.z = pk2(a1.x, a1.y); aw.u.w = pk2(a1.z, a1.w);
    float pb0 = pb[mt * 16 + lg * 4], pb1 = pb[mt * 16 + lg * 4 + 1];
    float pb2 = pb[mt * 16 + lg * 4 + 2], pb3 = pb[mt * 16 + lg * 4 + 3];
#pragma unroll
    for (int nt = 0; nt < 4; ++nt) {
      int row = nt * 16 + lr;
      bf8_t bo = *(const bf8_t*)&aw_[row * 32 + ((lg ^ (lr & 3)) << 3)];
      f4_t po = __builtin_amdgcn_mfma_f32_16x16x32_bf16(aw.v, bo, z4, 0, 0, 0);
      int n = nt * 16 + lr;
      int hdst = (wh * 8 + (n >> 3) + shift) & 127;
      int wdst = (ww * 8 + (n & 7) + shift) & 127;
      uint2 w = {pk2(po[0] + pb0, po[1] + pb1), pk2(po[2] + pb2, po[3] + pb3)};
      *(uint2*)(yT + ((size_t)(b * 16384 + hdst * 128 + wdst)) * 128 + yc0 + mt * 16 + lg * 4) = w;
    }
  }
}

// ---------------------------------------------------------------------------
extern "C" void kernel_launch(void* const* d_in, const int* in_sizes, int n_in,
                              void* d_out, int out_size, void* d_ws, size_t ws_size,
                              hipStream_t stream) {
  (void)in_sizes; (void)n_in; (void)out_size; (void)ws_size;
  const float* x        = (const float*)d_in[0];
  const float* ln_g     = (const float*)d_in[1];
  const float* ln_b     = (const float*)d_in[2];
  const float* ga_qkv_w = (const float*)d_in[3];
  const float* ga_qkv_b = (const float*)d_in[4];
  const float* ga_gp_w  = (const float*)d_in[5];
  const float* ga_gp_b  = (const float*)d_in[6];
  const float* pos_w1   = (const float*)d_in[7];
  const float* pos_b1   = (const float*)d_in[8];
  const float* pos_w2   = (const float*)d_in[9];
  const float* pos_b2   = (const float*)d_in[10];
  const float* pos_w3   = (const float*)d_in[11];
  const float* pos_b3   = (const float*)d_in[12];
  const float* a1_pw    = (const float*)d_in[13];
  const float* a1_pb    = (const float*)d_in[14];
  const float* a2_pw    = (const float*)d_in[15];
  const float* a2_pb    = (const float*)d_in[16];
  const float* sw_qkv_w = (const float*)d_in[17];
  const float* sw_qkv_b = (const float*)d_in[18];
  const float* sw_rpb   = (const float*)d_in[19];
  const float* sw_pw    = (const float*)d_in[20];
  const float* sw_pb    = (const float*)d_in[21];
  const float* wn_qkv_w = (const float*)d_in[22];
  const float* wn_qkv_b = (const float*)d_in[23];
  const float* wn_rpb   = (const float*)d_in[24];
  const float* wn_pw    = (const float*)d_in[25];
  const float* wn_pb    = (const float*)d_in[26];
  const float* fc_w     = (const float*)d_in[27];
  const float* fc_b     = (const float*)d_in[28];
  const float* n2_g     = (const float*)d_in[29];
  const float* n2_b     = (const float*)d_in[30];
  const float* m1_w     = (const float*)d_in[31];
  const float* m1_b     = (const float*)d_in[32];
  const float* m2_w     = (const float*)d_in[33];
  const float* m2_b     = (const float*)d_in[34];
  float* out = (float*)d_out;
  char* base = (char*)d_ws;

  float*          xTf    = (float*)(base);                    // 32 MB
  unsigned short* qgT    = (unsigned short*)(base + 32 * MB); // 32 MB [px][256: q|k|v|g]
  unsigned short* t1T    = (unsigned short*)(base + 64 * MB); //  8 MB
  unsigned short* t1pT   = (unsigned short*)(base + 72 * MB); //  8 MB
  unsigned short* yT     = (unsigned short*)(base + 80 * MB); // 16 MB
  unsigned short* x2T    = (unsigned short*)(base + 96 * MB); // 16 MB
  unsigned short* qkv2   = (unsigned short*)(base + 32 * MB); // alias (after gattn2)
  unsigned short* hT     = (unsigned short*)(base + 32 * MB); // alias (after swat)
  float*          pbT    = (float*)(base + 112 * MB);         //  1 MB
  float*          ptab   = (float*)(base + 113 * MB);         // 16 KB
  float*          rpbT_sw= (float*)(base + 113 * MB + 65536);
  float*          rpbT_wn= (float*)(base + 113 * MB + 131072);
  unsigned short* wq2bf  = (unsigned short*)(base + 113 * MB + 196608); // 24 KB
  float*          bias192= (float*)(base + 113 * MB + 229376);          // 768 B
  float*          biasQG = (float*)(base + 113 * MB + 230400);          // 1 KB
  unsigned short* wbf    = (unsigned short*)(base + 113 * MB + 262144); // 208 KB

  pos_mlp_k<<<4, 256, 0, stream>>>(pos_w1, pos_b1, pos_w2, pos_b2, pos_w3, pos_b3, ptab);
  pbT_gather_k<<<1024, 256, 0, stream>>>(ptab, pbT);
  rpbT_k<<<64, 256, 0, stream>>>(sw_rpb, rpbT_sw);
  rpbT_k<<<64, 256, 0, stream>>>(wn_rpb, rpbT_wn);
  wq2_k<<<48, 256, 0, stream>>>(sw_qkv_w, sw_qkv_b, wn_qkv_w, wn_qkv_b, wq2bf, bias192);
  wcvt_k<<<416, 256, 0, stream>>>(ga_qkv_w, ga_gp_w, a1_pw, a2_pw, fc_w, m1_w, m2_w,
                                  ga_qkv_b, ga_gp_b, wbf, biasQG);

  tin_k<<<dim3(256, 1, 4), 256, 0, stream>>>(x, xTf);

  // grid branch: one merged qkv+gp GEMM (256 out-ch), grid-shuffled
  gemm_k<4, 1, 1, 0, 1><<<dim3(512, 4, 1), 256, 0, stream>>>(
      xTf, 128, 0, wbf, biasQG, nullptr, nullptr, nullptr, nullptr, qgT, 256, 0);

  gattn_k<<<dim3(256, 4), 256, 0, stream>>>(
      qgT, 256, 192, qgT, 256, 64, qgT, 256, 128, pbT, t1T, 64, 0);
  gemm_k<4, 1, 0, 0, 0><<<dim3(512, 1, 1), 256, 0, stream>>>(
      t1T, 64, 0, wbf + 16384, a1_pb, nullptr, nullptr, nullptr, nullptr, t1pT, 64, 0);

  gattn_k<<<dim3(256, 4), 256, 0, stream>>>(
      qgT, 256, 0, qgT, 256, 192, t1pT, 64, 0, pbT, t1T, 64, 0);
  gemm_k<4, 1, 0, 0, 2><<<dim3(512, 1, 1), 256, 0, stream>>>(
      t1T, 64, 0, wbf + 20480, a2_pb, nullptr, nullptr, nullptr, nullptr, yT, 128, 64);

  // window branches: qkv GEMM (window-ordered) + MFMA attention
  gemm_k<6, 1, 1, 0, 3><<<dim3(512, 2, 1), 256, 0, stream>>>(
      xTf, 128, 64, wq2bf, bias192, nullptr, nullptr, nullptr, nullptr, qkv2, 96, 0);
  swat_k<<<dim3(256, 2), 256, 0, stream>>>(
      qkv2, rpbT_sw, rpbT_wn, sw_pw, sw_pb, wn_pw, wn_pb, yT);

  gemm_k<8, 2, 0, 2, 0><<<dim3(512, 1, 1), 256, 0, stream>>>(
      yT, 128, 0, wbf + 24576, fc_b, ln_g, ln_b, xTf, nullptr, x2T, 128, 0);

  gemm_k<8, 2, 0, 1, 0><<<dim3(512, 2, 1), 256, 0, stream>>>(
      x2T, 128, 0, wbf + 40960, m1_b, nullptr, nullptr, nullptr, nullptr, hT, 256, 0);
  gemm_k<8, 4, 0, 3, 0><<<dim3(512, 1, 1), 256, 0, stream>>>(
      hT, 256, 0, wbf + 73728, m2_b, n2_g, n2_b, xTf, x2T, out, 128, 0);
}

// Round 10
// 194.641 us; speedup vs baseline: 2.0205x; 1.0843x over previous
//
#include <hip/hip_runtime.h>
#include <hip/hip_bf16.h>
#include <cstdint>

// ---------------------------------------------------------------------------
// GABlock, channel-last bf16-MFMA pipeline.
// R10: bf16 channel-last activation buffer (halves 4 big reads/writes);
//      EPI=3 NCHW epilogue restructured to full-line float4 stores.
// ---------------------------------------------------------------------------

typedef __attribute__((ext_vector_type(8))) short bf8_t;   // 8 bf16 (4 VGPR)
typedef __attribute__((ext_vector_type(4))) float f4_t;    // 4 f32 acc

__device__ __forceinline__ float bf2f(unsigned short u) {
  union { unsigned int i; float f; } x; x.i = ((unsigned int)u) << 16; return x.f;
}
__device__ __forceinline__ unsigned short f2bf(float f) {
  union { float f; unsigned int i; } x; x.f = f;
  unsigned int r = x.i + 0x7FFFu + ((x.i >> 16) & 1u);
  return (unsigned short)(r >> 16);
}
// HW packed f32x2 -> bf16x2 (RNE).
__device__ __forceinline__ unsigned int pk2(float a, float b) {
  unsigned int d;
  asm("v_cvt_pk_bf16_f32 %0, %1, %2" : "=v"(d) : "v"(a), "v"(b));
  return d;
}

#define MB (1048576L)

// ---------------- dynamic position bias MLP --------------------------------
__global__ void pos_mlp_k(const float* __restrict__ w1, const float* __restrict__ b1,
                          const float* __restrict__ w2, const float* __restrict__ b2,
                          const float* __restrict__ w3, const float* __restrict__ b3,
                          float* __restrict__ table) {
  int j = blockIdx.x * 256 + threadIdx.x;
  if (j >= 961) return;
  float chv = (float)(j / 31) - 15.0f;
  float cwv = (float)(j % 31) - 15.0f;
  float t1[16], t2[16];
#pragma unroll
  for (int i = 0; i < 16; ++i) {
    float s = fmaf(w1[i * 2], chv, fmaf(w1[i * 2 + 1], cwv, b1[i]));
    t1[i] = fmaxf(s, 0.0f);
  }
#pragma unroll
  for (int i = 0; i < 16; ++i) {
    float s = b2[i];
#pragma unroll
    for (int k = 0; k < 16; ++k) s = fmaf(w2[i * 16 + k], t1[k], s);
    t2[i] = fmaxf(s, 0.0f);
  }
#pragma unroll
  for (int hh = 0; hh < 4; ++hh) {
    float s = b3[hh];
#pragma unroll
    for (int k = 0; k < 16; ++k) s = fmaf(w3[hh * 16 + k], t2[k], s);
    table[j * 4 + hh] = s;
  }
}

// pbT[h][m][q]
__global__ void pbT_gather_k(const float* __restrict__ table, float* __restrict__ pbT) {
  int t = blockIdx.x * 256 + threadIdx.x;   // 4*256*256
  int hh = t >> 16;
  int r = t & 65535;
  int m = r >> 8;
  int q = r & 255;
  int idx = ((q >> 4) - (m >> 4) + 15) * 31 + ((q & 15) - (m & 15) + 15);
  pbT[t] = table[idx * 4 + hh];
}

// rpbT[h][m][n]
__global__ void rpbT_k(const float* __restrict__ rpb, float* __restrict__ rpbT) {
  int t = blockIdx.x * 256 + threadIdx.x;  // 16384
  int h = t >> 12, r = t & 4095, m = r >> 6, n = r & 63;
  int idx = ((n >> 3) - (m >> 3) + 7) * 15 + ((n & 7) - (m & 7) + 7);
  rpbT[t] = rpb[idx * 4 + h];
}

// block-diagonal 192x64 qkv weight (bf16, q-rows pre-scaled) + 192 bias
__global__ void wq2_k(const float* __restrict__ sw_w, const float* __restrict__ sw_b,
                      const float* __restrict__ wn_w, const float* __restrict__ wn_b,
                      unsigned short* __restrict__ w2, float* __restrict__ b2) {
  const float QS = 0.35355339059327373f;
  int t = blockIdx.x * 256 + threadIdx.x;   // 12288
  if (t < 12288) {
    int row = t >> 6, col = t & 63;
    float v = 0.0f;
    if (row < 96) { if (col < 32) v = sw_w[row * 32 + col]; }
    else          { if (col >= 32) v = wn_w[(row - 96) * 32 + col - 32]; }
    int rb = row % 96;
    if (rb < 32) v *= QS;
    w2[t] = f2bf(v);
  }
  if (t < 192) {
    float v = t < 96 ? sw_b[t] : wn_b[t - 96];
    if ((t % 96) < 32) v *= QS;
    b2[t] = v;
  }
}

// all GEMM weights -> bf16 (ga_gp pre-scaled 0.25), plus combined qg bias.
__global__ void wcvt_k(const float* __restrict__ w0, const float* __restrict__ w1,
                       const float* __restrict__ w2, const float* __restrict__ w3,
                       const float* __restrict__ w4, const float* __restrict__ w5,
                       const float* __restrict__ w6,
                       const float* __restrict__ qkv_b, const float* __restrict__ gp_b,
                       unsigned short* __restrict__ dst, float* __restrict__ biasQG) {
  int t = blockIdx.x * 256 + threadIdx.x;
  if (t < 256) biasQG[t] = t < 192 ? qkv_b[t] : gp_b[t - 192] * 0.25f;
  if (t >= 106496) return;
  const float* src; int off; float sc = 1.0f;
  if (t < 12288)      { src = w0; off = 0; }
  else if (t < 16384) { src = w1; off = 12288; sc = 0.25f; }
  else if (t < 20480) { src = w2; off = 16384; }
  else if (t < 24576) { src = w3; off = 20480; }
  else if (t < 40960) { src = w4; off = 24576; }
  else if (t < 73728) { src = w5; off = 40960; }
  else                { src = w6; off = 73728; }
  dst[t] = f2bf(src[t - off] * sc);
}

// ---------------- NCHW fp32 -> channel-last bf16 ---------------------------
__global__ __launch_bounds__(256) void tin_k(const float* __restrict__ x,
                                             unsigned short* __restrict__ xTb) {
  __shared__ float tile[64][132];
  const int b = blockIdx.z, px0 = blockIdx.x * 64, tid = threadIdx.x;
#pragma unroll
  for (int i = 0; i < 8; ++i) {
    int e = i * 256 + tid;
    int c = e >> 4, p4 = (e & 15) * 4;
    float4 v = *(const float4*)(x + (((size_t)(b * 128 + c)) << 14) + px0 + p4);
    tile[p4][c] = v.x; tile[p4 + 1][c] = v.y; tile[p4 + 2][c] = v.z; tile[p4 + 3][c] = v.w;
  }
  __syncthreads();
#pragma unroll
  for (int i = 0; i < 8; ++i) {
    int e = i * 256 + tid;
    int px = e >> 5, c4 = (e & 31) * 4;
    uint2 w = {pk2(tile[px][c4], tile[px][c4 + 1]), pk2(tile[px][c4 + 2], tile[px][c4 + 3])};
    *(uint2*)(xTb + ((size_t)(b * 16384 + px0 + px)) * 128 + c4) = w;
  }
}

// ---------------- generic bf16-MFMA GEMM (all operands bf16) ---------------
// EPI: 0 plain->bf16, 1 gelu->bf16, 2 cLN+res(bf16)->bf16,
//      3 cLN+res(bf16)+res2(bf16)->f32 NCHW full-line stores
template <int NF, int KC, int EPI, int OSHUF>
__global__ __launch_bounds__(256) void gemm_k(
    const unsigned short* __restrict__ A, int a_rs, int a_c0,
    const unsigned short* __restrict__ W, const float* __restrict__ bias,
    const float* __restrict__ g, const float* __restrict__ bb,
    const unsigned short* __restrict__ resf, const unsigned short* __restrict__ resb,
    void* __restrict__ out, int o_rs, int o_c0) {
  __shared__ __align__(16) char Asw[128 * 128];
  __shared__ __align__(16) char Bsw[NF * 16 * 128];
  const int tid = threadIdx.x;
  const int lane = tid & 63, wv = tid >> 6, wpx = wv * 32;
  const int lr = lane & 15, lg = lane >> 4;
  const int px0 = blockIdx.x * 128;
  const int co0 = blockIdx.y * (NF * 16);

  f4_t acc[2][NF];
#pragma unroll
  for (int mf = 0; mf < 2; ++mf)
#pragma unroll
    for (int nf = 0; nf < NF; ++nf) acc[mf][nf] = (f4_t){0.f, 0.f, 0.f, 0.f};

  for (int kc = 0; kc < KC; ++kc) {
    const int k0 = kc * 64;
    if (kc) __syncthreads();
#pragma unroll
    for (int i = 0; i < 4; ++i) {
      int e = i * 256 + tid;
      int row = e >> 3, q8 = e & 7;
      const unsigned short* src = A + (size_t)(px0 + row) * a_rs + a_c0 + k0 + q8 * 8;
      *(uint4*)(Asw + row * 128 + ((q8 ^ (row & 7)) << 4)) = *(const uint4*)src;
    }
#pragma unroll
    for (int i = 0; i < NF / 2; ++i) {
      int e = i * 256 + tid;
      int row = e >> 3, q8 = e & 7;
      const unsigned short* src = W + (size_t)(co0 + row) * (KC * 64) + k0 + q8 * 8;
      *(uint4*)(Bsw + row * 128 + ((q8 ^ (row & 7)) << 4)) = *(const uint4*)src;
    }
    __syncthreads();
#pragma unroll
    for (int ks = 0; ks < 2; ++ks) {
      const int xk = (((ks * 4) + lg) ^ (lane & 7)) << 4;
      bf8_t av[2], bv[NF];
#pragma unroll
      for (int mf = 0; mf < 2; ++mf)
        av[mf] = *(const bf8_t*)(Asw + (wpx + mf * 16 + lr) * 128 + xk);
#pragma unroll
      for (int nf = 0; nf < NF; ++nf)
        bv[nf] = *(const bf8_t*)(Bsw + (nf * 16 + lr) * 128 + xk);
#pragma unroll
      for (int mf = 0; mf < 2; ++mf)
#pragma unroll
        for (int nf = 0; nf < NF; ++nf)
          acc[mf][nf] = __builtin_amdgcn_mfma_f32_16x16x32_bf16(av[mf], bv[nf], acc[mf][nf], 0, 0, 0);
    }
  }

  float bco[NF];
#pragma unroll
  for (int nf = 0; nf < NF; ++nf) bco[nf] = bias[co0 + nf * 16 + lr];

  if constexpr (EPI >= 2) {
    float gv[NF], bbv[NF];
#pragma unroll
    for (int nf = 0; nf < NF; ++nf) { gv[nf] = g[nf * 16 + lr]; bbv[nf] = bb[nf * 16 + lr]; }
#pragma unroll
    for (int mf = 0; mf < 2; ++mf)
#pragma unroll
      for (int nf = 0; nf < NF; ++nf)
#pragma unroll
        for (int r = 0; r < 4; ++r) acc[mf][nf][r] += bco[nf];
#pragma unroll
    for (int mf = 0; mf < 2; ++mf) {
      float mus[4], rss[4];
#pragma unroll
      for (int r = 0; r < 4; ++r) {
        float s = 0.f, q = 0.f;
#pragma unroll
        for (int nf = 0; nf < NF; ++nf) {
          float v = acc[mf][nf][r];
          s += v; q += v * v;
        }
#pragma unroll
        for (int msk = 1; msk < 16; msk <<= 1) {
          s += __shfl_xor(s, msk);
          q += __shfl_xor(q, msk);
        }
        float mu = s * (1.0f / 128.0f);
        float var = q * (1.0f / 128.0f) - mu * mu;
        mus[r] = mu;
        rss[r] = rsqrtf(var + 1e-5f);
      }
      if constexpr (EPI == 2) {
#pragma unroll
        for (int r = 0; r < 4; ++r) {
          int px_e = px0 + wpx + mf * 16 + lg * 4 + r;
          const unsigned short* xr = resf + (size_t)px_e * 128 + lr;
          unsigned short* op = (unsigned short*)out + (size_t)px_e * o_rs + lr;
#pragma unroll
          for (int nf = 0; nf < NF; ++nf) {
            float v = (acc[mf][nf][r] - mus[r]) * rss[r] * gv[nf] + bbv[nf] + bf2f(xr[nf * 16]);
            op[nf * 16] = f2bf(v);
          }
        }
      } else {  // EPI == 3: fp32 NCHW, one float4 (4 px) per channel per thread
        int pxb = px0 + wpx + mf * 16 + lg * 4;
        int b_ = pxb >> 14, p_ = pxb & 16383;
#pragma unroll
        for (int nf = 0; nf < NF; ++nf) {
          int ch = lr + nf * 16;
          float vr[4];
#pragma unroll
          for (int r = 0; r < 4; ++r) {
            float xv  = bf2f(resf[(size_t)(pxb + r) * 128 + ch]);
            float x2v = bf2f(resb[(size_t)(pxb + r) * 128 + ch]);
            vr[r] = (acc[mf][nf][r] - mus[r]) * rss[r] * gv[nf] + bbv[nf] + xv + x2v;
          }
          float4 v4 = {vr[0], vr[1], vr[2], vr[3]};
          *(float4*)((float*)out + (((size_t)(b_ * 128 + ch)) << 14) + p_) = v4;
        }
      }
    }
  } else {
#pragma unroll
    for (int mf = 0; mf < 2; ++mf) {
#pragma unroll
      for (int r = 0; r < 4; ++r) {
        int px_e = px0 + wpx + mf * 16 + lg * 4 + r;
        size_t orow;
        int cadj = co0;
        if constexpr (OSHUF == 0) {
          orow = (size_t)px_e;
        } else if constexpr (OSHUF == 1) {
          int b = px_e >> 14, p = px_e & 16383, hh = p >> 7, w_ = p & 127;
          orow = (size_t)(b * 64 + (hh & 7) * 8 + (w_ & 7)) * 256 + ((hh >> 3) * 16 + (w_ >> 3));
        } else if constexpr (OSHUF == 2) {
          int gbb = px_e >> 8, n = px_e & 255;
          int b = gbb >> 6, ih = (gbb >> 3) & 7, iw = gbb & 7;
          orow = (size_t)b * 16384 + ((n >> 4) * 8 + ih) * 128 + (n & 15) * 8 + iw;
        } else {  // window-order: br0 = sw(shift 4), br1 = wn(shift 0)
          int brx = (co0 >= 96);
          int b = px_e >> 14, p = px_e & 16383, hh = p >> 7, w_ = p & 127;
          int sh = brx ? 0 : 4;
          int h2 = (hh - sh) & 127, w2_ = (w_ - sh) & 127;
          orow = (size_t)brx * 65536 + (size_t)b * 16384 +
                 (size_t)(((h2 >> 3) * 16 + (w2_ >> 3)) * 64 + (h2 & 7) * 8 + (w2_ & 7));
          cadj = co0 - brx * 96;
        }
        unsigned short* op = (unsigned short*)out + orow * o_rs + o_c0 + cadj + lr;
#pragma unroll
        for (int nf = 0; nf < NF; ++nf) {
          float v = acc[mf][nf][r] + bco[nf];
          if constexpr (EPI == 1) v = 0.5f * v * (1.0f + erff(v * 0.7071067811865475f));
          op[nf * 16] = f2bf(v);
        }
      }
    }
  }
}

// ---------------- MFMA grid attention (N=256, hd=16, 4 heads) --------------
__global__ __launch_bounds__(256) void gattn_k(
    const unsigned short* __restrict__ Q, int q_rs, int q_c0,
    const unsigned short* __restrict__ K, int k_rs, int k_c0,
    const unsigned short* __restrict__ V, int v_rs, int v_c0,
    const float* __restrict__ pbT, unsigned short* __restrict__ outb, int o_rs, int o_c0) {
  __shared__ __align__(16) unsigned short K_lds[256 * 16];
  __shared__ __align__(16) unsigned short Vt[16 * 256];      // swz [d][m]
  __shared__ __align__(16) unsigned short P_lds[4 * 64 * 32];// per-wave swz [q][m]
  const int gb = blockIdx.x, h = blockIdx.y, tid = threadIdx.x;
  const int lane = tid & 63, wv = tid >> 6;
  const int lr = lane & 15, lg = lane >> 4;
  const int q0 = wv * 64;

  {
    const unsigned short* kp = K + (size_t)(gb * 256 + tid) * k_rs + k_c0 + h * 16;
    *(uint4*)&K_lds[tid * 16]     = *(const uint4*)kp;
    *(uint4*)&K_lds[tid * 16 + 8] = *(const uint4*)(kp + 8);
    const unsigned short* vp = V + (size_t)(gb * 256 + tid) * v_rs + v_c0 + h * 16;
    uint4 va = *(const uint4*)vp;
    uint4 vb = *(const uint4*)(vp + 8);
    unsigned int w8[8] = {va.x, va.y, va.z, va.w, vb.x, vb.y, vb.z, vb.w};
    int chb = (tid >> 3);
    int wi = tid & 7;
#pragma unroll
    for (int w = 0; w < 8; ++w) {
      int d0 = 2 * w, d1 = 2 * w + 1;
      Vt[d0 * 256 + ((chb ^ (d0 & 7)) << 3) + wi] = (unsigned short)(w8[w] & 0xffff);
      Vt[d1 * 256 + ((chb ^ (d1 & 7)) << 3) + wi] = (unsigned short)(w8[w] >> 16);
    }
  }
  bf8_t bq[4];
  const bf8_t bz = {0, 0, 0, 0, 0, 0, 0, 0};
#pragma unroll
  for (int qt = 0; qt < 4; ++qt) {
    bq[qt] = bz;
    if (lg < 2)
      bq[qt] = *(const bf8_t*)(Q + (size_t)(gb * 256 + q0 + qt * 16 + lr) * q_rs + q_c0 + h * 16 + lg * 8);
  }
  __syncthreads();

  const f4_t z4 = {0.f, 0.f, 0.f, 0.f};
  f4_t oacc[4];
  float lrun[4];
#pragma unroll
  for (int qt = 0; qt < 4; ++qt) { oacc[qt] = z4; lrun[qt] = 0.0f; }

  unsigned short* Pw = &P_lds[wv * 64 * 32];

  for (int m0 = 0; m0 < 256; m0 += 32) {
    bf8_t ak0 = bz, ak1 = bz;
    if (lg < 2) {
      ak0 = *(const bf8_t*)&K_lds[(m0 + lr) * 16 + lg * 8];
      ak1 = *(const bf8_t*)&K_lds[(m0 + 16 + lr) * 16 + lg * 8];
    }
    bf8_t av = *(const bf8_t*)&Vt[lr * 256 + ((((m0 >> 3) + lg) ^ (lr & 7)) << 3)];

#pragma unroll
    for (int qt = 0; qt < 4; ++qt) {
      const float* bpm = pbT + ((size_t)(h * 256 + m0 + lg * 4) << 8) + q0 + qt * 16 + lr;
      f4_t c0v = {bpm[0], bpm[256], bpm[512], bpm[768]};
      f4_t c1v = {bpm[4096], bpm[4352], bpm[4608], bpm[4864]};
      f4_t st0 = __builtin_amdgcn_mfma_f32_16x16x32_bf16(ak0, bq[qt], c0v, 0, 0, 0);
      f4_t st1 = __builtin_amdgcn_mfma_f32_16x16x32_bf16(ak1, bq[qt], c1v, 0, 0, 0);
      float p0[4], p1[4], ls = 0.0f;
#pragma unroll
      for (int r = 0; r < 4; ++r) {
        p0[r] = __expf(st0[r]);
        p1[r] = __expf(st1[r]);
        ls += p0[r] + p1[r];
      }
      ls += __shfl_xor(ls, 16);
      ls += __shfl_xor(ls, 32);
      lrun[qt] += ls;
      int row = qt * 16 + lr;
      int rw3 = row & 3;
      uint2 w0 = {pk2(p0[0], p0[1]), pk2(p0[2], p0[3])};
      uint2 w1 = {pk2(p1[0], p1[1]), pk2(p1[2], p1[3])};
      *(uint2*)&Pw[row * 32 + ((((lg >> 1)) ^ rw3) << 3) + (lg & 1) * 4]     = w0;
      *(uint2*)&Pw[row * 32 + (((2 + (lg >> 1)) ^ rw3) << 3) + (lg & 1) * 4] = w1;
    }
#pragma unroll
    for (int qt = 0; qt < 4; ++qt) {
      int row = qt * 16 + lr;
      bf8_t bp = *(const bf8_t*)&Pw[row * 32 + ((lg ^ (row & 3)) << 3)];
      oacc[qt] = __builtin_amdgcn_mfma_f32_16x16x32_bf16(av, bp, oacc[qt], 0, 0, 0);
    }
  }

#pragma unroll
  for (int qt = 0; qt < 4; ++qt) {
    float inv = 1.0f / lrun[qt];
    uint2 o;
    o.x = pk2(oacc[qt][0] * inv, oacc[qt][1] * inv);
    o.y = pk2(oacc[qt][2] * inv, oacc[qt][3] * inv);
    unsigned short* op = outb + (size_t)(gb * 256 + q0 + qt * 16 + lr) * o_rs + o_c0 + h * 16 + lg * 4;
    *(uint2*)op = o;
  }
}

// ---------------- MFMA swin window attention (barrier-free) ----------------
__global__ __launch_bounds__(256) void swat_k(
    const unsigned short* __restrict__ qkv2,
    const float* __restrict__ rpbT_sw, const float* __restrict__ rpbT_wn,
    const float* __restrict__ sw_pw, const float* __restrict__ sw_pb,
    const float* __restrict__ wn_pw, const float* __restrict__ wn_pb,
    unsigned short* __restrict__ yT) {
  __shared__ __align__(16) unsigned short Vt[4 * 8 * 64];
  __shared__ __align__(16) unsigned short Pt[4 * 64 * 64];
  __shared__ __align__(16) unsigned short aoT[4 * 64 * 32];
  const int tid = threadIdx.x, lane = tid & 63, wv = tid >> 6;
  const int lr = lane & 15, lg = lane >> 4;
  const int br = blockIdx.y;
  const int win = blockIdx.x * 4 + wv;
  const int b = win >> 8, wl = win & 255, wh = wl >> 4, ww = wl & 15;
  const float* rpbT = br ? rpbT_wn : rpbT_sw;
  const float* pw   = br ? wn_pw : sw_pw;
  const float* pb   = br ? wn_pb : sw_pb;
  const int shift = br ? 0 : 4;
  const int yc0 = br ? 0 : 32;
  const bool edge = (shift > 0) && (wh == 15 || ww == 15);

  const unsigned short* qw = qkv2 + (size_t)br * 65536 * 96 + (size_t)win * 64 * 96;
  const f4_t z4 = {0.f, 0.f, 0.f, 0.f};
  const bf8_t bz = {0, 0, 0, 0, 0, 0, 0, 0};
  unsigned short* Vw = &Vt[wv * 8 * 64];
  unsigned short* Pw = &Pt[wv * 64 * 64];
  unsigned short* aw_ = &aoT[wv * 64 * 32];

#pragma unroll 1
  for (int h = 0; h < 4; ++h) {
    {
      uint4 v = *(const uint4*)(qw + lane * 96 + 64 + h * 8);
      unsigned int w4[4] = {v.x, v.y, v.z, v.w};
      int chb = lane >> 3, wi = lane & 7;
#pragma unroll
      for (int j = 0; j < 4; ++j) {
        int d0 = 2 * j, d1 = 2 * j + 1;
        Vw[d0 * 64 + ((chb ^ (d0 & 7)) << 3) + wi] = (unsigned short)(w4[j] & 0xffff);
        Vw[d1 * 64 + ((chb ^ (d1 & 7)) << 3) + wi] = (unsigned short)(w4[j] >> 16);
      }
    }
    bf8_t bq[4];
#pragma unroll
    for (int nt = 0; nt < 4; ++nt) {
      bq[nt] = bz;
      if (lg == 0) bq[nt] = *(const bf8_t*)(qw + (nt * 16 + lr) * 96 + h * 8);
    }
    f4_t st[4][4];
#pragma unroll
    for (int mt = 0; mt < 4; ++mt) {
      bf8_t ak = bz;
      if (lg == 0) ak = *(const bf8_t*)(qw + (mt * 16 + lr) * 96 + 32 + h * 8);
#pragma unroll
      for (int nt = 0; nt < 4; ++nt) {
        const float* rp = rpbT + h * 4096 + (mt * 16 + lg * 4) * 64 + nt * 16 + lr;
        f4_t cb = {rp[0], rp[64], rp[128], rp[192]};
        st[mt][nt] = __builtin_amdgcn_mfma_f32_16x16x32_bf16(ak, bq[nt], cb, 0, 0, 0);
      }
    }
#pragma unroll
    for (int nt = 0; nt < 4; ++nt) {
      float sv[16];
#pragma unroll
      for (int mt = 0; mt < 4; ++mt)
#pragma unroll
        for (int r = 0; r < 4; ++r) sv[mt * 4 + r] = st[mt][nt][r];
      if (edge) {
        int n = nt * 16 + lr;
        int regn = ((wh < 15) ? 0 : (((n >> 3) < 4) ? 1 : 2)) * 3 +
                   ((ww < 15) ? 0 : (((n & 7) < 4) ? 1 : 2));
#pragma unroll
        for (int mt = 0; mt < 4; ++mt)
#pragma unroll
          for (int r = 0; r < 4; ++r) {
            int m = mt * 16 + lg * 4 + r;
            int regm = ((wh < 15) ? 0 : (((m >> 3) < 4) ? 1 : 2)) * 3 +
                       ((ww < 15) ? 0 : (((m & 7) < 4) ? 1 : 2));
            if (regm != regn) sv[mt * 4 + r] -= 100.0f;
          }
      }
      float l = 0.0f;
#pragma unroll
      for (int i = 0; i < 16; ++i) {
        sv[i] = __expf(sv[i]);
        l += sv[i];
      }
      l += __shfl_xor(l, 16);
      l += __shfl_xor(l, 32);
      float inv = 1.0f / l;
      int row = nt * 16 + lr, rw7 = lr & 7;
#pragma unroll
      for (int mt = 0; mt < 4; ++mt) {
        uint2 w = {pk2(sv[mt * 4] * inv, sv[mt * 4 + 1] * inv),
                   pk2(sv[mt * 4 + 2] * inv, sv[mt * 4 + 3] * inv)};
        *(uint2*)&Pw[row * 64 + (((2 * mt + (lg >> 1)) ^ rw7) << 3) + (lg & 1) * 4] = w;
      }
    }
    f4_t oa[4] = {z4, z4, z4, z4};
#pragma unroll
    for (int ks = 0; ks < 2; ++ks) {
      bf8_t av = bz;
      if (lr < 8) av = *(const bf8_t*)&Vw[lr * 64 + (((4 * ks + lg) ^ (lr & 7)) << 3)];
#pragma unroll
      for (int nt = 0; nt < 4; ++nt) {
        int row = nt * 16 + lr;
        bf8_t bp = *(const bf8_t*)&Pw[row * 64 + (((4 * ks + lg) ^ (lr & 7)) << 3)];
        oa[nt] = __builtin_amdgcn_mfma_f32_16x16x32_bf16(av, bp, oa[nt], 0, 0, 0);
      }
    }
    if (lg < 2) {
#pragma unroll
      for (int nt = 0; nt < 4; ++nt) {
        uint2 w = {pk2(oa[nt][0], oa[nt][1]), pk2(oa[nt][2], oa[nt][3])};
        int row = nt * 16 + lr;
        *(uint2*)&aw_[row * 32 + ((h ^ (lr & 3)) << 3) + lg * 4] = w;
      }
    }
  }

#pragma unroll
  for (int mt = 0; mt < 2; ++mt) {
    const float* wr = pw + (mt * 16 + lr) * 32 + lg * 8;
    float4 a0 = *(const float4*)wr, a1 = *(const float4*)(wr + 4);
    union { uint4 u; bf8_t v; } aw;
    aw.u.x = pk2(a0.x, a0.y); aw.u.y = pk2(a0.z, a0.w);
    aw.u.z = pk2(a1.x, a1.y); aw.u.w = pk2(a1.z, a1.w);
    float pb0 = pb[mt * 16 + lg * 4], pb1 = pb[mt * 16 + lg * 4 + 1];
    float pb2 = pb[mt * 16 + lg * 4 + 2], pb3 = pb[mt * 16 + lg * 4 + 3];
#pragma unroll
    for (int nt = 0; nt < 4; ++nt) {
      int row = nt * 16 + lr;
      bf8_t bo = *(const bf8_t*)&aw_[row * 32 + ((lg ^ (lr & 3)) << 3)];
      f4_t po = __builtin_amdgcn_mfma_f32_16x16x32_bf16(aw.v, bo, z4, 0, 0, 0);
      int n = nt * 16 + lr;
      int hdst = (wh * 8 + (n >> 3) + shift) & 127;
      int wdst = (ww * 8 + (n & 7) + shift) & 127;
      uint2 w = {pk2(po[0] + pb0, po[1] + pb1), pk2(po[2] + pb2, po[3] + pb3)};
      *(uint2*)(yT + ((size_t)(b * 16384 + hdst * 128 + wdst)) * 128 + yc0 + mt * 16 + lg * 4) = w;
    }
  }
}

// ---------------------------------------------------------------------------
extern "C" void kernel_launch(void* const* d_in, const int* in_sizes, int n_in,
                              void* d_out, int out_size, void* d_ws, size_t ws_size,
                              hipStream_t stream) {
  (void)in_sizes; (void)n_in; (void)out_size; (void)ws_size;
  const float* x        = (const float*)d_in[0];
  const float* ln_g     = (const float*)d_in[1];
  const float* ln_b     = (const float*)d_in[2];
  const float* ga_qkv_w = (const float*)d_in[3];
  const float* ga_qkv_b = (const float*)d_in[4];
  const float* ga_gp_w  = (const float*)d_in[5];
  const float* ga_gp_b  = (const float*)d_in[6];
  const float* pos_w1   = (const float*)d_in[7];
  const float* pos_b1   = (const float*)d_in[8];
  const float* pos_w2   = (const float*)d_in[9];
  const float* pos_b2   = (const float*)d_in[10];
  const float* pos_w3   = (const float*)d_in[11];
  const float* pos_b3   = (const float*)d_in[12];
  const float* a1_pw    = (const float*)d_in[13];
  const float* a1_pb    = (const float*)d_in[14];
  const float* a2_pw    = (const float*)d_in[15];
  const float* a2_pb    = (const float*)d_in[16];
  const float* sw_qkv_w = (const float*)d_in[17];
  const float* sw_qkv_b = (const float*)d_in[18];
  const float* sw_rpb   = (const float*)d_in[19];
  const float* sw_pw    = (const float*)d_in[20];
  const float* sw_pb    = (const float*)d_in[21];
  const float* wn_qkv_w = (const float*)d_in[22];
  const float* wn_qkv_b = (const float*)d_in[23];
  const float* wn_rpb   = (const float*)d_in[24];
  const float* wn_pw    = (const float*)d_in[25];
  const float* wn_pb    = (const float*)d_in[26];
  const float* fc_w     = (const float*)d_in[27];
  const float* fc_b     = (const float*)d_in[28];
  const float* n2_g     = (const float*)d_in[29];
  const float* n2_b     = (const float*)d_in[30];
  const float* m1_w     = (const float*)d_in[31];
  const float* m1_b     = (const float*)d_in[32];
  const float* m2_w     = (const float*)d_in[33];
  const float* m2_b     = (const float*)d_in[34];
  float* out = (float*)d_out;
  char* base = (char*)d_ws;

  unsigned short* xTb    = (unsigned short*)(base);           // 16 MB (alive thru m2)
  unsigned short* qgT    = (unsigned short*)(base + 16 * MB); // 32 MB [px][256: q|k|v|g]
  unsigned short* t1T    = (unsigned short*)(base + 48 * MB); //  8 MB
  unsigned short* t1pT   = (unsigned short*)(base + 56 * MB); //  8 MB
  unsigned short* yT     = (unsigned short*)(base + 64 * MB); // 16 MB
  unsigned short* x2T    = (unsigned short*)(base + 80 * MB); // 16 MB
  unsigned short* qkv2   = (unsigned short*)(base + 16 * MB); // 24 MB alias (after gattn2)
  unsigned short* hT     = (unsigned short*)(base + 16 * MB); // 32 MB alias (after swat)
  float*          pbT    = (float*)(base + 96 * MB);          //  1 MB
  float*          ptab   = (float*)(base + 97 * MB);          // 16 KB
  float*          rpbT_sw= (float*)(base + 97 * MB + 65536);
  float*          rpbT_wn= (float*)(base + 97 * MB + 131072);
  unsigned short* wq2bf  = (unsigned short*)(base + 97 * MB + 196608); // 24 KB
  float*          bias192= (float*)(base + 97 * MB + 229376);          // 768 B
  float*          biasQG = (float*)(base + 97 * MB + 230400);          // 1 KB
  unsigned short* wbf    = (unsigned short*)(base + 97 * MB + 262144); // 208 KB

  pos_mlp_k<<<4, 256, 0, stream>>>(pos_w1, pos_b1, pos_w2, pos_b2, pos_w3, pos_b3, ptab);
  pbT_gather_k<<<1024, 256, 0, stream>>>(ptab, pbT);
  rpbT_k<<<64, 256, 0, stream>>>(sw_rpb, rpbT_sw);
  rpbT_k<<<64, 256, 0, stream>>>(wn_rpb, rpbT_wn);
  wq2_k<<<48, 256, 0, stream>>>(sw_qkv_w, sw_qkv_b, wn_qkv_w, wn_qkv_b, wq2bf, bias192);
  wcvt_k<<<416, 256, 0, stream>>>(ga_qkv_w, ga_gp_w, a1_pw, a2_pw, fc_w, m1_w, m2_w,
                                  ga_qkv_b, ga_gp_b, wbf, biasQG);

  tin_k<<<dim3(256, 1, 4), 256, 0, stream>>>(x, xTb);

  // grid branch: one merged qkv+gp GEMM (256 out-ch), grid-shuffled
  gemm_k<4, 1, 0, 1><<<dim3(512, 4, 1), 256, 0, stream>>>(
      xTb, 128, 0, wbf, biasQG, nullptr, nullptr, nullptr, nullptr, qgT, 256, 0);

  gattn_k<<<dim3(256, 4), 256, 0, stream>>>(
      qgT, 256, 192, qgT, 256, 64, qgT, 256, 128, pbT, t1T, 64, 0);
  gemm_k<4, 1, 0, 0><<<dim3(512, 1, 1), 256, 0, stream>>>(
      t1T, 64, 0, wbf + 16384, a1_pb, nullptr, nullptr, nullptr, nullptr, t1pT, 64, 0);

  gattn_k<<<dim3(256, 4), 256, 0, stream>>>(
      qgT, 256, 0, qgT, 256, 192, t1pT, 64, 0, pbT, t1T, 64, 0);
  gemm_k<4, 1, 0, 2><<<dim3(512, 1, 1), 256, 0, stream>>>(
      t1T, 64, 0, wbf + 20480, a2_pb, nullptr, nullptr, nullptr, nullptr, yT, 128, 64);

  // window branches: qkv GEMM (window-ordered) + MFMA attention
  gemm_k<6, 1, 0, 3><<<dim3(512, 2, 1), 256, 0, stream>>>(
      xTb, 128, 64, wq2bf, bias192, nullptr, nullptr, nullptr, nullptr, qkv2, 96, 0);
  swat_k<<<dim3(256, 2), 256, 0, stream>>>(
      qkv2, rpbT_sw, rpbT_wn, sw_pw, sw_pb, wn_pw, wn_pb, yT);

  // fc + cLN + residual(x bf16) -> x2T
  gemm_k<8, 2, 2, 0><<<dim3(512, 1, 1), 256, 0, stream>>>(
      yT, 128, 0, wbf + 24576, fc_b, ln_g, ln_b, xTb, nullptr, x2T, 128, 0);

  gemm_k<8, 2, 1, 0><<<dim3(512, 2, 1), 256, 0, stream>>>(
      x2T, 128, 0, wbf + 40960, m1_b, nullptr, nullptr, nullptr, nullptr, hT, 256, 0);
  gemm_k<8, 4, 3, 0><<<dim3(512, 1, 1), 256, 0, stream>>>(
      hT, 256, 0, wbf + 73728, m2_b, n2_g, n2_b, xTb, x2T, out, 128, 0);
}